// Round 8
// baseline (841.942 us; speedup 1.0000x reference)
//
#include <hip/hip_runtime.h>
#include <hip/hip_bf16.h>

typedef __hip_bfloat16 bf16;
typedef short s8v __attribute__((ext_vector_type(8)));
typedef short s4v __attribute__((ext_vector_type(4)));
typedef float f4v __attribute__((ext_vector_type(4)));

#define A_  5
#define D_  512
#define E_  256
#define NS_ 2048
#define NQ_ 8192
#define NM_ 10240
#define NWAY_ 5
#define QSCALE 0.088388347648318447f
#define FSTR ((size_t)NM_ * E_)

__device__ inline float ldw(const void* p, size_t i, int f32) {
  return f32 ? ((const float*)p)[i] : __bfloat162float(((const bf16*)p)[i]);
}
template<bool DYN>
__device__ inline float ldT(const void* p, size_t i, int f32) {
  if (DYN) return ldw(p, i, f32);
  return ((const float*)p)[i];
}

__device__ inline short f2bf(float v) {
  union { float f; unsigned u; } x; x.f = v;
  unsigned r = x.u + 0x7fffu + ((x.u >> 16) & 1u);
  return (short)(r >> 16);
}
__device__ inline float bf2f(short s) {
  union { unsigned u; float f; } x; x.u = ((unsigned)(unsigned short)s) << 16;
  return x.f;
}

// async global->LDS, 16B per lane; lds dest = base + lane*16 (wave-uniform base)
__device__ __forceinline__ void gload16(const void* g, void* l) {
  __builtin_amdgcn_global_load_lds(
      (const __attribute__((address_space(1))) unsigned int*)g,
      (__attribute__((address_space(3))) unsigned int*)l, 16, 0, 0);
}

struct Ptrs { const void* p[64]; int sz[64]; };

__global__ void probe_k(Ptrs P, int* flags) {
  int b = blockIdx.x, lane = threadIdx.x;
  if (b == 1 || b == 3) { if (lane == 0) flags[b] = 0; return; }
  const bf16* t = (const bf16*)P.p[b];
  int n = P.sz[b];
  int K = (n >> 1) < 64 ? (n >> 1) : 64;
  bool big = false, eNZ = false, oNZ = false;
  if (lane < K) {
    float e = __bfloat162float(t[2 * lane]);
    float o = __bfloat162float(t[2 * lane + 1]);
    big = !(fabsf(e) <= 1e3f);
    eNZ = (e != 0.f); oNZ = (o != 0.f);
  }
  unsigned long long bb = __ballot(big), eb = __ballot(eNZ), ob = __ballot(oNZ);
  if (lane == 0) flags[b] = (bb != 0ull || (eb == 0ull && ob != 0ull)) ? 1 : 0;
}

__global__ void classidx_k(const int* __restrict__ y, int* __restrict__ idx,
                           int* __restrict__ cnt, int* __restrict__ cstart) {
  __shared__ int sc[NWAY_];
  int tid = threadIdx.x;
  if (tid < NWAY_) sc[tid] = 0;
  __syncthreads();
  for (int i = tid; i < NS_; i += 256) {
    int c = y[i];
    int pos = atomicAdd(&sc[c], 1);
    idx[c * NS_ + pos] = i;
  }
  __syncthreads();
  if (tid < NWAY_) cnt[tid] = sc[tid];
  if (tid == 0) { int s = 0; for (int q = 0; q < NWAY_; ++q) { cstart[q] = s; s += sc[q]; } }
}

__global__ void xcopy_k(const void* __restrict__ sx, const void* __restrict__ qx,
                        short* __restrict__ XC, const int* __restrict__ flags) {
  size_t i = ((size_t)blockIdx.x * 256 + threadIdx.x) * 4;
  const size_t SN = (size_t)NS_ * 512;
  if (i < SN) {
    int f = flags[0];
    #pragma unroll
    for (int q = 0; q < 4; ++q) XC[i + q] = f2bf(ldw(sx, i + q, f));
  } else {
    int f = flags[2];
    size_t j = i - SN;
    #pragma unroll
    for (int q = 0; q < 4; ++q) XC[i + q] = f2bf(ldw(qx, j + q, f));
  }
}

// ---- concat 5 layer-1 weights into Wcat[2304][512] bf16 (TRB layout) + bias cat ----
__global__ void wcat_k(Ptrs P, short* __restrict__ Wcat, float* __restrict__ bcat,
                       const int* __restrict__ flags) {
  int n = blockIdx.x * 256 + threadIdx.x;
  int k = blockIdx.y;
  int iw, ib, nl, Nloc;
  if (n < 512)       { iw = 4;  ib = 5;  nl = n;        Nloc = 512; }
  else if (n < 768)  { iw = 12; ib = 13; nl = n - 512;  Nloc = 256; }
  else if (n < 1536) { iw = 18; ib = 19; nl = n - 768;  Nloc = 768; }
  else if (n < 1792) { iw = 24; ib = 25; nl = n - 1536; Nloc = 256; }
  else               { iw = 30; ib = 31; nl = n - 1792; Nloc = 512; }
  Wcat[(size_t)n * 512 + k] = f2bf(ldw(P.p[iw], (size_t)k * Nloc + nl, flags[iw]));
  if (k == 0) bcat[n] = ldw(P.p[ib], nl, flags[ib]);
}

// ---- Bcat2[a][n][k] bf16 ----
__global__ void wcls_k(const void* __restrict__ cw1, const void* __restrict__ fw1,
                       short* __restrict__ B2, const int* __restrict__ flags) {
  int n = blockIdx.x, a = blockIdx.y, k = threadIdx.x;
  float v;
  if (n < 256) v = ldw(cw1, ((size_t)a * 512 + k) * 256 + n, flags[51]);
  else v = ldw(fw1, ((size_t)(a * 256 + k)) * 256 + (n - 256), flags[58]);
  B2[((size_t)a * 512 + n) * 256 + k] = f2bf(v);
}

// ---- convert/transpose remaining weights to bf16 TRB [N][K] into W2 ----
__global__ void wconv_k(Ptrs P, short* __restrict__ W2, const int* __restrict__ flags) {
  const int id = blockIdx.y;
  int src, K, N; size_t off; int tr, batch;
  switch (id) {
    case 0: src = 8;  K = 512; N = 256; off = 0;      tr = 1; batch = 1;  break;
    case 1: src = 16; K = 256; N = 256; off = 131072; tr = 1; batch = 1;  break;
    case 2: src = 20; K = 768; N = 256; off = 196608; tr = 1; batch = 1;  break;
    case 3: src = 26; K = 256; N = 256; off = 393216; tr = 1; batch = 1;  break;
    case 4: src = 32; K = 512; N = 256; off = 458752; tr = 1; batch = 1;  break;
    case 5: src = 34; K = 256; N = 256; off = 589824; tr = 1; batch = 1;  break;
    case 6: src = 53; K = 256; N = 128; off = 655360; tr = 1; batch = A_; break;
    case 7: src = 60; K = 256; N = 128; off = 819200; tr = 1; batch = 1;  break;
    default: src = 47; K = 256; N = 768; off = 851968; tr = 0; batch = A_; break;
  }
  size_t tot = (size_t)batch * K * N;
  size_t e0 = ((size_t)blockIdx.x * 256 + threadIdx.x) * 4;
  if (e0 >= tot) return;
  const void* sp = P.p[src];
  int f = flags[src];
  if (!tr) {
    #pragma unroll
    for (int q = 0; q < 4; ++q) W2[off + e0 + q] = f2bf(ldw(sp, e0 + q, f));
  } else {
    size_t kn = (size_t)K * N;
    #pragma unroll
    for (int q = 0; q < 4; ++q) {
      size_t e = e0 + q;
      int b = (int)(e / kn);
      int r = (int)(e % kn);
      int n = r / K, k = r % K;
      W2[off + e] = f2bf(ldw(sp, ((size_t)b * K + k) * N + n, f));
    }
  }
}

// ============ MFMA bf16 GEMM (128x128, 4-wave) ============
#define LSTR 40
template<int AMODE, int BMODE, bool DYNBIAS, bool TRB, int ACT, bool ACCUM,
         bool KSPLIT = false, bool OUTBF16 = false, bool DOMAP = false>
__global__ __launch_bounds__(256) void gemm_k(
    const void* __restrict__ A, int lda,
    const void* __restrict__ B, int ldb, size_t offB,
    const void* __restrict__ bias, size_t offBias,
    float* __restrict__ C, int ldc,
    int M, int N, int K, float alpha,
    int ia, int ib, int ibias, const int* __restrict__ flags,
    size_t sA, size_t sB, size_t sBias, size_t sC, size_t kstrideA,
    unsigned long long amap)
{
  constexpr bool GDB = (AMODE == 2) && (BMODE == 2) && TRB && !KSPLIT;
  const int fA = (AMODE == 1) ? flags[ia] : 1;
  const int fB = (BMODE == 1) ? flags[ib] : 1;
  const int fBi = DYNBIAS ? flags[ibias] : 1;
  const size_t zA = (size_t)blockIdx.z * sA;
  const size_t zB = offB + (size_t)blockIdx.z * sB;
  const size_t zBias = offBias + (size_t)blockIdx.z * sBias;
  float* Cz = C + (size_t)blockIdx.z * sC;
  bf16* Cz16 = (bf16*)C + (size_t)blockIdx.z * sC;
  const int tid = threadIdx.x;
  const int bm = blockIdx.y * 128, bn = blockIdx.x * 128;
  const int lane = tid & 63, wid = tid >> 6;
  const int lm = lane & 15, quad = lane >> 4;
  const int wy = (wid >> 1) * 64, wx = (wid & 1) * 64;
  f4v acc[4][4];
  #pragma unroll
  for (int i = 0; i < 4; ++i)
    #pragma unroll
    for (int j = 0; j < 4; ++j) acc[i][j] = (f4v)(0.f);

  if constexpr (GDB) {
    __shared__ short smem[4 * 128 * 32];   // 32 KB: [A0|A1|B0|B1]
    const int srow = lane >> 2, scol = (lane & 3) * 8;
    const short* Azs = (const short*)A + zA;
    const short* Bzs = (const short*)B + zB;
    auto stage = [&](int bsel, int k0) {
      short* Asb = smem + bsel * 4096;
      short* Bsb = smem + 8192 + bsel * 4096;
      #pragma unroll
      for (int q = 0; q < 2; ++q) {
        int rb = (wid * 2 + q) * 16;
        gload16(Azs + (size_t)(bm + rb + srow) * lda + k0 + scol, Asb + rb * 32);
        gload16(Bzs + (size_t)(bn + rb + srow) * ldb + k0 + scol, Bsb + rb * 32);
      }
    };
    stage(0, 0);
    __syncthreads();
    int cur = 0;
    for (int k0 = 0; k0 < K; k0 += 32) {
      if (k0 + 32 < K) stage(cur ^ 1, k0 + 32);   // loads fly across MFMA
      const short* Asb = smem + cur * 4096;
      const short* Bsb = smem + 8192 + cur * 4096;
      s8v af[4], bfr[4];
      #pragma unroll
      for (int mi = 0; mi < 4; ++mi)
        af[mi] = *(const s8v*)&Asb[(wy + mi*16 + lm) * 32 + quad * 8];
      #pragma unroll
      for (int ni = 0; ni < 4; ++ni)
        bfr[ni] = *(const s8v*)&Bsb[(wx + ni*16 + lm) * 32 + quad * 8];
      #pragma unroll
      for (int mi = 0; mi < 4; ++mi)
        #pragma unroll
        for (int ni = 0; ni < 4; ++ni)
          acc[mi][ni] = __builtin_amdgcn_mfma_f32_16x16x32_bf16(af[mi], bfr[ni], acc[mi][ni], 0, 0, 0);
      __syncthreads();
      cur ^= 1;
    }
  } else {
    __shared__ short As[128 * LSTR];
    __shared__ short Bs[128 * LSTR];
    const int am = tid >> 1, ah = (tid & 1) * 16;

    s8v a_s0, a_s1;
    float a_f[16];
    s8v b_s0, b_s1;
    float b_f[16];
    short b_h[16];

    auto loadA = [&](int k0) {
      int kk = k0 + ah;
      size_t base;
      if (KSPLIT) base = zA + (size_t)(kk >> 8) * kstrideA + (size_t)(bm + am) * lda + (kk & 255);
      else base = zA + (size_t)(bm + am) * lda + kk;
      if constexpr (AMODE == 2) {
        const bf16* ap = (const bf16*)A + base;
        a_s0 = *(const s8v*)ap;
        a_s1 = *(const s8v*)(ap + 8);
      } else {
        if (fA) {
          const float4* src = (const float4*)((const float*)A + base);
          #pragma unroll
          for (int q = 0; q < 4; ++q) {
            float4 v = src[q];
            a_f[q*4] = v.x; a_f[q*4+1] = v.y; a_f[q*4+2] = v.z; a_f[q*4+3] = v.w;
          }
        } else {
          #pragma unroll
          for (int q = 0; q < 16; ++q) a_f[q] = ldw(A, base + q, 0);
        }
      }
    };
    auto storeA = [&]() {
      if constexpr (AMODE == 2) {
        *(s8v*)&As[am * LSTR + ah] = a_s0;
        *(s8v*)&As[am * LSTR + ah + 8] = a_s1;
      } else {
        short tmp[16];
        #pragma unroll
        for (int q = 0; q < 16; ++q) tmp[q] = f2bf(a_f[q]);
        s4v* dst = (s4v*)&As[am * LSTR + ah];
        #pragma unroll
        for (int q = 0; q < 4; ++q) dst[q] = *(s4v*)&tmp[q*4];
      }
    };
    auto loadB = [&](int k0) {
      if constexpr (TRB) {
        int n = tid >> 1, h = (tid & 1) * 16;
        size_t base = zB + (size_t)(bn + n) * ldb + k0 + h;
        if constexpr (BMODE == 2) {
          const bf16* bp = (const bf16*)B + base;
          b_s0 = *(const s8v*)bp;
          b_s1 = *(const s8v*)(bp + 8);
        } else {
          if (fB) {
            const float4* src = (const float4*)((const float*)B + base);
            #pragma unroll
            for (int q = 0; q < 4; ++q) {
              float4 v = src[q];
              b_f[q*4] = v.x; b_f[q*4+1] = v.y; b_f[q*4+2] = v.z; b_f[q*4+3] = v.w;
            }
          } else {
            #pragma unroll
            for (int q = 0; q < 16; ++q) b_f[q] = ldw(B, base + q, 0);
          }
        }
      } else {
        int n = tid & 127, kk2 = (tid >> 7) * 16;
        #pragma unroll
        for (int j = 0; j < 16; ++j) {
          size_t bi = zB + (size_t)(k0 + kk2 + j) * ldb + bn + n;
          if constexpr (BMODE == 2) b_h[j] = ((const short*)B)[bi];
          else b_f[j] = ldT<BMODE == 1>(B, bi, fB);
        }
      }
    };
    auto storeB = [&]() {
      if constexpr (TRB) {
        int n = tid >> 1, h = (tid & 1) * 16;
        if constexpr (BMODE == 2) {
          *(s8v*)&Bs[n * LSTR + h] = b_s0;
          *(s8v*)&Bs[n * LSTR + h + 8] = b_s1;
        } else {
          short tmp[16];
          #pragma unroll
          for (int q = 0; q < 16; ++q) tmp[q] = f2bf(b_f[q]);
          s4v* dst = (s4v*)&Bs[n * LSTR + h];
          #pragma unroll
          for (int q = 0; q < 4; ++q) dst[q] = *(s4v*)&tmp[q*4];
        }
      } else {
        int n = tid & 127, kk2 = (tid >> 7) * 16;
        short tmp[16];
        #pragma unroll
        for (int j = 0; j < 16; ++j) tmp[j] = (BMODE == 2) ? b_h[j] : f2bf(b_f[j]);
        s4v* dst = (s4v*)&Bs[n * LSTR + kk2];
        #pragma unroll
        for (int q = 0; q < 4; ++q) dst[q] = *(s4v*)&tmp[q*4];
      }
    };

    loadA(0);
    loadB(0);
    for (int k0 = 0; k0 < K; k0 += 32) {
      storeA();
      storeB();
      __syncthreads();
      if (k0 + 32 < K) { loadA(k0 + 32); loadB(k0 + 32); }
      s8v af[4], bfr[4];
      #pragma unroll
      for (int mi = 0; mi < 4; ++mi)
        af[mi] = *(const s8v*)&As[(wy + mi*16 + lm) * LSTR + quad * 8];
      #pragma unroll
      for (int ni = 0; ni < 4; ++ni)
        bfr[ni] = *(const s8v*)&Bs[(wx + ni*16 + lm) * LSTR + quad * 8];
      #pragma unroll
      for (int mi = 0; mi < 4; ++mi)
        #pragma unroll
        for (int ni = 0; ni < 4; ++ni)
          acc[mi][ni] = __builtin_amdgcn_mfma_f32_16x16x32_bf16(af[mi], bfr[ni], acc[mi][ni], 0, 0, 0);
      __syncthreads();
    }
  }

  const int actc = DOMAP ? (int)((amap >> (((bn + wx) >> 7) * 2)) & 3ULL) : ACT;
  #pragma unroll
  for (int mi = 0; mi < 4; ++mi) {
    #pragma unroll
    for (int r = 0; r < 4; ++r) {
      int row = bm + wy + mi*16 + quad*4 + r;
      #pragma unroll
      for (int ni = 0; ni < 4; ++ni) {
        int col = bn + wx + ni*16 + lm;
        float v = acc[mi][ni][r] * alpha;
        if (ACCUM) v += Cz[(size_t)row * ldc + col];
        if (bias) v += ldT<DYNBIAS>(bias, zBias + col, fBi);
        if (actc == 1) v = fmaxf(v, 0.f);
        else if (actc == 2) v = tanhf(v);
        else if (actc == 3) v = 1.f / (1.f + expf(-v));
        if (OUTBF16) Cz16[(size_t)row * ldc + col] = __float2bfloat16(v);
        else Cz[(size_t)row * ldc + col] = v;
      }
    }
  }
}

template<int AMODE, int BMODE, bool DYNBIAS, bool TRB, int ACT, bool ACCUM,
         bool KSPLIT = false, bool OUTBF16 = false, bool DOMAP = false>
static void gemm(hipStream_t s, const void* A, int lda, const void* B, int ldb, size_t offB,
                 const void* bias, size_t offBias, float* C, int ldc, int M, int N, int K,
                 float alpha, int ia, int ib, int ibias, const int* flags,
                 int batch = 1, size_t sA = 0, size_t sB = 0, size_t sBias = 0, size_t sC = 0,
                 size_t kstrideA = 0, unsigned long long amap = 0) {
  dim3 g(N / 128, M / 128, batch), b(256);
  gemm_k<AMODE, BMODE, DYNBIAS, TRB, ACT, ACCUM, KSPLIT, OUTBF16, DOMAP><<<g, b, 0, s>>>(
      A, lda, B, ldb, offB, bias, offBias, C, ldc, M, N, K, alpha, ia, ib, ibias, flags,
      sA, sB, sBias, sC, kstrideA, amap);
}

// ============ wide MFMA bf16 GEMM: 128x256 tile, 8 waves, GDB dbuf ============
// 48 KB LDS -> 3 blocks/CU x 8 waves = 24 waves/CU (vs 9 for the 128x128 GDB).
template<bool DYNBIAS, int ACT, bool OUTBF16, bool DOMAP>
__global__ __launch_bounds__(512) void gemmw_k(
    const short* __restrict__ A, int lda,
    const short* __restrict__ B, int ldb,
    const void* __restrict__ bias,
    float* __restrict__ C, int ldc,
    int M, int N, int K,
    int ibias, const int* __restrict__ flags,
    size_t sA, size_t sB, size_t sBias, size_t sC,
    unsigned long long amap)
{
  const int fBi = DYNBIAS ? flags[ibias] : 1;
  const short* Az = A + (size_t)blockIdx.z * sA;
  const short* Bz = B + (size_t)blockIdx.z * sB;
  const size_t zBias = (size_t)blockIdx.z * sBias;
  float* Cz = C + (size_t)blockIdx.z * sC;
  bf16* Cz16 = (bf16*)C + (size_t)blockIdx.z * sC;
  __shared__ short smem[2 * 4096 + 2 * 8192];   // A0|A1|B0|B1 = 48 KB
  const int tid = threadIdx.x;
  const int bm = blockIdx.y * 128, bn = blockIdx.x * 256;
  const int lane = tid & 63, wid = tid >> 6;        // 8 waves
  const int lm = lane & 15, quad = lane >> 4;
  const int wy = (wid >> 2) * 64, wx = (wid & 3) * 64;  // 2M x 4N wave grid
  const int srow = lane >> 2, scol = (lane & 3) * 8;
  f4v acc[4][4];
  #pragma unroll
  for (int i = 0; i < 4; ++i)
    #pragma unroll
    for (int j = 0; j < 4; ++j) acc[i][j] = (f4v)(0.f);

  auto stage = [&](int bsel, int k0) {
    short* Asb = smem + bsel * 4096;
    short* Bsb = smem + 8192 + bsel * 8192;
    int ra = wid * 16;                 // A: 1 gload/wave (16 rows x 32 k)
    gload16(Az + (size_t)(bm + ra + srow) * lda + k0 + scol, Asb + ra * 32);
    #pragma unroll
    for (int q = 0; q < 2; ++q) {      // B: 2 gloads/wave (32 rows)
      int rb = wid * 32 + q * 16;
      gload16(Bz + (size_t)(bn + rb + srow) * ldb + k0 + scol, Bsb + rb * 32);
    }
  };
  stage(0, 0);
  __syncthreads();
  int cur = 0;
  for (int k0 = 0; k0 < K; k0 += 32) {
    if (k0 + 32 < K) stage(cur ^ 1, k0 + 32);   // loads fly across MFMA
    const short* Asb = smem + cur * 4096;
    const short* Bsb = smem + 8192 + cur * 8192;
    s8v af[4], bfr[4];
    #pragma unroll
    for (int mi = 0; mi < 4; ++mi)
      af[mi] = *(const s8v*)&Asb[(wy + mi*16 + lm) * 32 + quad * 8];
    #pragma unroll
    for (int ni = 0; ni < 4; ++ni)
      bfr[ni] = *(const s8v*)&Bsb[(wx + ni*16 + lm) * 32 + quad * 8];
    #pragma unroll
    for (int mi = 0; mi < 4; ++mi)
      #pragma unroll
      for (int ni = 0; ni < 4; ++ni)
        acc[mi][ni] = __builtin_amdgcn_mfma_f32_16x16x32_bf16(af[mi], bfr[ni], acc[mi][ni], 0, 0, 0);
    __syncthreads();
    cur ^= 1;
  }

  const int actc = DOMAP ? (int)((amap >> (((bn + wx) >> 7) * 2)) & 3ULL) : ACT;
  #pragma unroll
  for (int mi = 0; mi < 4; ++mi) {
    #pragma unroll
    for (int r = 0; r < 4; ++r) {
      int row = bm + wy + mi*16 + quad*4 + r;
      #pragma unroll
      for (int ni = 0; ni < 4; ++ni) {
        int col = bn + wx + ni*16 + lm;
        float v = acc[mi][ni][r];
        if (bias) v += ldT<DYNBIAS>(bias, zBias + col, fBi);
        if (actc == 1) v = fmaxf(v, 0.f);
        else if (actc == 2) v = tanhf(v);
        else if (actc == 3) v = 1.f / (1.f + expf(-v));
        if (OUTBF16) Cz16[(size_t)row * ldc + col] = __float2bfloat16(v);
        else Cz[(size_t)row * ldc + col] = v;
      }
    }
  }
}

template<bool DYNBIAS, int ACT, bool OUTBF16, bool DOMAP = false>
static void gemmw(hipStream_t s, const short* A, int lda, const short* B, int ldb,
                  const void* bias, float* C, int ldc, int M, int N, int K,
                  int ibias, const int* flags, int batch = 1,
                  size_t sA = 0, size_t sB = 0, size_t sBias = 0, size_t sC = 0,
                  unsigned long long amap = 0) {
  dim3 g(N / 256, M / 128, batch), b(512);
  gemmw_k<DYNBIAS, ACT, OUTBF16, DOMAP><<<g, b, 0, s>>>(
      A, lda, B, ldb, bias, C, ldc, M, N, K, ibias, flags, sA, sB, sBias, sC, amap);
}

// ---------------- vectorized wave-per-row LayerNorm (+relu/sigmoid), bf16 in/out ----------------
template<int ACT, int W>
__global__ __launch_bounds__(256) void lnv_k(const short* __restrict__ X, const void* __restrict__ g,
                                             const void* __restrict__ be, short* __restrict__ Y,
                                             int ldx, int ldy,
                                             int ig, int ibe, const int* __restrict__ flags) {
  const int fG = flags[ig], fBe = flags[ibe];
  const int wid = threadIdx.x >> 6, lane = threadIdx.x & 63;
  const int row = blockIdx.x * 4 + wid;
  constexpr int V = W / 64;
  const short* x = X + (size_t)row * ldx + lane * V;
  float xv[V];
  if constexpr (V == 8) {
    s8v v = *(const s8v*)x;
    #pragma unroll
    for (int q = 0; q < 8; ++q) xv[q] = bf2f(v[q]);
  } else {
    s4v v = *(const s4v*)x;
    #pragma unroll
    for (int q = 0; q < 4; ++q) xv[q] = bf2f(v[q]);
  }
  float s1 = 0.f, s2 = 0.f;
  #pragma unroll
  for (int q = 0; q < V; ++q) { s1 += xv[q]; s2 += xv[q] * xv[q]; }
  #pragma unroll
  for (int o = 32; o > 0; o >>= 1) { s1 += __shfl_xor(s1, o); s2 += __shfl_xor(s2, o); }
  float mean = s1 * (1.f / W);
  float var = fmaxf(s2 * (1.f / W) - mean * mean, 0.f);
  float rstd = rsqrtf(var + 1e-5f);
  short yv[V];
  #pragma unroll
  for (int q = 0; q < V; ++q) {
    int i = lane * V + q;
    float v = (xv[q] - mean) * rstd * ldw(g, i, fG) + ldw(be, i, fBe);
    if (ACT == 1) v = fmaxf(v, 0.f);
    else if (ACT == 3) v = 1.f / (1.f + expf(-v));
    yv[q] = f2bf(v);
  }
  short* y = Y + (size_t)row * ldy + lane * V;
  if constexpr (V == 8) *(s8v*)y = *(s8v*)yv;
  else *(s4v*)y = *(s4v*)yv;
}

// ================= comm round =================
__global__ void statepart_k(const short* __restrict__ featsC, float* __restrict__ part) {
  int a = blockIdx.x, g = blockIdx.y, e = threadIdx.x;
  const short* p = featsC + (size_t)a * FSTR + ((size_t)g * 128) * E_ + e;
  float s = 0.f;
  for (int n = 0; n < 128; ++n) s += bf2f(p[(size_t)n * E_]);
  part[((size_t)a * 16 + g) * E_ + e] = s;
}

__global__ void statecomb_k(const float* __restrict__ part, const void* __restrict__ internal,
                            float* __restrict__ state, const int* __restrict__ flags) {
  int a = blockIdx.x, e = threadIdx.x;
  float s = 0.f;
  for (int g = 0; g < 16; ++g) s += part[((size_t)a * 16 + g) * E_ + e];
  state[a * E_ + e] = s * (1.f / NS_) + ldw(internal, (size_t)a * E_ + e, flags[46]);
}

__global__ void mvpart_k(const float* __restrict__ x, const void* __restrict__ W, int iw,
                         float* __restrict__ part, const int* __restrict__ flags) {
  int a = blockIdx.x, g = blockIdx.y, f = threadIdx.x;
  const int fW = flags[iw];
  float s = 0.f;
  size_t wb = (size_t)a * E_ * E_ + f;
  for (int e = g * 32; e < g * 32 + 32; ++e)
    s += x[a * E_ + e] * ldw(W, wb + (size_t)e * E_, fW);
  part[((size_t)a * 8 + g) * E_ + f] = s;
}

template<int ACT>
__global__ void mvcomb_k(const float* __restrict__ part, const void* __restrict__ b, int ibb,
                         float* __restrict__ y, const int* __restrict__ flags) {
  int a = blockIdx.x, f = threadIdx.x;
  float s = 0.f;
  for (int g = 0; g < 8; ++g) s += part[((size_t)a * 8 + g) * E_ + f];
  s += ldw(b, (size_t)a * E_ + f, flags[ibb]);
  if (ACT == 1) s = fmaxf(s, 0.f);
  else if (ACT == 2) s = tanhf(s);
  y[a * E_ + f] = s;
}

__device__ inline float wave_sum64(float v) {
  for (int o = 32; o > 0; o >>= 1) v += __shfl_down(v, o);
  return v;
}

__global__ __launch_bounds__(256) void qkvcomm_k(const float* __restrict__ msg,
                                                 const void* __restrict__ comm_w,
                                                 const void* __restrict__ in_w,
                                                 const void* __restrict__ in_b,
                                                 float* __restrict__ qkvc,
                                                 const int* __restrict__ flags) {
  const int fCW = flags[57], fIW = flags[38], fIB = flags[39];
  int gw = blockIdx.x * 4 + (threadIdx.x >> 6);
  int a = gw / 768, f = gw % 768;
  int lane = threadIdx.x & 63;
  float w[5]; float mx = -1e30f;
  for (int j = 0; j < 5; ++j) { w[j] = ldw(comm_w, a * 5 + j, fCW); mx = fmaxf(mx, w[j]); }
  float sum = 0.f;
  for (int j = 0; j < 5; ++j) { w[j] = __expf(w[j] - mx); sum += w[j]; }
  for (int j = 0; j < 5; ++j) w[j] /= sum;
  int others[4]; { int c = 0; for (int j = 0; j < 5; ++j) if (j != a) others[c++] = j; }
  int e0 = lane * 4;
  float4 wv;
  size_t b = (size_t)a * 768 * E_ + (size_t)f * E_ + e0;
  if (fIW) wv = *(const float4*)((const float*)in_w + b);
  else wv = make_float4(ldw(in_w, b, 0), ldw(in_w, b + 1, 0), ldw(in_w, b + 2, 0), ldw(in_w, b + 3, 0));
  float acc[4];
  #pragma unroll
  for (int t = 0; t < 4; ++t) {
    const float4 mv = *(const float4*)(msg + others[t] * E_ + e0);
    acc[t] = mv.x * wv.x + mv.y * wv.y + mv.z * wv.z + mv.w * wv.w;
  }
  #pragma unroll
  for (int t = 0; t < 4; ++t) acc[t] = wave_sum64(acc[t]);
  if (lane == 0) {
    float bb = ldw(in_b, (size_t)a * 768 + f, fIB);
    #pragma unroll
    for (int t = 0; t < 4; ++t)
      qkvc[((size_t)a * 4 + t) * 768 + f] = acc[t] * w[others[t]] + bb;
  }
}

__global__ __launch_bounds__(256) void attn4_k(const float* __restrict__ qkvc,
                                               float* __restrict__ obar) {
  int a = blockIdx.x, tid = threadIdx.x;
  __shared__ float qkv[4][768];
  __shared__ float attw[4][16];
  for (int i = tid; i < 4 * 768; i += 256) qkv[i / 768][i % 768] = qkvc[(size_t)a * 4 * 768 + i];
  __syncthreads();
  if (tid < 16) {
    int h = tid >> 2, t = tid & 3;
    float sc[4]; float mx = -1e30f;
    for (int t2 = 0; t2 < 4; ++t2) {
      float s = 0.f;
      for (int d = 0; d < 64; ++d) s += qkv[t][h * 64 + d] * qkv[t2][256 + h * 64 + d];
      sc[t2] = s * 0.125f; mx = fmaxf(mx, sc[t2]);
    }
    float ss = 0.f;
    for (int t2 = 0; t2 < 4; ++t2) { sc[t2] = __expf(sc[t2] - mx); ss += sc[t2]; }
    for (int t2 = 0; t2 < 4; ++t2) attw[h][t * 4 + t2] = sc[t2] / ss;
  }
  __syncthreads();
  {
    int e = tid, h = e >> 6;
    float s = 0.f;
    for (int t = 0; t < 4; ++t)
      for (int t2 = 0; t2 < 4; ++t2)
        s += attw[h][t * 4 + t2] * qkv[t2][512 + e];
    obar[a * E_ + e] = s * 0.25f;
  }
}

__global__ __launch_bounds__(256) void combproj_k(const float* __restrict__ obar,
                                                  const void* __restrict__ ow,
                                                  const void* __restrict__ ob,
                                                  const void* __restrict__ internal,
                                                  float* __restrict__ comb,
                                                  const int* __restrict__ flags) {
  const int fOW = flags[40], fOB = flags[41], fIN = flags[46];
  int gw = blockIdx.x * 4 + (threadIdx.x >> 6);
  int a = gw >> 8, f = gw & 255;
  int lane = threadIdx.x & 63;
  int e0 = lane * 4;
  float4 wv;
  size_t b = (size_t)a * E_ * E_ + (size_t)f * E_ + e0;
  if (fOW) wv = *(const float4*)((const float*)ow + b);
  else wv = make_float4(ldw(ow, b, 0), ldw(ow, b + 1, 0), ldw(ow, b + 2, 0), ldw(ow, b + 3, 0));
  const float4 ov = *(const float4*)(obar + a * E_ + e0);
  float s = wave_sum64(ov.x * wv.x + ov.y * wv.y + ov.z * wv.z + ov.w * wv.w);
  if (lane == 0)
    comb[a * E_ + f] = ldw(internal, (size_t)a * E_ + f, fIN) + s + ldw(ob, (size_t)a * E_ + f, fOB);
}

__global__ __launch_bounds__(256) void ckb_k(const float* __restrict__ ck,
                                             const void* __restrict__ in_w,
                                             const void* __restrict__ in_b,
                                             float* __restrict__ ckb,
                                             const int* __restrict__ flags) {
  const int fW = flags[47], fB = flags[48];
  int gw = blockIdx.x * 4 + (threadIdx.x >> 6);
  int a = gw / 768, f = gw % 768;
  int lane = threadIdx.x & 63;
  int e0 = lane * 4;
  float4 wv;
  size_t b = (size_t)a * 768 * E_ + (size_t)f * E_ + e0;
  if (fW) wv = *(const float4*)((const float*)in_w + b);
  else wv = make_float4(ldw(in_w, b, 0), ldw(in_w, b + 1, 0), ldw(in_w, b + 2, 0), ldw(in_w, b + 3, 0));
  const float4 cv = *(const float4*)(ck + a * E_ + e0);
  float s = wave_sum64(cv.x * wv.x + cv.y * wv.y + cv.z * wv.z + cv.w * wv.w);
  if (lane == 0) ckb[(size_t)a * 768 + f] = s + ldw(in_b, (size_t)a * 768 + f, fB);
}

// ======== MFMA class-block attention (qkv_all is bf16) ========
#define LS 136
__device__ inline void stage64x128(const short* __restrict__ qkv, const int* __restrict__ myidx,
                                   int row0, int n, int ho, short* dst) {
  int t = threadIdx.x;
  int r = t >> 2, c0 = (t & 3) * 32;
  int rr = row0 + r;
  s8v v0 = (s8v)(short)0, v1 = v0, v2 = v0, v3 = v0;
  if (rr < n) {
    const s8v* s = (const s8v*)(qkv + (size_t)myidx[rr] * 768 + ho + c0);
    v0 = s[0]; v1 = s[1]; v2 = s[2]; v3 = s[3];
  }
  s8v* d = (s8v*)&dst[r * LS + c0];
  d[0] = v0; d[1] = v1; d[2] = v2; d[3] = v3;
}

__global__ __launch_bounds__(256) void attn_stats_k(
    const short* __restrict__ qkv_all, const int* __restrict__ idx,
    const int* __restrict__ cnt, const int* __restrict__ cstart,
    float* __restrict__ ml)
{
  int c = blockIdx.x, z = blockIdx.z, a = z >> 1, h = z & 1;
  int n = cnt[c];
  int r0 = blockIdx.y * 64;
  if (r0 >= n) return;
  const short* qkv = qkv_all + (size_t)a * NS_ * 768;
  const int* myidx = idx + c * NS_;
  __shared__ short Qs[64 * LS];
  __shared__ short Ks[64 * LS];
  __shared__ float Mw[4][64], Lw[4][64];
  int tid = threadIdx.x, lane = tid & 63, wid = tid >> 6;
  int lm = lane & 15, quad = lane >> 4;
  stage64x128(qkv, myidx, r0, n, h * 128, Qs);
  float m_run[16], l_run[16];
  #pragma unroll
  for (int i = 0; i < 16; ++i) { m_run[i] = -3e38f; l_run[i] = 0.f; }
  for (int j0 = 0; j0 < n; j0 += 64) {
    __syncthreads();
    stage64x128(qkv, myidx, j0, n, 256 + h * 128, Ks);
    __syncthreads();
    f4v acc[4];
    #pragma unroll
    for (int mi = 0; mi < 4; ++mi) acc[mi] = (f4v)(0.f);
    #pragma unroll
    for (int kc = 0; kc < 4; ++kc) {
      s8v bfr = *(const s8v*)&Ks[(wid * 16 + lm) * LS + kc * 32 + quad * 8];
      #pragma unroll
      for (int mi = 0; mi < 4; ++mi) {
        s8v af = *(const s8v*)&Qs[(mi * 16 + lm) * LS + kc * 32 + quad * 8];
        acc[mi] = __builtin_amdgcn_mfma_f32_16x16x32_bf16(af, bfr, acc[mi], 0, 0, 0);
      }
    }
    int col = j0 + wid * 16 + lm;
    bool cv = col < n;
    #pragma unroll
    for (int mi = 0; mi < 4; ++mi) {
      #pragma unroll
      for (int r = 0; r < 4; ++r) {
        float s = cv ? acc[mi][r] * QSCALE : -3e38f;
        float m = s;
        m = fmaxf(m, __shfl_xor(m, 1));
        m = fmaxf(m, __shfl_xor(m, 2));
        m = fmaxf(m, __shfl_xor(m, 4));
        m = fmaxf(m, __shfl_xor(m, 8));
        float p = cv ? __expf(s - m) : 0.f;
        p += __shfl_xor(p, 1); p += __shfl_xor(p, 2);
        p += __shfl_xor(p, 4); p += __shfl_xor(p, 8);
        int ri = mi * 4 + r;
        float mo = m_run[ri];
        float mn = fmaxf(mo, m);
        l_run[ri] = l_run[ri] * __expf(mo - mn) + p * __expf(m - mn);
        m_run[ri] = mn;
      }
    }
  }
  if (lm == 0) {
    #pragma unroll
    for (int mi = 0; mi < 4; ++mi)
      #pragma unroll
      for (int r = 0; r < 4; ++r) {
        int row = mi * 16 + quad * 4 + r;
        Mw[wid][row] = m_run[mi * 4 + r];
        Lw[wid][row] = l_run[mi * 4 + r];
      }
  }
  __syncthreads();
  if (tid < 64 && r0 + tid < n) {
    float m = fmaxf(fmaxf(Mw[0][tid], Mw[1][tid]), fmaxf(Mw[2][tid], Mw[3][tid]));
    float l = Lw[0][tid] * __expf(Mw[0][tid] - m) + Lw[1][tid] * __expf(Mw[1][tid] - m)
            + Lw[2][tid] * __expf(Mw[2][tid] - m) + Lw[3][tid] * __expf(Mw[3][tid] - m);
    size_t p = (size_t)z * NS_ + cstart[c] + r0 + tid;
    ml[p * 2] = m; ml[p * 2 + 1] = l;
  }
}

__global__ __launch_bounds__(256) void attn_colsum_k(
    const short* __restrict__ qkv_all, const int* __restrict__ idx,
    const int* __restrict__ cnt, const int* __restrict__ cstart,
    const float* __restrict__ ml, float* __restrict__ colsum)
{
  int c = blockIdx.x, z = blockIdx.z, a = z >> 1, h = z & 1;
  int n = cnt[c];
  int j0 = blockIdx.y * 64;
  if (j0 >= n) return;
  const short* qkv = qkv_all + (size_t)a * NS_ * 768;
  const int* myidx = idx + c * NS_;
  __shared__ short Qs[64 * LS];
  __shared__ short Ks[64 * LS];
  __shared__ float Msm[64], Lsm[64];
  int tid = threadIdx.x, lane = tid & 63, wid = tid >> 6;
  int lm = lane & 15, quad = lane >> 4;
  stage64x128(qkv, myidx, j0, n, 256 + h * 128, Ks);
  float ca = 0.f;
  for (int i0 = 0; i0 < n; i0 += 64) {
    __syncthreads();
    stage64x128(qkv, myidx, i0, n, h * 128, Qs);
    if (tid < 64) {
      int gi = i0 + tid;
      if (gi < n) {
        size_t p = (size_t)z * NS_ + cstart[c] + gi;
        Msm[tid] = ml[p * 2]; Lsm[tid] = ml[p * 2 + 1];
      } else { Msm[tid] = 0.f; Lsm[tid] = 1.f; }
    }
    __syncthreads();
    f4v acc[4];
    #pragma unroll
    for (int mi = 0; mi < 4; ++mi) acc[mi] = (f4v)(0.f);
    #pragma unroll
    for (int kc = 0; kc < 4; ++kc) {
      s8v bfr = *(const s8v*)&Ks[(wid * 16 + lm) * LS + kc * 32 + quad * 8];
      #pragma unroll
      for (int mi = 0; mi < 4; ++mi) {
        s8v af = *(const s8v*)&Qs[(mi * 16 + lm) * LS + kc * 32 + quad * 8];
        acc[mi] = __builtin_amdgcn_mfma_f32_16x16x32_bf16(af, bfr, acc[mi], 0, 0, 0);
      }
    }
    #pragma unroll
    for (int mi = 0; mi < 4; ++mi) {
      #pragma unroll
      for (int r = 0; r < 4; ++r) {
        int lrow = mi * 16 + quad * 4 + r;
        int gi = i0 + lrow;
        if (gi < n) {
          float m = Msm[lrow];
          float invl = 1.f / Lsm[lrow];
          ca += __expf(acc[mi][r] * QSCALE - m) * invl;
        }
      }
    }
  }
  ca += __shfl_xor(ca, 16);
  ca += __shfl_xor(ca, 32);
  int col = j0 + wid * 16 + lm;
  if (quad == 0 && col < n)
    colsum[(size_t)z * NS_ + cstart[c] + col] = ca;
}

// ---- proto V-aggregation ----
#define PCH 8
__global__ __launch_bounds__(1024) void proto_reduce_k(
    const short* __restrict__ qkv_all, const int* __restrict__ idx,
    const int* __restrict__ cnt, const int* __restrict__ cstart,
    const float* __restrict__ colsum, float* __restrict__ proto_pre) {
  int c = blockIdx.x, a = blockIdx.y;
  int n = cnt[c];
  int tid = threadIdx.x, lane = tid & 63, wid = tid >> 6;
  int h = lane >> 5;
  int e0 = lane * 4;
  const short* qkv = qkv_all + (size_t)a * NS_ * 768 + 512;
  const float* csum = colsum + (size_t)(a * 2 + h) * NS_ + cstart[c];
  const int* myidx = idx + c * NS_;
  float a0 = 0.f, a1 = 0.f, a2 = 0.f, a3 = 0.f;
  for (int k = wid; k < n; k += 16) {
    float w = csum[k];
    const s4v v = *(const s4v*)(qkv + (size_t)myidx[k] * 768 + e0);
    a0 += w * bf2f(v[0]); a1 += w * bf2f(v[1]);
    a2 += w * bf2f(v[2]); a3 += w * bf2f(v[3]);
  }
  __shared__ float red[16][E_];
  *(float4*)&red[wid][e0] = make_float4(a0, a1, a2, a3);
  __syncthreads();
  if (tid < E_) {
    float s = 0.f;
    #pragma unroll
    for (int wdx = 0; wdx < 16; ++wdx) s += red[wdx][tid];
    proto_pre[((size_t)a * NWAY_ + c) * E_ + tid] = (n > 0) ? s / (float)n : 0.f;
  }
}

__global__ void proto_outproj_k(const float* __restrict__ proto_pre, const void* __restrict__ ow,
                                const void* __restrict__ ob, const int* __restrict__ cnt,
                                float* __restrict__ protos_all, float* __restrict__ pnorm,
                                const int* __restrict__ flags) {
  int c = blockIdx.x, a = blockIdx.y, e = threadIdx.x;
  const int fW = flags[49], fB = flags[50];
  __shared__ float pp[E_];
  __shared__ float r2[E_];
  pp[e] = proto_pre[((size_t)a * NWAY_ + c) * E_ + e];
  __syncthreads();
  size_t wb = (size_t)a * E_ * E_ + (size_t)e * E_;
  float s = 0.f;
  for (int k = 0; k < E_; ++k) s += pp[k] * ldw(ow, wb + k, fW);
  float v = s + ldw(ob, (size_t)a * E_ + e, fB);
  float vm = (cnt[c] > 0) ? v : 0.f;
  protos_all[((size_t)a * NWAY_ + c) * E_ + e] = vm;
  r2[e] = vm * vm;
  __syncthreads();
  for (int o = 128; o > 0; o >>= 1) { if (e < o) r2[e] += r2[e + o]; __syncthreads(); }
  if (e == 0) pnorm[a * NWAY_ + c] = r2[0];
}

// ---- biascat2[a][0:256] = ck@w1[256:512] + b1; [256:512] = 0 ----
__global__ void bias2_k(const float* __restrict__ ck, const void* __restrict__ w1,
                        const void* __restrict__ b1, float* __restrict__ biascat2,
                        const int* __restrict__ flags) {
  const int fW = flags[51], fB = flags[52];
  int a = blockIdx.x, n = threadIdx.x;
  __shared__ float c[E_];
  c[n] = ck[a * E_ + n]; __syncthreads();
  size_t wbase = (size_t)a * 2 * E_ * E_ + (size_t)E_ * E_ + n;
  float s = 0.f;
  for (int k = 0; k < E_; ++k) s += c[k] * ldw(w1, wbase + (size_t)k * E_, fW);
  biascat2[(size_t)a * 512 + n] = s + ldw(b1, (size_t)a * E_ + n, fB);
  biascat2[(size_t)a * 512 + 256 + n] = 0.f;
}

// ---- fusion combine: fh1 = relu(sum_a U[a][:,256:512] + f_b1); 8 rows/block ----
__global__ __launch_bounds__(256) void fcomb2_k(const short* __restrict__ U, const void* __restrict__ b1,
                                                short* __restrict__ fh1, const int* __restrict__ flags) {
  const int fB = flags[59];
  int r = threadIdx.x >> 5;
  int n0 = (threadIdx.x & 31) * 8;
  int i = blockIdx.x * 8 + r;
  float acc[8];
  #pragma unroll
  for (int q = 0; q < 8; ++q) acc[q] = ldw(b1, n0 + q, fB);
  #pragma unroll
  for (int a = 0; a < A_; ++a) {
    s8v v = *(const s8v*)(U + ((size_t)a * NQ_ + i) * 512 + 256 + n0);
    #pragma unroll
    for (int q = 0; q < 8; ++q) acc[q] += bf2f(v[q]);
  }
  short yv[8];
  #pragma unroll
  for (int q = 0; q < 8; ++q) yv[q] = f2bf(fmaxf(acc[q], 0.f));
  *(s8v*)(fh1 + (size_t)i * 256 + n0) = *(s8v*)yv;
}

// ---------------- epilogues: thread-per-row, no cross-lane reductions ----------------
__global__ __launch_bounds__(256) void logits2_k(const short* __restrict__ fqbase,
                                                 const float* __restrict__ protos_all,
                                                 const float* __restrict__ pnorm,
                                                 const bf16* __restrict__ c2all,
                                                 const void* __restrict__ w3,
                                                 const void* __restrict__ b3,
                                                 float* __restrict__ out,
                                                 const int* __restrict__ flags) {
  const int fW = flags[55], fB = flags[56];
  const int a = blockIdx.y;
  const int i = blockIdx.x * 256 + threadIdx.x;
  __shared__ float ps[NWAY_][E_];
  __shared__ float w3s[128];
  for (int t = threadIdx.x; t < NWAY_ * E_; t += 256)
    ps[t >> 8][t & 255] = protos_all[(size_t)a * NWAY_ * E_ + t];
  if (threadIdx.x < 128) w3s[threadIdx.x] = ldw(w3, (size_t)a * 128 + threadIdx.x, fW);
  __syncthreads();
  const short* fq = fqbase + (size_t)a * FSTR + (size_t)i * E_;
  float qq = 0.f, dt0 = 0.f, dt1 = 0.f, dt2 = 0.f, dt3 = 0.f, dt4 = 0.f;
  for (int e0 = 0; e0 < E_; e0 += 8) {
    s8v v = *(const s8v*)(fq + e0);
    #pragma unroll
    for (int q = 0; q < 8; ++q) {
      float x = bf2f(v[q]); int e = e0 + q;
      qq += x * x;
      dt0 += x * ps[0][e]; dt1 += x * ps[1][e]; dt2 += x * ps[2][e];
      dt3 += x * ps[3][e]; dt4 += x * ps[4][e];
    }
  }
  const short* c2 = (const short*)c2all + ((size_t)a * NQ_ + i) * 128;
  float conf = 0.f;
  for (int e0 = 0; e0 < 128; e0 += 8) {
    s8v v = *(const s8v*)(c2 + e0);
    #pragma unroll
    for (int q = 0; q < 8; ++q) conf += bf2f(v[q]) * w3s[e0 + q];
  }
  conf += ldw(b3, a, fB);
  float dts[5] = { dt0, dt1, dt2, dt3, dt4 };
  float* o = out + ((size_t)a * NQ_ + i) * NWAY_;
  #pragma unroll
  for (int c = 0; c < NWAY_; ++c) {
    float pp = pnorm[a * NWAY_ + c];
    float d2 = fmaxf(qq + pp - 2.f * dts[c], 1e-12f);
    o[c] = -sqrtf(d2) + 0.1f * conf;
  }
}

__global__ __launch_bounds__(256) void fused2_k(const float* __restrict__ h2, const void* __restrict__ w3,
                                                const void* __restrict__ b3, float* __restrict__ out,
                                                const int* __restrict__ flags) {
  const int fW = flags[62], fB = flags[63];
  int i = blockIdx.x * 256 + threadIdx.x;
  __shared__ float ws[128];
  if (threadIdx.x < 128) ws[threadIdx.x] = ldw(w3, threadIdx.x, fW);
  __syncthreads();
  const float* h = h2 + (size_t)i * 128;
  float s = 0.f;
  for (int e = 0; e < 128; e += 4) {
    float4 v = *(const float4*)(h + e);
    s += v.x * ws[e] + v.y * ws[e + 1] + v.z * ws[e + 2] + v.w * ws[e + 3];
  }
  out[i] = s + ldw(b3, 0, fB);
}

// ---------------- host ----------------
extern "C" void kernel_launch(void* const* d_in, const int* in_sizes, int n_in,
                              void* d_out, int out_size, void* d_ws, size_t ws_size,
                              hipStream_t stream) {
  (void)out_size; (void)ws_size;
  #define P(i) ((const void*)d_in[i])
  const int* support_y = (const int*)d_in[1];
  float* out = (float*)d_out;

  int* flags = (int*)d_ws;
  char* base = (char*)d_ws + 256;
  short* featsC = (short*)base;                        // bf16 [A][NM][E]
  char* R = base + (size_t)A_ * FSTR * 2;
  short* t1cat   = (short*)R;                          // [NM][2304] bf16
  short* qkv_all = (short*)R;                          // [A][NS][768] bf16
  short* U       = (short*)(R + (size_t)15728640);     // [A][NQ][512] bf16
  short* fh1     = (short*)R;                          // [NQ][256] bf16
  float* fh2     = (float*)(R + (size_t)8388608);      // [NQ][128] f32
  char* XCR = R + (size_t)57671680;
  short* XC   = (short*)XCR;
  short* tmp2 = (short*)XCR;
  short* b4   = (short*)(XCR + (size_t)NM_ * 256 * 2);
  short* clsC2_all = (short*)XCR;
  char* S = XCR + (size_t)10485760;
  float* state      = (float*)S;
  float* msg        = state + A_ * E_;
  float* ck         = msg + A_ * E_;
  float* protos_all = ck + A_ * E_;
  float* biascat2   = protos_all + A_ * NWAY_ * E_;
  float* ml         = biascat2 + A_ * 512;
  float* colsum     = ml + (size_t)A_ * 2 * NS_ * 2;
  float* proto_pre  = colsum + (size_t)A_ * 2 * NS_;
  int*   idx        = (int*)(proto_pre + A_ * NWAY_ * E_);
  int*   cnt        = idx + NWAY_ * NS_;
  int*   cstart     = cnt + NWAY_;
  float* statepart  = (float*)(cstart + NWAY_ + 3);
  float* mvp        = statepart + A_ * 16 * E_;
  float* qkvc       = mvp + A_ * 8 * E_;
  float* obar       = qkvc + A_ * 4 * 768;
  float* comb       = obar + A_ * E_;
  float* hh         = comb + A_ * E_;
  float* ckb        = hh + A_ * E_;
  float* ppart      = ckb + A_ * 768;                  // reused as pnorm (25 floats)
  float* bcat       = ppart + (size_t)A_ * NWAY_ * PCH * E_;
  short* Wcat       = (short*)(bcat + 2304);
  short* Bcat2      = Wcat + (size_t)2304 * 512;
  short* W2         = Bcat2 + (size_t)A_ * 512 * 256;  // converted TRB bf16 weights (~3.7 MB)

  const short* fq_base = featsC + (size_t)NS_ * E_;

  Ptrs ps;
  for (int i = 0; i < 64; ++i) {
    ps.p[i] = (i < n_in) ? d_in[i] : nullptr;
    ps.sz[i] = (i < n_in) ? in_sizes[i] : 0;
  }
  probe_k<<<64, 64, 0, stream>>>(ps, flags);
  classidx_k<<<1, 256, 0, stream>>>(support_y, idx, cnt, cstart);
  xcopy_k<<<(NM_ * 512 / 4) / 256, 256, 0, stream>>>(P(0), P(2), XC, flags);
  wcat_k<<<dim3(9, 512), 256, 0, stream>>>(ps, Wcat, bcat, flags);
  wcls_k<<<dim3(512, A_), 256, 0, stream>>>(P(51), P(58), Bcat2, flags);
  wconv_k<<<dim3(960, 9), 256, 0, stream>>>(ps, W2, flags);

  // ---- FE: mega layer-1 GEMM (N = 2304), per-tile act map; WIDE 8-wave path ----
  gemmw<false, 0, true, true>(stream, XC, 512, Wcat, 512, bcat, (float*)t1cat, 2304,
                              NM_, 2304, 512, -1, flags, 1, 0, 0, 0, 0, 0x555555000ULL);
  lnv_k<1, 512><<<NM_ / 4, 256, 0, stream>>>(t1cat, P(6), P(7), t1cat, 2304, 2304, 6, 7, flags);
  gemm<2, 2, true, true, 0, false, false, true>(stream, t1cat, 2304, W2 + 0, 512, 0, P(9), 0,
                                                (float*)tmp2, 256, NM_, 256, 512, 1.f, -1, -1, 9, flags);
  lnv_k<1, 256><<<NM_ / 4, 256, 0, stream>>>(tmp2, P(10), P(11), featsC, 256, 256, 10, 11, flags);
  lnv_k<1, 256><<<NM_ / 4, 256, 0, stream>>>(t1cat + 512, P(14), P(15), t1cat + 512, 2304, 2304, 14, 15, flags);
  gemm<2, 2, true, true, 2, false, false, true>(stream, t1cat + 512, 2304, W2 + 131072, 256, 0, P(17), 0,
                                                (float*)(featsC + FSTR), 256, NM_, 256, 256, 1.f, -1, -1, 17, flags);
  gemm<2, 2, true, true, 0, false, false, true>(stream, t1cat + 768, 2304, W2 + 196608, 768, 0, P(21), 0,
                                                (float*)tmp2, 256, NM_, 256, 768, 1.f, -1, -1, 21, flags);
  lnv_k<1, 256><<<NM_ / 4, 256, 0, stream>>>(tmp2, P(22), P(23), featsC + 2 * FSTR, 256, 256, 22, 23, flags);
  gemm<2, 2, true, true, 0, false, false, true>(stream, t1cat + 1536, 2304, W2 + 393216, 256, 0, P(27), 0,
                                                (float*)tmp2, 256, NM_, 256, 256, 1.f, -1, -1, 27, flags);
  lnv_k<3, 256><<<NM_ / 4, 256, 0, stream>>>(tmp2, P(28), P(29), featsC + 3 * FSTR, 256, 256, 28, 29, flags);
  gemm<2, 2, true, true, 1, false, false, true>(stream, t1cat + 1792, 2304, W2 + 458752, 512, 0, P(33), 0,
                                                (float*)b4, 256, NM_, 256, 512, 1.f, -1, -1, 33, flags);
  gemm<2, 2, true, true, 0, false, false, true>(stream, b4, 256, W2 + 589824, 256, 0, P(35), 0,
                                                (float*)(featsC + 4 * FSTR), 256, NM_, 256, 256, 1.f, -1, -1, 35, flags);

  // ---- comm round ----
  statepart_k<<<dim3(A_, 16), 256, 0, stream>>>(featsC, statepart);
  statecomb_k<<<A_, 256, 0, stream>>>(statepart, P(46), state, flags);
  mvpart_k<<<dim3(A_, 8), 256, 0, stream>>>(state, P(36), 36, mvp, flags);
  mvcomb_k<2><<<A_, 256, 0, stream>>>(mvp, P(37), 37, msg, flags);
  qkvcomm_k<<<A_ * 768 / 4, 256, 0, stream>>>(msg, P(57), P(38), P(39), qkvc, flags);
  attn4_k<<<A_, 256, 0, stream>>>(qkvc, obar);
  combproj_k<<<A_ * E_ / 4, 256, 0, stream>>>(obar, P(40), P(41), P(46), comb, flags);
  mvpart_k<<<dim3(A_, 8), 256, 0, stream>>>(comb, P(42), 42, mvp, flags);
  mvcomb_k<1><<<A_, 256, 0, stream>>>(mvp, P(43), 43, hh, flags);
  mvpart_k<<<dim3(A_, 8), 256, 0, stream>>>(hh, P(44), 44, mvp, flags);
  mvcomb_k<0><<<A_, 256, 0, stream>>>(mvp, P(45), 45, ck, flags);

  // ---- batched prototype attention (ck folded into qkv bias; qkv bf16, WIDE path) ----
  ckb_k<<<A_ * 768 / 4, 256, 0, stream>>>(ck, P(47), P(48), ckb, flags);
  gemmw<false, 0, true>(stream, featsC, 256, W2 + 851968, 256, ckb, (float*)qkv_all, 768,
                        NS_, 768, 256, -1, flags,
                        A_, FSTR, (size_t)768 * 256, (size_t)768, (size_t)NS_ * 768);
  {
    dim3 g(NWAY_, NS_ / 64, A_ * 2);
    attn_stats_k<<<g, 256, 0, stream>>>(qkv_all, idx, cnt, cstart, ml);
    attn_colsum_k<<<g, 256, 0, stream>>>(qkv_all, idx, cnt, cstart, ml, colsum);
  }
  proto_reduce_k<<<dim3(NWAY_, A_), 1024, 0, stream>>>(qkv_all, idx, cnt, cstart, colsum, proto_pre);
  proto_outproj_k<<<dim3(NWAY_, A_), 256, 0, stream>>>(proto_pre, P(49), P(50), cnt, protos_all, ppart, flags);
  bias2_k<<<A_, 256, 0, stream>>>(ck, P(51), P(52), biascat2, flags);

  // ---- combined cls1 + fusion-partial GEMM (WIDE 8-wave path) ----
  gemmw<false, 0, true, true>(stream, fq_base, 256, Bcat2, 256, biascat2, (float*)U, 512,
                              NQ_, 512, 256, -1, flags,
                              A_, FSTR, (size_t)512 * 256, (size_t)512, (size_t)NQ_ * 512, 0x5ULL);
  fcomb2_k<<<NQ_ / 8, 256, 0, stream>>>(U, P(59), fh1, flags);

  // ---- cls2 + logits ----
  gemm<2, 2, true, true, 1, false, false, true>(stream, U, 512, W2 + 655360, 256, 0,
                                     P(54), 0, (float*)clsC2_all, 128, NQ_, 128, 256, 1.f, -1, -1, 54, flags,
                                     A_, (size_t)NQ_ * 512, (size_t)128 * 256, (size_t)128, (size_t)NQ_ * 128);
  logits2_k<<<dim3(NQ_ / 256, A_), 256, 0, stream>>>(fq_base, protos_all, ppart,
                                                     (const bf16*)clsC2_all, P(55), P(56), out, flags);

  // ---- fusion layer-2 + output ----
  gemm<2, 2, true, true, 1, false>(stream, fh1, 256, W2 + 819200, 256, 0, P(61), 0, fh2, 128,
                                   NQ_, 128, 256, 1.f, -1, -1, 61, flags);
  fused2_k<<<NQ_ / 256, 256, 0, stream>>>(fh2, P(62), P(63), out + (size_t)A_ * NQ_ * NWAY_, flags);
}

// Round 9
// 821.470 us; speedup vs baseline: 1.0249x; 1.0249x over previous
//
#include <hip/hip_runtime.h>
#include <hip/hip_bf16.h>

typedef __hip_bfloat16 bf16;
typedef short s8v __attribute__((ext_vector_type(8)));
typedef short s4v __attribute__((ext_vector_type(4)));
typedef float f4v __attribute__((ext_vector_type(4)));

#define A_  5
#define D_  512
#define E_  256
#define NS_ 2048
#define NQ_ 8192
#define NM_ 10240
#define NWAY_ 5
#define QSCALE 0.088388347648318447f
#define FSTR ((size_t)NM_ * E_)

__device__ inline float ldw(const void* p, size_t i, int f32) {
  return f32 ? ((const float*)p)[i] : __bfloat162float(((const bf16*)p)[i]);
}
template<bool DYN>
__device__ inline float ldT(const void* p, size_t i, int f32) {
  if (DYN) return ldw(p, i, f32);
  return ((const float*)p)[i];
}

__device__ inline short f2bf(float v) {
  union { float f; unsigned u; } x; x.f = v;
  unsigned r = x.u + 0x7fffu + ((x.u >> 16) & 1u);
  return (short)(r >> 16);
}
__device__ inline float bf2f(short s) {
  union { unsigned u; float f; } x; x.u = ((unsigned)(unsigned short)s) << 16;
  return x.f;
}

// async global->LDS, 16B per lane; lds dest = base + lane*16 (wave-uniform base)
__device__ __forceinline__ void gload16(const void* g, void* l) {
  __builtin_amdgcn_global_load_lds(
      (const __attribute__((address_space(1))) unsigned int*)g,
      (__attribute__((address_space(3))) unsigned int*)l, 16, 0, 0);
}

struct Ptrs { const void* p[64]; int sz[64]; };

__global__ void probe_k(Ptrs P, int* flags) {
  int b = blockIdx.x, lane = threadIdx.x;
  if (b == 1 || b == 3) { if (lane == 0) flags[b] = 0; return; }
  const bf16* t = (const bf16*)P.p[b];
  int n = P.sz[b];
  int K = (n >> 1) < 64 ? (n >> 1) : 64;
  bool big = false, eNZ = false, oNZ = false;
  if (lane < K) {
    float e = __bfloat162float(t[2 * lane]);
    float o = __bfloat162float(t[2 * lane + 1]);
    big = !(fabsf(e) <= 1e3f);
    eNZ = (e != 0.f); oNZ = (o != 0.f);
  }
  unsigned long long bb = __ballot(big), eb = __ballot(eNZ), ob = __ballot(oNZ);
  if (lane == 0) flags[b] = (bb != 0ull || (eb == 0ull && ob != 0ull)) ? 1 : 0;
}

__global__ void classidx_k(const int* __restrict__ y, int* __restrict__ idx,
                           int* __restrict__ cnt, int* __restrict__ cstart) {
  __shared__ int sc[NWAY_];
  int tid = threadIdx.x;
  if (tid < NWAY_) sc[tid] = 0;
  __syncthreads();
  for (int i = tid; i < NS_; i += 256) {
    int c = y[i];
    int pos = atomicAdd(&sc[c], 1);
    idx[c * NS_ + pos] = i;
  }
  __syncthreads();
  if (tid < NWAY_) cnt[tid] = sc[tid];
  if (tid == 0) { int s = 0; for (int q = 0; q < NWAY_; ++q) { cstart[q] = s; s += sc[q]; } }
}

__global__ void xcopy_k(const void* __restrict__ sx, const void* __restrict__ qx,
                        short* __restrict__ XC, const int* __restrict__ flags) {
  size_t i = ((size_t)blockIdx.x * 256 + threadIdx.x) * 4;
  const size_t SN = (size_t)NS_ * 512;
  if (i < SN) {
    int f = flags[0];
    #pragma unroll
    for (int q = 0; q < 4; ++q) XC[i + q] = f2bf(ldw(sx, i + q, f));
  } else {
    int f = flags[2];
    size_t j = i - SN;
    #pragma unroll
    for (int q = 0; q < 4; ++q) XC[i + q] = f2bf(ldw(qx, j + q, f));
  }
}

// ---- concat 5 layer-1 weights into Wcat[2304][512] bf16 (TRB layout) + bias cat ----
__global__ void wcat_k(Ptrs P, short* __restrict__ Wcat, float* __restrict__ bcat,
                       const int* __restrict__ flags) {
  int n = blockIdx.x * 256 + threadIdx.x;
  int k = blockIdx.y;
  int iw, ib, nl, Nloc;
  if (n < 512)       { iw = 4;  ib = 5;  nl = n;        Nloc = 512; }
  else if (n < 768)  { iw = 12; ib = 13; nl = n - 512;  Nloc = 256; }
  else if (n < 1536) { iw = 18; ib = 19; nl = n - 768;  Nloc = 768; }
  else if (n < 1792) { iw = 24; ib = 25; nl = n - 1536; Nloc = 256; }
  else               { iw = 30; ib = 31; nl = n - 1792; Nloc = 512; }
  Wcat[(size_t)n * 512 + k] = f2bf(ldw(P.p[iw], (size_t)k * Nloc + nl, flags[iw]));
  if (k == 0) bcat[n] = ldw(P.p[ib], nl, flags[ib]);
}

// ---- Bcat2[a][n][k] bf16 ----
__global__ void wcls_k(const void* __restrict__ cw1, const void* __restrict__ fw1,
                       short* __restrict__ B2, const int* __restrict__ flags) {
  int n = blockIdx.x, a = blockIdx.y, k = threadIdx.x;
  float v;
  if (n < 256) v = ldw(cw1, ((size_t)a * 512 + k) * 256 + n, flags[51]);
  else v = ldw(fw1, ((size_t)(a * 256 + k)) * 256 + (n - 256), flags[58]);
  B2[((size_t)a * 512 + n) * 256 + k] = f2bf(v);
}

// ---- convert/transpose remaining weights to bf16 TRB [N][K] into W2 ----
__global__ void wconv_k(Ptrs P, short* __restrict__ W2, const int* __restrict__ flags) {
  const int id = blockIdx.y;
  int src, K, N; size_t off; int tr, batch;
  switch (id) {
    case 0: src = 8;  K = 512; N = 256; off = 0;      tr = 1; batch = 1;  break;
    case 1: src = 16; K = 256; N = 256; off = 131072; tr = 1; batch = 1;  break;
    case 2: src = 20; K = 768; N = 256; off = 196608; tr = 1; batch = 1;  break;
    case 3: src = 26; K = 256; N = 256; off = 393216; tr = 1; batch = 1;  break;
    case 4: src = 32; K = 512; N = 256; off = 458752; tr = 1; batch = 1;  break;
    case 5: src = 34; K = 256; N = 256; off = 589824; tr = 1; batch = 1;  break;
    case 6: src = 53; K = 256; N = 128; off = 655360; tr = 1; batch = A_; break;
    case 7: src = 60; K = 256; N = 128; off = 819200; tr = 1; batch = 1;  break;
    default: src = 47; K = 256; N = 768; off = 851968; tr = 0; batch = A_; break;
  }
  size_t tot = (size_t)batch * K * N;
  size_t e0 = ((size_t)blockIdx.x * 256 + threadIdx.x) * 4;
  if (e0 >= tot) return;
  const void* sp = P.p[src];
  int f = flags[src];
  if (!tr) {
    #pragma unroll
    for (int q = 0; q < 4; ++q) W2[off + e0 + q] = f2bf(ldw(sp, e0 + q, f));
  } else {
    size_t kn = (size_t)K * N;
    #pragma unroll
    for (int q = 0; q < 4; ++q) {
      size_t e = e0 + q;
      int b = (int)(e / kn);
      int r = (int)(e % kn);
      int n = r / K, k = r % K;
      W2[off + e] = f2bf(ldw(sp, ((size_t)b * K + k) * N + n, f));
    }
  }
}

// ============ MFMA bf16 GEMM (128x128, 4-wave) ============
#define LSTR 40
template<int AMODE, int BMODE, bool DYNBIAS, bool TRB, int ACT, bool ACCUM,
         bool KSPLIT = false, bool OUTBF16 = false, bool DOMAP = false>
__global__ __launch_bounds__(256) void gemm_k(
    const void* __restrict__ A, int lda,
    const void* __restrict__ B, int ldb, size_t offB,
    const void* __restrict__ bias, size_t offBias,
    float* __restrict__ C, int ldc,
    int M, int N, int K, float alpha,
    int ia, int ib, int ibias, const int* __restrict__ flags,
    size_t sA, size_t sB, size_t sBias, size_t sC, size_t kstrideA,
    unsigned long long amap)
{
  constexpr bool GDB = (AMODE == 2) && (BMODE == 2) && TRB && !KSPLIT;
  const int fA = (AMODE == 1) ? flags[ia] : 1;
  const int fB = (BMODE == 1) ? flags[ib] : 1;
  const int fBi = DYNBIAS ? flags[ibias] : 1;
  const size_t zA = (size_t)blockIdx.z * sA;
  const size_t zB = offB + (size_t)blockIdx.z * sB;
  const size_t zBias = offBias + (size_t)blockIdx.z * sBias;
  float* Cz = C + (size_t)blockIdx.z * sC;
  bf16* Cz16 = (bf16*)C + (size_t)blockIdx.z * sC;
  const int tid = threadIdx.x;
  const int bm = blockIdx.y * 128, bn = blockIdx.x * 128;
  const int lane = tid & 63, wid = tid >> 6;
  const int lm = lane & 15, quad = lane >> 4;
  const int wy = (wid >> 1) * 64, wx = (wid & 1) * 64;
  f4v acc[4][4];
  #pragma unroll
  for (int i = 0; i < 4; ++i)
    #pragma unroll
    for (int j = 0; j < 4; ++j) acc[i][j] = (f4v)(0.f);

  if constexpr (GDB) {
    __shared__ short smem[4 * 128 * 32];   // 32 KB: [A0|A1|B0|B1]
    const int srow = lane >> 2, scol = (lane & 3) * 8;
    const short* Azs = (const short*)A + zA;
    const short* Bzs = (const short*)B + zB;
    auto stage = [&](int bsel, int k0) {
      short* Asb = smem + bsel * 4096;
      short* Bsb = smem + 8192 + bsel * 4096;
      #pragma unroll
      for (int q = 0; q < 2; ++q) {
        int rb = (wid * 2 + q) * 16;
        gload16(Azs + (size_t)(bm + rb + srow) * lda + k0 + scol, Asb + rb * 32);
        gload16(Bzs + (size_t)(bn + rb + srow) * ldb + k0 + scol, Bsb + rb * 32);
      }
    };
    stage(0, 0);
    __syncthreads();
    int cur = 0;
    for (int k0 = 0; k0 < K; k0 += 32) {
      if (k0 + 32 < K) stage(cur ^ 1, k0 + 32);   // loads fly across MFMA
      const short* Asb = smem + cur * 4096;
      const short* Bsb = smem + 8192 + cur * 4096;
      s8v af[4], bfr[4];
      #pragma unroll
      for (int mi = 0; mi < 4; ++mi)
        af[mi] = *(const s8v*)&Asb[(wy + mi*16 + lm) * 32 + quad * 8];
      #pragma unroll
      for (int ni = 0; ni < 4; ++ni)
        bfr[ni] = *(const s8v*)&Bsb[(wx + ni*16 + lm) * 32 + quad * 8];
      #pragma unroll
      for (int mi = 0; mi < 4; ++mi)
        #pragma unroll
        for (int ni = 0; ni < 4; ++ni)
          acc[mi][ni] = __builtin_amdgcn_mfma_f32_16x16x32_bf16(af[mi], bfr[ni], acc[mi][ni], 0, 0, 0);
      __syncthreads();
      cur ^= 1;
    }
  } else {
    __shared__ short As[128 * LSTR];
    __shared__ short Bs[128 * LSTR];
    const int am = tid >> 1, ah = (tid & 1) * 16;

    s8v a_s0, a_s1;
    float a_f[16];
    s8v b_s0, b_s1;
    float b_f[16];
    short b_h[16];

    auto loadA = [&](int k0) {
      int kk = k0 + ah;
      size_t base;
      if (KSPLIT) base = zA + (size_t)(kk >> 8) * kstrideA + (size_t)(bm + am) * lda + (kk & 255);
      else base = zA + (size_t)(bm + am) * lda + kk;
      if constexpr (AMODE == 2) {
        const bf16* ap = (const bf16*)A + base;
        a_s0 = *(const s8v*)ap;
        a_s1 = *(const s8v*)(ap + 8);
      } else {
        if (fA) {
          const float4* src = (const float4*)((const float*)A + base);
          #pragma unroll
          for (int q = 0; q < 4; ++q) {
            float4 v = src[q];
            a_f[q*4] = v.x; a_f[q*4+1] = v.y; a_f[q*4+2] = v.z; a_f[q*4+3] = v.w;
          }
        } else {
          #pragma unroll
          for (int q = 0; q < 16; ++q) a_f[q] = ldw(A, base + q, 0);
        }
      }
    };
    auto storeA = [&]() {
      if constexpr (AMODE == 2) {
        *(s8v*)&As[am * LSTR + ah] = a_s0;
        *(s8v*)&As[am * LSTR + ah + 8] = a_s1;
      } else {
        short tmp[16];
        #pragma unroll
        for (int q = 0; q < 16; ++q) tmp[q] = f2bf(a_f[q]);
        s4v* dst = (s4v*)&As[am * LSTR + ah];
        #pragma unroll
        for (int q = 0; q < 4; ++q) dst[q] = *(s4v*)&tmp[q*4];
      }
    };
    auto loadB = [&](int k0) {
      if constexpr (TRB) {
        int n = tid >> 1, h = (tid & 1) * 16;
        size_t base = zB + (size_t)(bn + n) * ldb + k0 + h;
        if constexpr (BMODE == 2) {
          const bf16* bp = (const bf16*)B + base;
          b_s0 = *(const s8v*)bp;
          b_s1 = *(const s8v*)(bp + 8);
        } else {
          if (fB) {
            const float4* src = (const float4*)((const float*)B + base);
            #pragma unroll
            for (int q = 0; q < 4; ++q) {
              float4 v = src[q];
              b_f[q*4] = v.x; b_f[q*4+1] = v.y; b_f[q*4+2] = v.z; b_f[q*4+3] = v.w;
            }
          } else {
            #pragma unroll
            for (int q = 0; q < 16; ++q) b_f[q] = ldw(B, base + q, 0);
          }
        }
      } else {
        int n = tid & 127, kk2 = (tid >> 7) * 16;
        #pragma unroll
        for (int j = 0; j < 16; ++j) {
          size_t bi = zB + (size_t)(k0 + kk2 + j) * ldb + bn + n;
          if constexpr (BMODE == 2) b_h[j] = ((const short*)B)[bi];
          else b_f[j] = ldT<BMODE == 1>(B, bi, fB);
        }
      }
    };
    auto storeB = [&]() {
      if constexpr (TRB) {
        int n = tid >> 1, h = (tid & 1) * 16;
        if constexpr (BMODE == 2) {
          *(s8v*)&Bs[n * LSTR + h] = b_s0;
          *(s8v*)&Bs[n * LSTR + h + 8] = b_s1;
        } else {
          short tmp[16];
          #pragma unroll
          for (int q = 0; q < 16; ++q) tmp[q] = f2bf(b_f[q]);
          s4v* dst = (s4v*)&Bs[n * LSTR + h];
          #pragma unroll
          for (int q = 0; q < 4; ++q) dst[q] = *(s4v*)&tmp[q*4];
        }
      } else {
        int n = tid & 127, kk2 = (tid >> 7) * 16;
        short tmp[16];
        #pragma unroll
        for (int j = 0; j < 16; ++j) tmp[j] = (BMODE == 2) ? b_h[j] : f2bf(b_f[j]);
        s4v* dst = (s4v*)&Bs[n * LSTR + kk2];
        #pragma unroll
        for (int q = 0; q < 4; ++q) dst[q] = *(s4v*)&tmp[q*4];
      }
    };

    loadA(0);
    loadB(0);
    for (int k0 = 0; k0 < K; k0 += 32) {
      storeA();
      storeB();
      __syncthreads();
      if (k0 + 32 < K) { loadA(k0 + 32); loadB(k0 + 32); }
      s8v af[4], bfr[4];
      #pragma unroll
      for (int mi = 0; mi < 4; ++mi)
        af[mi] = *(const s8v*)&As[(wy + mi*16 + lm) * LSTR + quad * 8];
      #pragma unroll
      for (int ni = 0; ni < 4; ++ni)
        bfr[ni] = *(const s8v*)&Bs[(wx + ni*16 + lm) * LSTR + quad * 8];
      #pragma unroll
      for (int mi = 0; mi < 4; ++mi)
        #pragma unroll
        for (int ni = 0; ni < 4; ++ni)
          acc[mi][ni] = __builtin_amdgcn_mfma_f32_16x16x32_bf16(af[mi], bfr[ni], acc[mi][ni], 0, 0, 0);
      __syncthreads();
    }
  }

  const int actc = DOMAP ? (int)((amap >> (((bn + wx) >> 7) * 2)) & 3ULL) : ACT;
  #pragma unroll
  for (int mi = 0; mi < 4; ++mi) {
    #pragma unroll
    for (int r = 0; r < 4; ++r) {
      int row = bm + wy + mi*16 + quad*4 + r;
      #pragma unroll
      for (int ni = 0; ni < 4; ++ni) {
        int col = bn + wx + ni*16 + lm;
        float v = acc[mi][ni][r] * alpha;
        if (ACCUM) v += Cz[(size_t)row * ldc + col];
        if (bias) v += ldT<DYNBIAS>(bias, zBias + col, fBi);
        if (actc == 1) v = fmaxf(v, 0.f);
        else if (actc == 2) v = tanhf(v);
        else if (actc == 3) v = 1.f / (1.f + expf(-v));
        if (OUTBF16) Cz16[(size_t)row * ldc + col] = __float2bfloat16(v);
        else Cz[(size_t)row * ldc + col] = v;
      }
    }
  }
}

template<int AMODE, int BMODE, bool DYNBIAS, bool TRB, int ACT, bool ACCUM,
         bool KSPLIT = false, bool OUTBF16 = false, bool DOMAP = false>
static void gemm(hipStream_t s, const void* A, int lda, const void* B, int ldb, size_t offB,
                 const void* bias, size_t offBias, float* C, int ldc, int M, int N, int K,
                 float alpha, int ia, int ib, int ibias, const int* flags,
                 int batch = 1, size_t sA = 0, size_t sB = 0, size_t sBias = 0, size_t sC = 0,
                 size_t kstrideA = 0, unsigned long long amap = 0) {
  dim3 g(N / 128, M / 128, batch), b(256);
  gemm_k<AMODE, BMODE, DYNBIAS, TRB, ACT, ACCUM, KSPLIT, OUTBF16, DOMAP><<<g, b, 0, s>>>(
      A, lda, B, ldb, offB, bias, offBias, C, ldc, M, N, K, alpha, ia, ib, ibias, flags,
      sA, sB, sBias, sC, kstrideA, amap);
}

// ============ deep-pipelined MFMA bf16 GEMM: 128x128, 3-buffer, counted vmcnt ============
// T4 (m218/AITER): never drain vmcnt to 0 in the loop. stage(j+2) in flight across the
// barrier; s_waitcnt vmcnt(8) leaves tiles j+1,j+2 outstanding => tile j landed.
// Race discipline: buf[(j+2)%3] disjoint from buf[j%3] (read) and buf[(j+1)%3] (pending);
// post-MFMA raw barrier prevents iter j+1's stage (writes buf[j%3]) racing iter-j readers.
__global__ __launch_bounds__(256) void gemmd_k(
    const short* __restrict__ A, int lda,
    const short* __restrict__ B, int ldb,
    const float* __restrict__ bias,
    bf16* __restrict__ C, int ldc,
    int K, unsigned long long amap)
{
  __shared__ short smem[6 * 4096];   // A0 A1 A2 | B0 B1 B2 = 48 KB
  const int tid = threadIdx.x;
  const int bm = blockIdx.y * 128, bn = blockIdx.x * 128;
  const int lane = tid & 63, wid = tid >> 6;
  const int lm = lane & 15, quad = lane >> 4;
  const int wy = (wid >> 1) * 64, wx = (wid & 1) * 64;
  const int srow = lane >> 2, scol = (lane & 3) * 8;
  f4v acc[4][4];
  #pragma unroll
  for (int i = 0; i < 4; ++i)
    #pragma unroll
    for (int j = 0; j < 4; ++j) acc[i][j] = (f4v)(0.f);

  auto stage = [&](int bsel, int k0) {
    short* Asb = smem + bsel * 4096;
    short* Bsb = smem + 12288 + bsel * 4096;
    #pragma unroll
    for (int q = 0; q < 2; ++q) {
      int rb = (wid * 2 + q) * 16;
      gload16(A + (size_t)(bm + rb + srow) * lda + k0 + scol, Asb + rb * 32);
      gload16(B + (size_t)(bn + rb + srow) * ldb + k0 + scol, Bsb + rb * 32);
    }
  };

  const int NT = K >> 5;
  stage(0, 0);
  if (NT > 1) stage(1, 32);
  int bsel = 0;
  for (int j = 0; j < NT; ++j) {
    if (j + 2 < NT) stage((j + 2) % 3, (j + 2) * 32);
    // wait for tile j only: tiles j+1, j+2 (<= 8 gloads/wave) may stay in flight
    asm volatile("s_waitcnt vmcnt(8)" ::: "memory");
    __builtin_amdgcn_sched_barrier(0);
    __builtin_amdgcn_s_barrier();
    const short* Asb = smem + bsel * 4096;
    const short* Bsb = smem + 12288 + bsel * 4096;
    s8v af[4], bfr[4];
    #pragma unroll
    for (int mi = 0; mi < 4; ++mi)
      af[mi] = *(const s8v*)&Asb[(wy + mi*16 + lm) * 32 + quad * 8];
    #pragma unroll
    for (int ni = 0; ni < 4; ++ni)
      bfr[ni] = *(const s8v*)&Bsb[(wx + ni*16 + lm) * 32 + quad * 8];
    #pragma unroll
    for (int mi = 0; mi < 4; ++mi)
      #pragma unroll
      for (int ni = 0; ni < 4; ++ni)
        acc[mi][ni] = __builtin_amdgcn_mfma_f32_16x16x32_bf16(af[mi], bfr[ni], acc[mi][ni], 0, 0, 0);
    // protect buf[j%3] before iter j+1 stages into it (writes buf[(j+3)%3] == buf[j%3])
    __builtin_amdgcn_s_barrier();
    bsel = (bsel + 1 == 3) ? 0 : bsel + 1;
  }

  const int actc = (int)((amap >> ((bn >> 7) * 2)) & 3ULL);
  #pragma unroll
  for (int mi = 0; mi < 4; ++mi) {
    #pragma unroll
    for (int r = 0; r < 4; ++r) {
      int row = bm + wy + mi*16 + quad*4 + r;
      #pragma unroll
      for (int ni = 0; ni < 4; ++ni) {
        int col = bn + wx + ni*16 + lm;
        float v = acc[mi][ni][r] + bias[col];
        if (actc == 1) v = fmaxf(v, 0.f);
        else if (actc == 2) v = tanhf(v);
        else if (actc == 3) v = 1.f / (1.f + expf(-v));
        C[(size_t)row * ldc + col] = __float2bfloat16(v);
      }
    }
  }
}

// ---------------- vectorized wave-per-row LayerNorm (+relu/sigmoid), bf16 in/out ----------------
template<int ACT, int W>
__global__ __launch_bounds__(256) void lnv_k(const short* __restrict__ X, const void* __restrict__ g,
                                             const void* __restrict__ be, short* __restrict__ Y,
                                             int ldx, int ldy,
                                             int ig, int ibe, const int* __restrict__ flags) {
  const int fG = flags[ig], fBe = flags[ibe];
  const int wid = threadIdx.x >> 6, lane = threadIdx.x & 63;
  const int row = blockIdx.x * 4 + wid;
  constexpr int V = W / 64;
  const short* x = X + (size_t)row * ldx + lane * V;
  float xv[V];
  if constexpr (V == 8) {
    s8v v = *(const s8v*)x;
    #pragma unroll
    for (int q = 0; q < 8; ++q) xv[q] = bf2f(v[q]);
  } else {
    s4v v = *(const s4v*)x;
    #pragma unroll
    for (int q = 0; q < 4; ++q) xv[q] = bf2f(v[q]);
  }
  float s1 = 0.f, s2 = 0.f;
  #pragma unroll
  for (int q = 0; q < V; ++q) { s1 += xv[q]; s2 += xv[q] * xv[q]; }
  #pragma unroll
  for (int o = 32; o > 0; o >>= 1) { s1 += __shfl_xor(s1, o); s2 += __shfl_xor(s2, o); }
  float mean = s1 * (1.f / W);
  float var = fmaxf(s2 * (1.f / W) - mean * mean, 0.f);
  float rstd = rsqrtf(var + 1e-5f);
  short yv[V];
  #pragma unroll
  for (int q = 0; q < V; ++q) {
    int i = lane * V + q;
    float v = (xv[q] - mean) * rstd * ldw(g, i, fG) + ldw(be, i, fBe);
    if (ACT == 1) v = fmaxf(v, 0.f);
    else if (ACT == 3) v = 1.f / (1.f + expf(-v));
    yv[q] = f2bf(v);
  }
  short* y = Y + (size_t)row * ldy + lane * V;
  if constexpr (V == 8) *(s8v*)y = *(s8v*)yv;
  else *(s4v*)y = *(s4v*)yv;
}

// ================= comm round =================
__global__ void statepart_k(const short* __restrict__ featsC, float* __restrict__ part) {
  int a = blockIdx.x, g = blockIdx.y, e = threadIdx.x;
  const short* p = featsC + (size_t)a * FSTR + ((size_t)g * 128) * E_ + e;
  float s = 0.f;
  for (int n = 0; n < 128; ++n) s += bf2f(p[(size_t)n * E_]);
  part[((size_t)a * 16 + g) * E_ + e] = s;
}

__global__ void statecomb_k(const float* __restrict__ part, const void* __restrict__ internal,
                            float* __restrict__ state, const int* __restrict__ flags) {
  int a = blockIdx.x, e = threadIdx.x;
  float s = 0.f;
  for (int g = 0; g < 16; ++g) s += part[((size_t)a * 16 + g) * E_ + e];
  state[a * E_ + e] = s * (1.f / NS_) + ldw(internal, (size_t)a * E_ + e, flags[46]);
}

__global__ void mvpart_k(const float* __restrict__ x, const void* __restrict__ W, int iw,
                         float* __restrict__ part, const int* __restrict__ flags) {
  int a = blockIdx.x, g = blockIdx.y, f = threadIdx.x;
  const int fW = flags[iw];
  float s = 0.f;
  size_t wb = (size_t)a * E_ * E_ + f;
  for (int e = g * 32; e < g * 32 + 32; ++e)
    s += x[a * E_ + e] * ldw(W, wb + (size_t)e * E_, fW);
  part[((size_t)a * 8 + g) * E_ + f] = s;
}

template<int ACT>
__global__ void mvcomb_k(const float* __restrict__ part, const void* __restrict__ b, int ibb,
                         float* __restrict__ y, const int* __restrict__ flags) {
  int a = blockIdx.x, f = threadIdx.x;
  float s = 0.f;
  for (int g = 0; g < 8; ++g) s += part[((size_t)a * 8 + g) * E_ + f];
  s += ldw(b, (size_t)a * E_ + f, flags[ibb]);
  if (ACT == 1) s = fmaxf(s, 0.f);
  else if (ACT == 2) s = tanhf(s);
  y[a * E_ + f] = s;
}

__device__ inline float wave_sum64(float v) {
  for (int o = 32; o > 0; o >>= 1) v += __shfl_down(v, o);
  return v;
}

__global__ __launch_bounds__(256) void qkvcomm_k(const float* __restrict__ msg,
                                                 const void* __restrict__ comm_w,
                                                 const void* __restrict__ in_w,
                                                 const void* __restrict__ in_b,
                                                 float* __restrict__ qkvc,
                                                 const int* __restrict__ flags) {
  const int fCW = flags[57], fIW = flags[38], fIB = flags[39];
  int gw = blockIdx.x * 4 + (threadIdx.x >> 6);
  int a = gw / 768, f = gw % 768;
  int lane = threadIdx.x & 63;
  float w[5]; float mx = -1e30f;
  for (int j = 0; j < 5; ++j) { w[j] = ldw(comm_w, a * 5 + j, fCW); mx = fmaxf(mx, w[j]); }
  float sum = 0.f;
  for (int j = 0; j < 5; ++j) { w[j] = __expf(w[j] - mx); sum += w[j]; }
  for (int j = 0; j < 5; ++j) w[j] /= sum;
  int others[4]; { int c = 0; for (int j = 0; j < 5; ++j) if (j != a) others[c++] = j; }
  int e0 = lane * 4;
  float4 wv;
  size_t b = (size_t)a * 768 * E_ + (size_t)f * E_ + e0;
  if (fIW) wv = *(const float4*)((const float*)in_w + b);
  else wv = make_float4(ldw(in_w, b, 0), ldw(in_w, b + 1, 0), ldw(in_w, b + 2, 0), ldw(in_w, b + 3, 0));
  float acc[4];
  #pragma unroll
  for (int t = 0; t < 4; ++t) {
    const float4 mv = *(const float4*)(msg + others[t] * E_ + e0);
    acc[t] = mv.x * wv.x + mv.y * wv.y + mv.z * wv.z + mv.w * wv.w;
  }
  #pragma unroll
  for (int t = 0; t < 4; ++t) acc[t] = wave_sum64(acc[t]);
  if (lane == 0) {
    float bb = ldw(in_b, (size_t)a * 768 + f, fIB);
    #pragma unroll
    for (int t = 0; t < 4; ++t)
      qkvc[((size_t)a * 4 + t) * 768 + f] = acc[t] * w[others[t]] + bb;
  }
}

__global__ __launch_bounds__(256) void attn4_k(const float* __restrict__ qkvc,
                                               float* __restrict__ obar) {
  int a = blockIdx.x, tid = threadIdx.x;
  __shared__ float qkv[4][768];
  __shared__ float attw[4][16];
  for (int i = tid; i < 4 * 768; i += 256) qkv[i / 768][i % 768] = qkvc[(size_t)a * 4 * 768 + i];
  __syncthreads();
  if (tid < 16) {
    int h = tid >> 2, t = tid & 3;
    float sc[4]; float mx = -1e30f;
    for (int t2 = 0; t2 < 4; ++t2) {
      float s = 0.f;
      for (int d = 0; d < 64; ++d) s += qkv[t][h * 64 + d] * qkv[t2][256 + h * 64 + d];
      sc[t2] = s * 0.125f; mx = fmaxf(mx, sc[t2]);
    }
    float ss = 0.f;
    for (int t2 = 0; t2 < 4; ++t2) { sc[t2] = __expf(sc[t2] - mx); ss += sc[t2]; }
    for (int t2 = 0; t2 < 4; ++t2) attw[h][t * 4 + t2] = sc[t2] / ss;
  }
  __syncthreads();
  {
    int e = tid, h = e >> 6;
    float s = 0.f;
    for (int t = 0; t < 4; ++t)
      for (int t2 = 0; t2 < 4; ++t2)
        s += attw[h][t * 4 + t2] * qkv[t2][512 + e];
    obar[a * E_ + e] = s * 0.25f;
  }
}

__global__ __launch_bounds__(256) void combproj_k(const float* __restrict__ obar,
                                                  const void* __restrict__ ow,
                                                  const void* __restrict__ ob,
                                                  const void* __restrict__ internal,
                                                  float* __restrict__ comb,
                                                  const int* __restrict__ flags) {
  const int fOW = flags[40], fOB = flags[41], fIN = flags[46];
  int gw = blockIdx.x * 4 + (threadIdx.x >> 6);
  int a = gw >> 8, f = gw & 255;
  int lane = threadIdx.x & 63;
  int e0 = lane * 4;
  float4 wv;
  size_t b = (size_t)a * E_ * E_ + (size_t)f * E_ + e0;
  if (fOW) wv = *(const float4*)((const float*)ow + b);
  else wv = make_float4(ldw(ow, b, 0), ldw(ow, b + 1, 0), ldw(ow, b + 2, 0), ldw(ow, b + 3, 0));
  const float4 ov = *(const float4*)(obar + a * E_ + e0);
  float s = wave_sum64(ov.x * wv.x + ov.y * wv.y + ov.z * wv.z + ov.w * wv.w);
  if (lane == 0)
    comb[a * E_ + f] = ldw(internal, (size_t)a * E_ + f, fIN) + s + ldw(ob, (size_t)a * E_ + f, fOB);
}

__global__ __launch_bounds__(256) void ckb_k(const float* __restrict__ ck,
                                             const void* __restrict__ in_w,
                                             const void* __restrict__ in_b,
                                             float* __restrict__ ckb,
                                             const int* __restrict__ flags) {
  const int fW = flags[47], fB = flags[48];
  int gw = blockIdx.x * 4 + (threadIdx.x >> 6);
  int a = gw / 768, f = gw % 768;
  int lane = threadIdx.x & 63;
  int e0 = lane * 4;
  float4 wv;
  size_t b = (size_t)a * 768 * E_ + (size_t)f * E_ + e0;
  if (fW) wv = *(const float4*)((const float*)in_w + b);
  else wv = make_float4(ldw(in_w, b, 0), ldw(in_w, b + 1, 0), ldw(in_w, b + 2, 0), ldw(in_w, b + 3, 0));
  const float4 cv = *(const float4*)(ck + a * E_ + e0);
  float s = wave_sum64(cv.x * wv.x + cv.y * wv.y + cv.z * wv.z + cv.w * wv.w);
  if (lane == 0) ckb[(size_t)a * 768 + f] = s + ldw(in_b, (size_t)a * 768 + f, fB);
}

// ======== MFMA class-block attention (qkv_all is bf16) ========
#define LS 136
__device__ inline void stage64x128(const short* __restrict__ qkv, const int* __restrict__ myidx,
                                   int row0, int n, int ho, short* dst) {
  int t = threadIdx.x;
  int r = t >> 2, c0 = (t & 3) * 32;
  int rr = row0 + r;
  s8v v0 = (s8v)(short)0, v1 = v0, v2 = v0, v3 = v0;
  if (rr < n) {
    const s8v* s = (const s8v*)(qkv + (size_t)myidx[rr] * 768 + ho + c0);
    v0 = s[0]; v1 = s[1]; v2 = s[2]; v3 = s[3];
  }
  s8v* d = (s8v*)&dst[r * LS + c0];
  d[0] = v0; d[1] = v1; d[2] = v2; d[3] = v3;
}

__global__ __launch_bounds__(256) void attn_stats_k(
    const short* __restrict__ qkv_all, const int* __restrict__ idx,
    const int* __restrict__ cnt, const int* __restrict__ cstart,
    float* __restrict__ ml)
{
  int c = blockIdx.x, z = blockIdx.z, a = z >> 1, h = z & 1;
  int n = cnt[c];
  int r0 = blockIdx.y * 64;
  if (r0 >= n) return;
  const short* qkv = qkv_all + (size_t)a * NS_ * 768;
  const int* myidx = idx + c * NS_;
  __shared__ short Qs[64 * LS];
  __shared__ short Ks[64 * LS];
  __shared__ float Mw[4][64], Lw[4][64];
  int tid = threadIdx.x, lane = tid & 63, wid = tid >> 6;
  int lm = lane & 15, quad = lane >> 4;
  stage64x128(qkv, myidx, r0, n, h * 128, Qs);
  float m_run[16], l_run[16];
  #pragma unroll
  for (int i = 0; i < 16; ++i) { m_run[i] = -3e38f; l_run[i] = 0.f; }
  for (int j0 = 0; j0 < n; j0 += 64) {
    __syncthreads();
    stage64x128(qkv, myidx, j0, n, 256 + h * 128, Ks);
    __syncthreads();
    f4v acc[4];
    #pragma unroll
    for (int mi = 0; mi < 4; ++mi) acc[mi] = (f4v)(0.f);
    #pragma unroll
    for (int kc = 0; kc < 4; ++kc) {
      s8v bfr = *(const s8v*)&Ks[(wid * 16 + lm) * LS + kc * 32 + quad * 8];
      #pragma unroll
      for (int mi = 0; mi < 4; ++mi) {
        s8v af = *(const s8v*)&Qs[(mi * 16 + lm) * LS + kc * 32 + quad * 8];
        acc[mi] = __builtin_amdgcn_mfma_f32_16x16x32_bf16(af, bfr, acc[mi], 0, 0, 0);
      }
    }
    int col = j0 + wid * 16 + lm;
    bool cv = col < n;
    #pragma unroll
    for (int mi = 0; mi < 4; ++mi) {
      #pragma unroll
      for (int r = 0; r < 4; ++r) {
        float s = cv ? acc[mi][r] * QSCALE : -3e38f;
        float m = s;
        m = fmaxf(m, __shfl_xor(m, 1));
        m = fmaxf(m, __shfl_xor(m, 2));
        m = fmaxf(m, __shfl_xor(m, 4));
        m = fmaxf(m, __shfl_xor(m, 8));
        float p = cv ? __expf(s - m) : 0.f;
        p += __shfl_xor(p, 1); p += __shfl_xor(p, 2);
        p += __shfl_xor(p, 4); p += __shfl_xor(p, 8);
        int ri = mi * 4 + r;
        float mo = m_run[ri];
        float mn = fmaxf(mo, m);
        l_run[ri] = l_run[ri] * __expf(mo - mn) + p * __expf(m - mn);
        m_run[ri] = mn;
      }
    }
  }
  if (lm == 0) {
    #pragma unroll
    for (int mi = 0; mi < 4; ++mi)
      #pragma unroll
      for (int r = 0; r < 4; ++r) {
        int row = mi * 16 + quad * 4 + r;
        Mw[wid][row] = m_run[mi * 4 + r];
        Lw[wid][row] = l_run[mi * 4 + r];
      }
  }
  __syncthreads();
  if (tid < 64 && r0 + tid < n) {
    float m = fmaxf(fmaxf(Mw[0][tid], Mw[1][tid]), fmaxf(Mw[2][tid], Mw[3][tid]));
    float l = Lw[0][tid] * __expf(Mw[0][tid] - m) + Lw[1][tid] * __expf(Mw[1][tid] - m)
            + Lw[2][tid] * __expf(Mw[2][tid] - m) + Lw[3][tid] * __expf(Mw[3][tid] - m);
    size_t p = (size_t)z * NS_ + cstart[c] + r0 + tid;
    ml[p * 2] = m; ml[p * 2 + 1] = l;
  }
}

__global__ __launch_bounds__(256) void attn_colsum_k(
    const short* __restrict__ qkv_all, const int* __restrict__ idx,
    const int* __restrict__ cnt, const int* __restrict__ cstart,
    const float* __restrict__ ml, float* __restrict__ colsum)
{
  int c = blockIdx.x, z = blockIdx.z, a = z >> 1, h = z & 1;
  int n = cnt[c];
  int j0 = blockIdx.y * 64;
  if (j0 >= n) return;
  const short* qkv = qkv_all + (size_t)a * NS_ * 768;
  const int* myidx = idx + c * NS_;
  __shared__ short Qs[64 * LS];
  __shared__ short Ks[64 * LS];
  __shared__ float Msm[64], Lsm[64];
  int tid = threadIdx.x, lane = tid & 63, wid = tid >> 6;
  int lm = lane & 15, quad = lane >> 4;
  stage64x128(qkv, myidx, j0, n, 256 + h * 128, Ks);
  float ca = 0.f;
  for (int i0 = 0; i0 < n; i0 += 64) {
    __syncthreads();
    stage64x128(qkv, myidx, i0, n, h * 128, Qs);
    if (tid < 64) {
      int gi = i0 + tid;
      if (gi < n) {
        size_t p = (size_t)z * NS_ + cstart[c] + gi;
        Msm[tid] = ml[p * 2]; Lsm[tid] = ml[p * 2 + 1];
      } else { Msm[tid] = 0.f; Lsm[tid] = 1.f; }
    }
    __syncthreads();
    f4v acc[4];
    #pragma unroll
    for (int mi = 0; mi < 4; ++mi) acc[mi] = (f4v)(0.f);
    #pragma unroll
    for (int kc = 0; kc < 4; ++kc) {
      s8v bfr = *(const s8v*)&Ks[(wid * 16 + lm) * LS + kc * 32 + quad * 8];
      #pragma unroll
      for (int mi = 0; mi < 4; ++mi) {
        s8v af = *(const s8v*)&Qs[(mi * 16 + lm) * LS + kc * 32 + quad * 8];
        acc[mi] = __builtin_amdgcn_mfma_f32_16x16x32_bf16(af, bfr, acc[mi], 0, 0, 0);
      }
    }
    #pragma unroll
    for (int mi = 0; mi < 4; ++mi) {
      #pragma unroll
      for (int r = 0; r < 4; ++r) {
        int lrow = mi * 16 + quad * 4 + r;
        int gi = i0 + lrow;
        if (gi < n) {
          float m = Msm[lrow];
          float invl = 1.f / Lsm[lrow];
          ca += __expf(acc[mi][r] * QSCALE - m) * invl;
        }
      }
    }
  }
  ca += __shfl_xor(ca, 16);
  ca += __shfl_xor(ca, 32);
  int col = j0 + wid * 16 + lm;
  if (quad == 0 && col < n)
    colsum[(size_t)z * NS_ + cstart[c] + col] = ca;
}

// ---- proto V-aggregation ----
#define PCH 8
__global__ __launch_bounds__(1024) void proto_reduce_k(
    const short* __restrict__ qkv_all, const int* __restrict__ idx,
    const int* __restrict__ cnt, const int* __restrict__ cstart,
    const float* __restrict__ colsum, float* __restrict__ proto_pre) {
  int c = blockIdx.x, a = blockIdx.y;
  int n = cnt[c];
  int tid = threadIdx.x, lane = tid & 63, wid = tid >> 6;
  int h = lane >> 5;
  int e0 = lane * 4;
  const short* qkv = qkv_all + (size_t)a * NS_ * 768 + 512;
  const float* csum = colsum + (size_t)(a * 2 + h) * NS_ + cstart[c];
  const int* myidx = idx + c * NS_;
  float a0 = 0.f, a1 = 0.f, a2 = 0.f, a3 = 0.f;
  for (int k = wid; k < n; k += 16) {
    float w = csum[k];
    const s4v v = *(const s4v*)(qkv + (size_t)myidx[k] * 768 + e0);
    a0 += w * bf2f(v[0]); a1 += w * bf2f(v[1]);
    a2 += w * bf2f(v[2]); a3 += w * bf2f(v[3]);
  }
  __shared__ float red[16][E_];
  *(float4*)&red[wid][e0] = make_float4(a0, a1, a2, a3);
  __syncthreads();
  if (tid < E_) {
    float s = 0.f;
    #pragma unroll
    for (int wdx = 0; wdx < 16; ++wdx) s += red[wdx][tid];
    proto_pre[((size_t)a * NWAY_ + c) * E_ + tid] = (n > 0) ? s / (float)n : 0.f;
  }
}

__global__ void proto_outproj_k(const float* __restrict__ proto_pre, const void* __restrict__ ow,
                                const void* __restrict__ ob, const int* __restrict__ cnt,
                                float* __restrict__ protos_all, float* __restrict__ pnorm,
                                const int* __restrict__ flags) {
  int c = blockIdx.x, a = blockIdx.y, e = threadIdx.x;
  const int fW = flags[49], fB = flags[50];
  __shared__ float pp[E_];
  __shared__ float r2[E_];
  pp[e] = proto_pre[((size_t)a * NWAY_ + c) * E_ + e];
  __syncthreads();
  size_t wb = (size_t)a * E_ * E_ + (size_t)e * E_;
  float s = 0.f;
  for (int k = 0; k < E_; ++k) s += pp[k] * ldw(ow, wb + k, fW);
  float v = s + ldw(ob, (size_t)a * E_ + e, fB);
  float vm = (cnt[c] > 0) ? v : 0.f;
  protos_all[((size_t)a * NWAY_ + c) * E_ + e] = vm;
  r2[e] = vm * vm;
  __syncthreads();
  for (int o = 128; o > 0; o >>= 1) { if (e < o) r2[e] += r2[e + o]; __syncthreads(); }
  if (e == 0) pnorm[a * NWAY_ + c] = r2[0];
}

// ---- biascat2[a][0:256] = ck@w1[256:512] + b1; [256:512] = 0 ----
__global__ void bias2_k(const float* __restrict__ ck, const void* __restrict__ w1,
                        const void* __restrict__ b1, float* __restrict__ biascat2,
                        const int* __restrict__ flags) {
  const int fW = flags[51], fB = flags[52];
  int a = blockIdx.x, n = threadIdx.x;
  __shared__ float c[E_];
  c[n] = ck[a * E_ + n]; __syncthreads();
  size_t wbase = (size_t)a * 2 * E_ * E_ + (size_t)E_ * E_ + n;
  float s = 0.f;
  for (int k = 0; k < E_; ++k) s += c[k] * ldw(w1, wbase + (size_t)k * E_, fW);
  biascat2[(size_t)a * 512 + n] = s + ldw(b1, (size_t)a * E_ + n, fB);
  biascat2[(size_t)a * 512 + 256 + n] = 0.f;
}

// ---- fusion combine: fh1 = relu(sum_a U[a][:,256:512] + f_b1); 8 rows/block ----
__global__ __launch_bounds__(256) void fcomb2_k(const short* __restrict__ U, const void* __restrict__ b1,
                                                short* __restrict__ fh1, const int* __restrict__ flags) {
  const int fB = flags[59];
  int r = threadIdx.x >> 5;
  int n0 = (threadIdx.x & 31) * 8;
  int i = blockIdx.x * 8 + r;
  float acc[8];
  #pragma unroll
  for (int q = 0; q < 8; ++q) acc[q] = ldw(b1, n0 + q, fB);
  #pragma unroll
  for (int a = 0; a < A_; ++a) {
    s8v v = *(const s8v*)(U + ((size_t)a * NQ_ + i) * 512 + 256 + n0);
    #pragma unroll
    for (int q = 0; q < 8; ++q) acc[q] += bf2f(v[q]);
  }
  short yv[8];
  #pragma unroll
  for (int q = 0; q < 8; ++q) yv[q] = f2bf(fmaxf(acc[q], 0.f));
  *(s8v*)(fh1 + (size_t)i * 256 + n0) = *(s8v*)yv;
}

// ---------------- epilogues: thread-per-row, no cross-lane reductions ----------------
__global__ __launch_bounds__(256) void logits2_k(const short* __restrict__ fqbase,
                                                 const float* __restrict__ protos_all,
                                                 const float* __restrict__ pnorm,
                                                 const bf16* __restrict__ c2all,
                                                 const void* __restrict__ w3,
                                                 const void* __restrict__ b3,
                                                 float* __restrict__ out,
                                                 const int* __restrict__ flags) {
  const int fW = flags[55], fB = flags[56];
  const int a = blockIdx.y;
  const int i = blockIdx.x * 256 + threadIdx.x;
  __shared__ float ps[NWAY_][E_];
  __shared__ float w3s[128];
  for (int t = threadIdx.x; t < NWAY_ * E_; t += 256)
    ps[t >> 8][t & 255] = protos_all[(size_t)a * NWAY_ * E_ + t];
  if (threadIdx.x < 128) w3s[threadIdx.x] = ldw(w3, (size_t)a * 128 + threadIdx.x, fW);
  __syncthreads();
  const short* fq = fqbase + (size_t)a * FSTR + (size_t)i * E_;
  float qq = 0.f, dt0 = 0.f, dt1 = 0.f, dt2 = 0.f, dt3 = 0.f, dt4 = 0.f;
  for (int e0 = 0; e0 < E_; e0 += 8) {
    s8v v = *(const s8v*)(fq + e0);
    #pragma unroll
    for (int q = 0; q < 8; ++q) {
      float x = bf2f(v[q]); int e = e0 + q;
      qq += x * x;
      dt0 += x * ps[0][e]; dt1 += x * ps[1][e]; dt2 += x * ps[2][e];
      dt3 += x * ps[3][e]; dt4 += x * ps[4][e];
    }
  }
  const short* c2 = (const short*)c2all + ((size_t)a * NQ_ + i) * 128;
  float conf = 0.f;
  for (int e0 = 0; e0 < 128; e0 += 8) {
    s8v v = *(const s8v*)(c2 + e0);
    #pragma unroll
    for (int q = 0; q < 8; ++q) conf += bf2f(v[q]) * w3s[e0 + q];
  }
  conf += ldw(b3, a, fB);
  float dts[5] = { dt0, dt1, dt2, dt3, dt4 };
  float* o = out + ((size_t)a * NQ_ + i) * NWAY_;
  #pragma unroll
  for (int c = 0; c < NWAY_; ++c) {
    float pp = pnorm[a * NWAY_ + c];
    float d2 = fmaxf(qq + pp - 2.f * dts[c], 1e-12f);
    o[c] = -sqrtf(d2) + 0.1f * conf;
  }
}

__global__ __launch_bounds__(256) void fused2_k(const float* __restrict__ h2, const void* __restrict__ w3,
                                                const void* __restrict__ b3, float* __restrict__ out,
                                                const int* __restrict__ flags) {
  const int fW = flags[62], fB = flags[63];
  int i = blockIdx.x * 256 + threadIdx.x;
  __shared__ float ws[128];
  if (threadIdx.x < 128) ws[threadIdx.x] = ldw(w3, threadIdx.x, fW);
  __syncthreads();
  const float* h = h2 + (size_t)i * 128;
  float s = 0.f;
  for (int e = 0; e < 128; e += 4) {
    float4 v = *(const float4*)(h + e);
    s += v.x * ws[e] + v.y * ws[e + 1] + v.z * ws[e + 2] + v.w * ws[e + 3];
  }
  out[i] = s + ldw(b3, 0, fB);
}

// ---------------- host ----------------
extern "C" void kernel_launch(void* const* d_in, const int* in_sizes, int n_in,
                              void* d_out, int out_size, void* d_ws, size_t ws_size,
                              hipStream_t stream) {
  (void)out_size; (void)ws_size;
  #define P(i) ((const void*)d_in[i])
  const int* support_y = (const int*)d_in[1];
  float* out = (float*)d_out;

  int* flags = (int*)d_ws;
  char* base = (char*)d_ws + 256;
  short* featsC = (short*)base;                        // bf16 [A][NM][E]
  char* R = base + (size_t)A_ * FSTR * 2;
  short* t1cat   = (short*)R;                          // [NM][2304] bf16
  short* qkv_all = (short*)R;                          // [A][NS][768] bf16
  short* U       = (short*)(R + (size_t)15728640);     // [A][NQ][512] bf16
  short* fh1     = (short*)R;                          // [NQ][256] bf16
  float* fh2     = (float*)(R + (size_t)8388608);      // [NQ][128] f32
  char* XCR = R + (size_t)57671680;
  short* XC   = (short*)XCR;
  short* tmp2 = (short*)XCR;
  short* b4   = (short*)(XCR + (size_t)NM_ * 256 * 2);
  short* clsC2_all = (short*)XCR;
  char* S = XCR + (size_t)10485760;
  float* state      = (float*)S;
  float* msg        = state + A_ * E_;
  float* ck         = msg + A_ * E_;
  float* protos_all = ck + A_ * E_;
  float* biascat2   = protos_all + A_ * NWAY_ * E_;
  float* ml         = biascat2 + A_ * 512;
  float* colsum     = ml + (size_t)A_ * 2 * NS_ * 2;
  float* proto_pre  = colsum + (size_t)A_ * 2 * NS_;
  int*   idx        = (int*)(proto_pre + A_ * NWAY_ * E_);
  int*   cnt        = idx + NWAY_ * NS_;
  int*   cstart     = cnt + NWAY_;
  float* statepart  = (float*)(cstart + NWAY_ + 3);
  float* mvp        = statepart + A_ * 16 * E_;
  float* qkvc       = mvp + A_ * 8 * E_;
  float* obar       = qkvc + A_ * 4 * 768;
  float* comb       = obar + A_ * E_;
  float* hh         = comb + A_ * E_;
  float* ckb        = hh + A_ * E_;
  float* ppart      = ckb + A_ * 768;                  // reused as pnorm (25 floats)
  float* bcat       = ppart + (size_t)A_ * NWAY_ * PCH * E_;
  short* Wcat       = (short*)(bcat + 2304);
  short* Bcat2      = Wcat + (size_t)2304 * 512;
  short* W2         = Bcat2 + (size_t)A_ * 512 * 256;  // converted TRB bf16 weights (~3.7 MB)

  const short* fq_base = featsC + (size_t)NS_ * E_;

  Ptrs ps;
  for (int i = 0; i < 64; ++i) {
    ps.p[i] = (i < n_in) ? d_in[i] : nullptr;
    ps.sz[i] = (i < n_in) ? in_sizes[i] : 0;
  }
  probe_k<<<64, 64, 0, stream>>>(ps, flags);
  classidx_k<<<1, 256, 0, stream>>>(support_y, idx, cnt, cstart);
  xcopy_k<<<(NM_ * 512 / 4) / 256, 256, 0, stream>>>(P(0), P(2), XC, flags);
  wcat_k<<<dim3(9, 512), 256, 0, stream>>>(ps, Wcat, bcat, flags);
  wcls_k<<<dim3(512, A_), 256, 0, stream>>>(P(51), P(58), Bcat2, flags);
  wconv_k<<<dim3(960, 9), 256, 0, stream>>>(ps, W2, flags);

  // ---- FE: mega layer-1 GEMM (N = 2304), per-tile act map; deep-pipelined path ----
  {
    dim3 g(2304 / 128, NM_ / 128), b(256);
    gemmd_k<<<g, b, 0, stream>>>(XC, 512, Wcat, 512, bcat, (bf16*)t1cat, 2304, 512, 0x555555000ULL);
  }
  lnv_k<1, 512><<<NM_ / 4, 256, 0, stream>>>(t1cat, P(6), P(7), t1cat, 2304, 2304, 6, 7, flags);
  gemm<2, 2, true, true, 0, false, false, true>(stream, t1cat, 2304, W2 + 0, 512, 0, P(9), 0,
                                                (float*)tmp2, 256, NM_, 256, 512, 1.f, -1, -1, 9, flags);
  lnv_k<1, 256><<<NM_ / 4, 256, 0, stream>>>(tmp2, P(10), P(11), featsC, 256, 256, 10, 11, flags);
  lnv_k<1, 256><<<NM_ / 4, 256, 0, stream>>>(t1cat + 512, P(14), P(15), t1cat + 512, 2304, 2304, 14, 15, flags);
  gemm<2, 2, true, true, 2, false, false, true>(stream, t1cat + 512, 2304, W2 + 131072, 256, 0, P(17), 0,
                                                (float*)(featsC + FSTR), 256, NM_, 256, 256, 1.f, -1, -1, 17, flags);
  gemm<2, 2, true, true, 0, false, false, true>(stream, t1cat + 768, 2304, W2 + 196608, 768, 0, P(21), 0,
                                                (float*)tmp2, 256, NM_, 256, 768, 1.f, -1, -1, 21, flags);
  lnv_k<1, 256><<<NM_ / 4, 256, 0, stream>>>(tmp2, P(22), P(23), featsC + 2 * FSTR, 256, 256, 22, 23, flags);
  gemm<2, 2, true, true, 0, false, false, true>(stream, t1cat + 1536, 2304, W2 + 393216, 256, 0, P(27), 0,
                                                (float*)tmp2, 256, NM_, 256, 256, 1.f, -1, -1, 27, flags);
  lnv_k<3, 256><<<NM_ / 4, 256, 0, stream>>>(tmp2, P(28), P(29), featsC + 3 * FSTR, 256, 256, 28, 29, flags);
  gemm<2, 2, true, true, 1, false, false, true>(stream, t1cat + 1792, 2304, W2 + 458752, 512, 0, P(33), 0,
                                                (float*)b4, 256, NM_, 256, 512, 1.f, -1, -1, 33, flags);
  gemm<2, 2, true, true, 0, false, false, true>(stream, b4, 256, W2 + 589824, 256, 0, P(35), 0,
                                                (float*)(featsC + 4 * FSTR), 256, NM_, 256, 256, 1.f, -1, -1, 35, flags);

  // ---- comm round ----
  statepart_k<<<dim3(A_, 16), 256, 0, stream>>>(featsC, statepart);
  statecomb_k<<<A_, 256, 0, stream>>>(statepart, P(46), state, flags);
  mvpart_k<<<dim3(A_, 8), 256, 0, stream>>>(state, P(36), 36, mvp, flags);
  mvcomb_k<2><<<A_, 256, 0, stream>>>(mvp, P(37), 37, msg, flags);
  qkvcomm_k<<<A_ * 768 / 4, 256, 0, stream>>>(msg, P(57), P(38), P(39), qkvc, flags);
  attn4_k<<<A_, 256, 0, stream>>>(qkvc, obar);
  combproj_k<<<A_ * E_ / 4, 256, 0, stream>>>(obar, P(40), P(41), P(46), comb, flags);
  mvpart_k<<<dim3(A_, 8), 256, 0, stream>>>(comb, P(42), 42, mvp, flags);
  mvcomb_k<1><<<A_, 256, 0, stream>>>(mvp, P(43), 43, hh, flags);
  mvpart_k<<<dim3(A_, 8), 256, 0, stream>>>(hh, P(44), 44, mvp, flags);
  mvcomb_k<0><<<A_, 256, 0, stream>>>(mvp, P(45), 45, ck, flags);

  // ---- batched prototype attention (ck folded into qkv bias; qkv bf16, GDB path) ----
  ckb_k<<<A_ * 768 / 4, 256, 0, stream>>>(ck, P(47), P(48), ckb, flags);
  gemm<2, 2, false, true, 0, false, false, true>(stream, featsC, 256, W2 + 851968, 256, 0, ckb, 0,
                                    (float*)qkv_all, 768, NS_, 768, 256, 1.f, -1, -1, -1, flags,
                                    A_, FSTR, (size_t)768 * 256, (size_t)768, (size_t)NS_ * 768);
  {
    dim3 g(NWAY_, NS_ / 64, A_ * 2);
    attn_stats_k<<<g, 256, 0, stream>>>(qkv_all, idx, cnt, cstart, ml);
    attn_colsum_k<<<g, 256, 0, stream>>>(qkv_all, idx, cnt, cstart, ml, colsum);
  }
  proto_reduce_k<<<dim3(NWAY_, A_), 1024, 0, stream>>>(qkv_all, idx, cnt, cstart, colsum, proto_pre);
  proto_outproj_k<<<dim3(NWAY_, A_), 256, 0, stream>>>(proto_pre, P(49), P(50), cnt, protos_all, ppart, flags);
  bias2_k<<<A_, 256, 0, stream>>>(ck, P(51), P(52), biascat2, flags);

  // ---- combined cls1 + fusion-partial GEMM (GDB gload-dbuf path) ----
  gemm<2, 2, false, true, 0, false, false, true, true>(
      stream, fq_base, 256, Bcat2, 256, 0, biascat2, 0, (float*)U, 512,
      NQ_, 512, 256, 1.f, -1, -1, -1, flags,
      A_, FSTR, (size_t)512 * 256, (size_t)512, (size_t)NQ_ * 512, 0, 0x5ULL);
  fcomb2_k<<<NQ_ / 8, 256, 0, stream>>>(U, P(59), fh1, flags);

  // ---- cls2 + logits ----
  gemm<2, 2, true, true, 1, false, false, true>(stream, U, 512, W2 + 655360, 256, 0,
                                     P(54), 0, (float*)clsC2_all, 128, NQ_, 128, 256, 1.f, -1, -1, 54, flags,
                                     A_, (size_t)NQ_ * 512, (size_t)128 * 256, (size_t)128, (size_t)NQ_ * 128);
  logits2_k<<<dim3(NQ_ / 256, A_), 256, 0, stream>>>(fq_base, protos_all, ppart,
                                                     (const bf16*)clsC2_all, P(55), P(56), out, flags);

  // ---- fusion layer-2 + output ----
  gemm<2, 2, true, true, 1, false>(stream, fh1, 256, W2 + 819200, 256, 0, P(61), 0, fh2, 128,
                                   NQ_, 128, 256, 1.f, -1, -1, 61, flags);
  fused2_k<<<NQ_ / 256, 256, 0, stream>>>(fh2, P(62), P(63), out + (size_t)A_ * NQ_ * NWAY_, flags);
}

// Round 11
// 803.095 us; speedup vs baseline: 1.0484x; 1.0229x over previous
//
#include <hip/hip_runtime.h>
#include <hip/hip_bf16.h>

typedef __hip_bfloat16 bf16;
typedef short s8v __attribute__((ext_vector_type(8)));
typedef short s4v __attribute__((ext_vector_type(4)));
typedef float f4v __attribute__((ext_vector_type(4)));

#define A_  5
#define D_  512
#define E_  256
#define NS_ 2048
#define NQ_ 8192
#define NM_ 10240
#define NWAY_ 5
#define QSCALE 0.088388347648318447f
#define FSTR ((size_t)NM_ * E_)

__device__ inline float ldw(const void* p, size_t i, int f32) {
  return f32 ? ((const float*)p)[i] : __bfloat162float(((const bf16*)p)[i]);
}
template<bool DYN>
__device__ inline float ldT(const void* p, size_t i, int f32) {
  if (DYN) return ldw(p, i, f32);
  return ((const float*)p)[i];
}

__device__ inline short f2bf(float v) {
  union { float f; unsigned u; } x; x.f = v;
  unsigned r = x.u + 0x7fffu + ((x.u >> 16) & 1u);
  return (short)(r >> 16);
}
__device__ inline float bf2f(short s) {
  union { unsigned u; float f; } x; x.u = ((unsigned)(unsigned short)s) << 16;
  return x.f;
}

// async global->LDS, 16B per lane; lds dest = base + lane*16 (wave-uniform base)
__device__ __forceinline__ void gload16(const void* g, void* l) {
  __builtin_amdgcn_global_load_lds(
      (const __attribute__((address_space(1))) unsigned int*)g,
      (__attribute__((address_space(3))) unsigned int*)l, 16, 0, 0);
}

struct Ptrs { const void* p[64]; int sz[64]; };

__global__ void probe_k(Ptrs P, int* flags) {
  int b = blockIdx.x, lane = threadIdx.x;
  if (b == 1 || b == 3) { if (lane == 0) flags[b] = 0; return; }
  const bf16* t = (const bf16*)P.p[b];
  int n = P.sz[b];
  int K = (n >> 1) < 64 ? (n >> 1) : 64;
  bool big = false, eNZ = false, oNZ = false;
  if (lane < K) {
    float e = __bfloat162float(t[2 * lane]);
    float o = __bfloat162float(t[2 * lane + 1]);
    big = !(fabsf(e) <= 1e3f);
    eNZ = (e != 0.f); oNZ = (o != 0.f);
  }
  unsigned long long bb = __ballot(big), eb = __ballot(eNZ), ob = __ballot(oNZ);
  if (lane == 0) flags[b] = (bb != 0ull || (eb == 0ull && ob != 0ull)) ? 1 : 0;
}

__global__ void classidx_k(const int* __restrict__ y, int* __restrict__ idx,
                           int* __restrict__ cnt, int* __restrict__ cstart) {
  __shared__ int sc[NWAY_];
  int tid = threadIdx.x;
  if (tid < NWAY_) sc[tid] = 0;
  __syncthreads();
  for (int i = tid; i < NS_; i += 256) {
    int c = y[i];
    int pos = atomicAdd(&sc[c], 1);
    idx[c * NS_ + pos] = i;
  }
  __syncthreads();
  if (tid < NWAY_) cnt[tid] = sc[tid];
  if (tid == 0) { int s = 0; for (int q = 0; q < NWAY_; ++q) { cstart[q] = s; s += sc[q]; } }
}

__global__ void xcopy_k(const void* __restrict__ sx, const void* __restrict__ qx,
                        short* __restrict__ XC, const int* __restrict__ flags) {
  size_t i = ((size_t)blockIdx.x * 256 + threadIdx.x) * 4;
  const size_t SN = (size_t)NS_ * 512;
  if (i < SN) {
    int f = flags[0];
    #pragma unroll
    for (int q = 0; q < 4; ++q) XC[i + q] = f2bf(ldw(sx, i + q, f));
  } else {
    int f = flags[2];
    size_t j = i - SN;
    #pragma unroll
    for (int q = 0; q < 4; ++q) XC[i + q] = f2bf(ldw(qx, j + q, f));
  }
}

// ---- concat 5 layer-1 weights into Wcat[2304][512] bf16 (TRB layout) + bias cat ----
__global__ void wcat_k(Ptrs P, short* __restrict__ Wcat, float* __restrict__ bcat,
                       const int* __restrict__ flags) {
  int n = blockIdx.x * 256 + threadIdx.x;
  int k = blockIdx.y;
  int iw, ib, nl, Nloc;
  if (n < 512)       { iw = 4;  ib = 5;  nl = n;        Nloc = 512; }
  else if (n < 768)  { iw = 12; ib = 13; nl = n - 512;  Nloc = 256; }
  else if (n < 1536) { iw = 18; ib = 19; nl = n - 768;  Nloc = 768; }
  else if (n < 1792) { iw = 24; ib = 25; nl = n - 1536; Nloc = 256; }
  else               { iw = 30; ib = 31; nl = n - 1792; Nloc = 512; }
  Wcat[(size_t)n * 512 + k] = f2bf(ldw(P.p[iw], (size_t)k * Nloc + nl, flags[iw]));
  if (k == 0) bcat[n] = ldw(P.p[ib], nl, flags[ib]);
}

// ---- Bcat2[a][n][k] bf16 ----
__global__ void wcls_k(const void* __restrict__ cw1, const void* __restrict__ fw1,
                       short* __restrict__ B2, const int* __restrict__ flags) {
  int n = blockIdx.x, a = blockIdx.y, k = threadIdx.x;
  float v;
  if (n < 256) v = ldw(cw1, ((size_t)a * 512 + k) * 256 + n, flags[51]);
  else v = ldw(fw1, ((size_t)(a * 256 + k)) * 256 + (n - 256), flags[58]);
  B2[((size_t)a * 512 + n) * 256 + k] = f2bf(v);
}

// ---- convert/transpose remaining weights to bf16 TRB [N][K] into W2 ----
__global__ void wconv_k(Ptrs P, short* __restrict__ W2, const int* __restrict__ flags) {
  const int id = blockIdx.y;
  int src, K, N; size_t off; int tr, batch;
  switch (id) {
    case 0: src = 8;  K = 512; N = 256; off = 0;      tr = 1; batch = 1;  break;
    case 1: src = 16; K = 256; N = 256; off = 131072; tr = 1; batch = 1;  break;
    case 2: src = 20; K = 768; N = 256; off = 196608; tr = 1; batch = 1;  break;
    case 3: src = 26; K = 256; N = 256; off = 393216; tr = 1; batch = 1;  break;
    case 4: src = 32; K = 512; N = 256; off = 458752; tr = 1; batch = 1;  break;
    case 5: src = 34; K = 256; N = 256; off = 589824; tr = 1; batch = 1;  break;
    case 6: src = 53; K = 256; N = 128; off = 655360; tr = 1; batch = A_; break;
    case 7: src = 60; K = 256; N = 128; off = 819200; tr = 1; batch = 1;  break;
    default: src = 47; K = 256; N = 768; off = 851968; tr = 0; batch = A_; break;
  }
  size_t tot = (size_t)batch * K * N;
  size_t e0 = ((size_t)blockIdx.x * 256 + threadIdx.x) * 4;
  if (e0 >= tot) return;
  const void* sp = P.p[src];
  int f = flags[src];
  if (!tr) {
    #pragma unroll
    for (int q = 0; q < 4; ++q) W2[off + e0 + q] = f2bf(ldw(sp, e0 + q, f));
  } else {
    size_t kn = (size_t)K * N;
    #pragma unroll
    for (int q = 0; q < 4; ++q) {
      size_t e = e0 + q;
      int b = (int)(e / kn);
      int r = (int)(e % kn);
      int n = r / K, k = r % K;
      W2[off + e] = f2bf(ldw(sp, ((size_t)b * K + k) * N + n, f));
    }
  }
}

// ============ MFMA bf16 GEMM (128x128, 4-wave) ============
#define LSTR 40
template<int AMODE, int BMODE, bool DYNBIAS, bool TRB, int ACT, bool ACCUM,
         bool KSPLIT = false, bool OUTBF16 = false, bool DOMAP = false>
__global__ __launch_bounds__(256) void gemm_k(
    const void* __restrict__ A, int lda,
    const void* __restrict__ B, int ldb, size_t offB,
    const void* __restrict__ bias, size_t offBias,
    float* __restrict__ C, int ldc,
    int M, int N, int K, float alpha,
    int ia, int ib, int ibias, const int* __restrict__ flags,
    size_t sA, size_t sB, size_t sBias, size_t sC, size_t kstrideA,
    unsigned long long amap)
{
  constexpr bool GDB = (AMODE == 2) && (BMODE == 2) && TRB && !KSPLIT;
  const int fA = (AMODE == 1) ? flags[ia] : 1;
  const int fB = (BMODE == 1) ? flags[ib] : 1;
  const int fBi = DYNBIAS ? flags[ibias] : 1;
  const size_t zA = (size_t)blockIdx.z * sA;
  const size_t zB = offB + (size_t)blockIdx.z * sB;
  const size_t zBias = offBias + (size_t)blockIdx.z * sBias;
  float* Cz = C + (size_t)blockIdx.z * sC;
  bf16* Cz16 = (bf16*)C + (size_t)blockIdx.z * sC;
  const int tid = threadIdx.x;
  const int bm = blockIdx.y * 128, bn = blockIdx.x * 128;
  const int lane = tid & 63, wid = tid >> 6;
  const int lm = lane & 15, quad = lane >> 4;
  const int wy = (wid >> 1) * 64, wx = (wid & 1) * 64;
  f4v acc[4][4];
  #pragma unroll
  for (int i = 0; i < 4; ++i)
    #pragma unroll
    for (int j = 0; j < 4; ++j) acc[i][j] = (f4v)(0.f);

  if constexpr (GDB) {
    __shared__ short smem[4 * 128 * 32];   // 32 KB: [A0|A1|B0|B1]
    const int srow = lane >> 2, scol = (lane & 3) * 8;
    const short* Azs = (const short*)A + zA;
    const short* Bzs = (const short*)B + zB;
    auto stage = [&](int bsel, int k0) {
      short* Asb = smem + bsel * 4096;
      short* Bsb = smem + 8192 + bsel * 4096;
      #pragma unroll
      for (int q = 0; q < 2; ++q) {
        int rb = (wid * 2 + q) * 16;
        gload16(Azs + (size_t)(bm + rb + srow) * lda + k0 + scol, Asb + rb * 32);
        gload16(Bzs + (size_t)(bn + rb + srow) * ldb + k0 + scol, Bsb + rb * 32);
      }
    };
    stage(0, 0);
    __syncthreads();
    int cur = 0;
    for (int k0 = 0; k0 < K; k0 += 32) {
      if (k0 + 32 < K) stage(cur ^ 1, k0 + 32);   // loads fly across MFMA
      const short* Asb = smem + cur * 4096;
      const short* Bsb = smem + 8192 + cur * 4096;
      s8v af[4], bfr[4];
      #pragma unroll
      for (int mi = 0; mi < 4; ++mi)
        af[mi] = *(const s8v*)&Asb[(wy + mi*16 + lm) * 32 + quad * 8];
      #pragma unroll
      for (int ni = 0; ni < 4; ++ni)
        bfr[ni] = *(const s8v*)&Bsb[(wx + ni*16 + lm) * 32 + quad * 8];
      #pragma unroll
      for (int mi = 0; mi < 4; ++mi)
        #pragma unroll
        for (int ni = 0; ni < 4; ++ni)
          acc[mi][ni] = __builtin_amdgcn_mfma_f32_16x16x32_bf16(af[mi], bfr[ni], acc[mi][ni], 0, 0, 0);
      __syncthreads();
      cur ^= 1;
    }
  } else {
    __shared__ short As[128 * LSTR];
    __shared__ short Bs[128 * LSTR];
    const int am = tid >> 1, ah = (tid & 1) * 16;

    s8v a_s0, a_s1;
    float a_f[16];
    s8v b_s0, b_s1;
    float b_f[16];
    short b_h[16];

    auto loadA = [&](int k0) {
      int kk = k0 + ah;
      size_t base;
      if (KSPLIT) base = zA + (size_t)(kk >> 8) * kstrideA + (size_t)(bm + am) * lda + (kk & 255);
      else base = zA + (size_t)(bm + am) * lda + kk;
      if constexpr (AMODE == 2) {
        const bf16* ap = (const bf16*)A + base;
        a_s0 = *(const s8v*)ap;
        a_s1 = *(const s8v*)(ap + 8);
      } else {
        if (fA) {
          const float4* src = (const float4*)((const float*)A + base);
          #pragma unroll
          for (int q = 0; q < 4; ++q) {
            float4 v = src[q];
            a_f[q*4] = v.x; a_f[q*4+1] = v.y; a_f[q*4+2] = v.z; a_f[q*4+3] = v.w;
          }
        } else {
          #pragma unroll
          for (int q = 0; q < 16; ++q) a_f[q] = ldw(A, base + q, 0);
        }
      }
    };
    auto storeA = [&]() {
      if constexpr (AMODE == 2) {
        *(s8v*)&As[am * LSTR + ah] = a_s0;
        *(s8v*)&As[am * LSTR + ah + 8] = a_s1;
      } else {
        short tmp[16];
        #pragma unroll
        for (int q = 0; q < 16; ++q) tmp[q] = f2bf(a_f[q]);
        s4v* dst = (s4v*)&As[am * LSTR + ah];
        #pragma unroll
        for (int q = 0; q < 4; ++q) dst[q] = *(s4v*)&tmp[q*4];
      }
    };
    auto loadB = [&](int k0) {
      if constexpr (TRB) {
        int n = tid >> 1, h = (tid & 1) * 16;
        size_t base = zB + (size_t)(bn + n) * ldb + k0 + h;
        if constexpr (BMODE == 2) {
          const bf16* bp = (const bf16*)B + base;
          b_s0 = *(const s8v*)bp;
          b_s1 = *(const s8v*)(bp + 8);
        } else {
          if (fB) {
            const float4* src = (const float4*)((const float*)B + base);
            #pragma unroll
            for (int q = 0; q < 4; ++q) {
              float4 v = src[q];
              b_f[q*4] = v.x; b_f[q*4+1] = v.y; b_f[q*4+2] = v.z; b_f[q*4+3] = v.w;
            }
          } else {
            #pragma unroll
            for (int q = 0; q < 16; ++q) b_f[q] = ldw(B, base + q, 0);
          }
        }
      } else {
        int n = tid & 127, kk2 = (tid >> 7) * 16;
        #pragma unroll
        for (int j = 0; j < 16; ++j) {
          size_t bi = zB + (size_t)(k0 + kk2 + j) * ldb + bn + n;
          if constexpr (BMODE == 2) b_h[j] = ((const short*)B)[bi];
          else b_f[j] = ldT<BMODE == 1>(B, bi, fB);
        }
      }
    };
    auto storeB = [&]() {
      if constexpr (TRB) {
        int n = tid >> 1, h = (tid & 1) * 16;
        if constexpr (BMODE == 2) {
          *(s8v*)&Bs[n * LSTR + h] = b_s0;
          *(s8v*)&Bs[n * LSTR + h + 8] = b_s1;
        } else {
          short tmp[16];
          #pragma unroll
          for (int q = 0; q < 16; ++q) tmp[q] = f2bf(b_f[q]);
          s4v* dst = (s4v*)&Bs[n * LSTR + h];
          #pragma unroll
          for (int q = 0; q < 4; ++q) dst[q] = *(s4v*)&tmp[q*4];
        }
      } else {
        int n = tid & 127, kk2 = (tid >> 7) * 16;
        short tmp[16];
        #pragma unroll
        for (int j = 0; j < 16; ++j) tmp[j] = (BMODE == 2) ? b_h[j] : f2bf(b_f[j]);
        s4v* dst = (s4v*)&Bs[n * LSTR + kk2];
        #pragma unroll
        for (int q = 0; q < 4; ++q) dst[q] = *(s4v*)&tmp[q*4];
      }
    };

    loadA(0);
    loadB(0);
    for (int k0 = 0; k0 < K; k0 += 32) {
      storeA();
      storeB();
      __syncthreads();
      if (k0 + 32 < K) { loadA(k0 + 32); loadB(k0 + 32); }
      s8v af[4], bfr[4];
      #pragma unroll
      for (int mi = 0; mi < 4; ++mi)
        af[mi] = *(const s8v*)&As[(wy + mi*16 + lm) * LSTR + quad * 8];
      #pragma unroll
      for (int ni = 0; ni < 4; ++ni)
        bfr[ni] = *(const s8v*)&Bs[(wx + ni*16 + lm) * LSTR + quad * 8];
      #pragma unroll
      for (int mi = 0; mi < 4; ++mi)
        #pragma unroll
        for (int ni = 0; ni < 4; ++ni)
          acc[mi][ni] = __builtin_amdgcn_mfma_f32_16x16x32_bf16(af[mi], bfr[ni], acc[mi][ni], 0, 0, 0);
      __syncthreads();
    }
  }

  const int actc = DOMAP ? (int)((amap >> (((bn + wx) >> 7) * 2)) & 3ULL) : ACT;
  #pragma unroll
  for (int mi = 0; mi < 4; ++mi) {
    #pragma unroll
    for (int r = 0; r < 4; ++r) {
      int row = bm + wy + mi*16 + quad*4 + r;
      #pragma unroll
      for (int ni = 0; ni < 4; ++ni) {
        int col = bn + wx + ni*16 + lm;
        float v = acc[mi][ni][r] * alpha;
        if (ACCUM) v += Cz[(size_t)row * ldc + col];
        if (bias) v += ldT<DYNBIAS>(bias, zBias + col, fBi);
        if (actc == 1) v = fmaxf(v, 0.f);
        else if (actc == 2) v = tanhf(v);
        else if (actc == 3) v = 1.f / (1.f + expf(-v));
        if (OUTBF16) Cz16[(size_t)row * ldc + col] = __float2bfloat16(v);
        else Cz[(size_t)row * ldc + col] = v;
      }
    }
  }
}

template<int AMODE, int BMODE, bool DYNBIAS, bool TRB, int ACT, bool ACCUM,
         bool KSPLIT = false, bool OUTBF16 = false, bool DOMAP = false>
static void gemm(hipStream_t s, const void* A, int lda, const void* B, int ldb, size_t offB,
                 const void* bias, size_t offBias, float* C, int ldc, int M, int N, int K,
                 float alpha, int ia, int ib, int ibias, const int* flags,
                 int batch = 1, size_t sA = 0, size_t sB = 0, size_t sBias = 0, size_t sC = 0,
                 size_t kstrideA = 0, unsigned long long amap = 0) {
  dim3 g(N / 128, M / 128, batch), b(256);
  gemm_k<AMODE, BMODE, DYNBIAS, TRB, ACT, ACCUM, KSPLIT, OUTBF16, DOMAP><<<g, b, 0, s>>>(
      A, lda, B, ldb, offB, bias, offBias, C, ldc, M, N, K, alpha, ia, ib, ibias, flags,
      sA, sB, sBias, sC, kstrideA, amap);
}

// ---------------- vectorized wave-per-row LayerNorm (+relu/sigmoid), bf16 in/out ----------------
template<int ACT, int W>
__global__ __launch_bounds__(256) void lnv_k(const short* __restrict__ X, const void* __restrict__ g,
                                             const void* __restrict__ be, short* __restrict__ Y,
                                             int ldx, int ldy,
                                             int ig, int ibe, const int* __restrict__ flags) {
  const int fG = flags[ig], fBe = flags[ibe];
  const int wid = threadIdx.x >> 6, lane = threadIdx.x & 63;
  const int row = blockIdx.x * 4 + wid;
  constexpr int V = W / 64;
  const short* x = X + (size_t)row * ldx + lane * V;
  float xv[V];
  if constexpr (V == 8) {
    s8v v = *(const s8v*)x;
    #pragma unroll
    for (int q = 0; q < 8; ++q) xv[q] = bf2f(v[q]);
  } else {
    s4v v = *(const s4v*)x;
    #pragma unroll
    for (int q = 0; q < 4; ++q) xv[q] = bf2f(v[q]);
  }
  float s1 = 0.f, s2 = 0.f;
  #pragma unroll
  for (int q = 0; q < V; ++q) { s1 += xv[q]; s2 += xv[q] * xv[q]; }
  #pragma unroll
  for (int o = 32; o > 0; o >>= 1) { s1 += __shfl_xor(s1, o); s2 += __shfl_xor(s2, o); }
  float mean = s1 * (1.f / W);
  float var = fmaxf(s2 * (1.f / W) - mean * mean, 0.f);
  float rstd = rsqrtf(var + 1e-5f);
  short yv[V];
  #pragma unroll
  for (int q = 0; q < V; ++q) {
    int i = lane * V + q;
    float v = (xv[q] - mean) * rstd * ldw(g, i, fG) + ldw(be, i, fBe);
    if (ACT == 1) v = fmaxf(v, 0.f);
    else if (ACT == 3) v = 1.f / (1.f + expf(-v));
    yv[q] = f2bf(v);
  }
  short* y = Y + (size_t)row * ldy + lane * V;
  if constexpr (V == 8) *(s8v*)y = *(s8v*)yv;
  else *(s4v*)y = *(s4v*)yv;
}

// ================= comm round =================
__global__ void statepart_k(const short* __restrict__ featsC, float* __restrict__ part) {
  int a = blockIdx.x, g = blockIdx.y, e = threadIdx.x;
  const short* p = featsC + (size_t)a * FSTR + ((size_t)g * 128) * E_ + e;
  float s = 0.f;
  for (int n = 0; n < 128; ++n) s += bf2f(p[(size_t)n * E_]);
  part[((size_t)a * 16 + g) * E_ + e] = s;
}

__global__ void statecomb_k(const float* __restrict__ part, const void* __restrict__ internal,
                            float* __restrict__ state, const int* __restrict__ flags) {
  int a = blockIdx.x, e = threadIdx.x;
  float s = 0.f;
  for (int g = 0; g < 16; ++g) s += part[((size_t)a * 16 + g) * E_ + e];
  state[a * E_ + e] = s * (1.f / NS_) + ldw(internal, (size_t)a * E_ + e, flags[46]);
}

__global__ void mvpart_k(const float* __restrict__ x, const void* __restrict__ W, int iw,
                         float* __restrict__ part, const int* __restrict__ flags) {
  int a = blockIdx.x, g = blockIdx.y, f = threadIdx.x;
  const int fW = flags[iw];
  float s = 0.f;
  size_t wb = (size_t)a * E_ * E_ + f;
  for (int e = g * 32; e < g * 32 + 32; ++e)
    s += x[a * E_ + e] * ldw(W, wb + (size_t)e * E_, fW);
  part[((size_t)a * 8 + g) * E_ + f] = s;
}

template<int ACT>
__global__ void mvcomb_k(const float* __restrict__ part, const void* __restrict__ b, int ibb,
                         float* __restrict__ y, const int* __restrict__ flags) {
  int a = blockIdx.x, f = threadIdx.x;
  float s = 0.f;
  for (int g = 0; g < 8; ++g) s += part[((size_t)a * 8 + g) * E_ + f];
  s += ldw(b, (size_t)a * E_ + f, flags[ibb]);
  if (ACT == 1) s = fmaxf(s, 0.f);
  else if (ACT == 2) s = tanhf(s);
  y[a * E_ + f] = s;
}

__device__ inline float wave_sum64(float v) {
  for (int o = 32; o > 0; o >>= 1) v += __shfl_down(v, o);
  return v;
}

__global__ __launch_bounds__(256) void qkvcomm_k(const float* __restrict__ msg,
                                                 const void* __restrict__ comm_w,
                                                 const void* __restrict__ in_w,
                                                 const void* __restrict__ in_b,
                                                 float* __restrict__ qkvc,
                                                 const int* __restrict__ flags) {
  const int fCW = flags[57], fIW = flags[38], fIB = flags[39];
  int gw = blockIdx.x * 4 + (threadIdx.x >> 6);
  int a = gw / 768, f = gw % 768;
  int lane = threadIdx.x & 63;
  float w[5]; float mx = -1e30f;
  for (int j = 0; j < 5; ++j) { w[j] = ldw(comm_w, a * 5 + j, fCW); mx = fmaxf(mx, w[j]); }
  float sum = 0.f;
  for (int j = 0; j < 5; ++j) { w[j] = __expf(w[j] - mx); sum += w[j]; }
  for (int j = 0; j < 5; ++j) w[j] /= sum;
  int others[4]; { int c = 0; for (int j = 0; j < 5; ++j) if (j != a) others[c++] = j; }
  int e0 = lane * 4;
  float4 wv;
  size_t b = (size_t)a * 768 * E_ + (size_t)f * E_ + e0;
  if (fIW) wv = *(const float4*)((const float*)in_w + b);
  else wv = make_float4(ldw(in_w, b, 0), ldw(in_w, b + 1, 0), ldw(in_w, b + 2, 0), ldw(in_w, b + 3, 0));
  float acc[4];
  #pragma unroll
  for (int t = 0; t < 4; ++t) {
    const float4 mv = *(const float4*)(msg + others[t] * E_ + e0);
    acc[t] = mv.x * wv.x + mv.y * wv.y + mv.z * wv.z + mv.w * wv.w;
  }
  #pragma unroll
  for (int t = 0; t < 4; ++t) acc[t] = wave_sum64(acc[t]);
  if (lane == 0) {
    float bb = ldw(in_b, (size_t)a * 768 + f, fIB);
    #pragma unroll
    for (int t = 0; t < 4; ++t)
      qkvc[((size_t)a * 4 + t) * 768 + f] = acc[t] * w[others[t]] + bb;
  }
}

__global__ __launch_bounds__(256) void attn4_k(const float* __restrict__ qkvc,
                                               float* __restrict__ obar) {
  int a = blockIdx.x, tid = threadIdx.x;
  __shared__ float qkv[4][768];
  __shared__ float attw[4][16];
  for (int i = tid; i < 4 * 768; i += 256) qkv[i / 768][i % 768] = qkvc[(size_t)a * 4 * 768 + i];
  __syncthreads();
  if (tid < 16) {
    int h = tid >> 2, t = tid & 3;
    float sc[4]; float mx = -1e30f;
    for (int t2 = 0; t2 < 4; ++t2) {
      float s = 0.f;
      for (int d = 0; d < 64; ++d) s += qkv[t][h * 64 + d] * qkv[t2][256 + h * 64 + d];
      sc[t2] = s * 0.125f; mx = fmaxf(mx, sc[t2]);
    }
    float ss = 0.f;
    for (int t2 = 0; t2 < 4; ++t2) { sc[t2] = __expf(sc[t2] - mx); ss += sc[t2]; }
    for (int t2 = 0; t2 < 4; ++t2) attw[h][t * 4 + t2] = sc[t2] / ss;
  }
  __syncthreads();
  {
    int e = tid, h = e >> 6;
    float s = 0.f;
    for (int t = 0; t < 4; ++t)
      for (int t2 = 0; t2 < 4; ++t2)
        s += attw[h][t * 4 + t2] * qkv[t2][512 + e];
    obar[a * E_ + e] = s * 0.25f;
  }
}

__global__ __launch_bounds__(256) void combproj_k(const float* __restrict__ obar,
                                                  const void* __restrict__ ow,
                                                  const void* __restrict__ ob,
                                                  const void* __restrict__ internal,
                                                  float* __restrict__ comb,
                                                  const int* __restrict__ flags) {
  const int fOW = flags[40], fOB = flags[41], fIN = flags[46];
  int gw = blockIdx.x * 4 + (threadIdx.x >> 6);
  int a = gw >> 8, f = gw & 255;
  int lane = threadIdx.x & 63;
  int e0 = lane * 4;
  float4 wv;
  size_t b = (size_t)a * E_ * E_ + (size_t)f * E_ + e0;
  if (fOW) wv = *(const float4*)((const float*)ow + b);
  else wv = make_float4(ldw(ow, b, 0), ldw(ow, b + 1, 0), ldw(ow, b + 2, 0), ldw(ow, b + 3, 0));
  const float4 ov = *(const float4*)(obar + a * E_ + e0);
  float s = wave_sum64(ov.x * wv.x + ov.y * wv.y + ov.z * wv.z + ov.w * wv.w);
  if (lane == 0)
    comb[a * E_ + f] = ldw(internal, (size_t)a * E_ + f, fIN) + s + ldw(ob, (size_t)a * E_ + f, fOB);
}

__global__ __launch_bounds__(256) void ckb_k(const float* __restrict__ ck,
                                             const void* __restrict__ in_w,
                                             const void* __restrict__ in_b,
                                             float* __restrict__ ckb,
                                             const int* __restrict__ flags) {
  const int fW = flags[47], fB = flags[48];
  int gw = blockIdx.x * 4 + (threadIdx.x >> 6);
  int a = gw / 768, f = gw % 768;
  int lane = threadIdx.x & 63;
  int e0 = lane * 4;
  float4 wv;
  size_t b = (size_t)a * 768 * E_ + (size_t)f * E_ + e0;
  if (fW) wv = *(const float4*)((const float*)in_w + b);
  else wv = make_float4(ldw(in_w, b, 0), ldw(in_w, b + 1, 0), ldw(in_w, b + 2, 0), ldw(in_w, b + 3, 0));
  const float4 cv = *(const float4*)(ck + a * E_ + e0);
  float s = wave_sum64(cv.x * wv.x + cv.y * wv.y + cv.z * wv.z + cv.w * wv.w);
  if (lane == 0) ckb[(size_t)a * 768 + f] = s + ldw(in_b, (size_t)a * 768 + f, fB);
}

// ======== MFMA class-block attention (qkv_all is bf16) ========
#define LS 136
__device__ inline void stage64x128(const short* __restrict__ qkv, const int* __restrict__ myidx,
                                   int row0, int n, int ho, short* dst) {
  int t = threadIdx.x;
  int r = t >> 2, c0 = (t & 3) * 32;
  int rr = row0 + r;
  s8v v0 = (s8v)(short)0, v1 = v0, v2 = v0, v3 = v0;
  if (rr < n) {
    const s8v* s = (const s8v*)(qkv + (size_t)myidx[rr] * 768 + ho + c0);
    v0 = s[0]; v1 = s[1]; v2 = s[2]; v3 = s[3];
  }
  s8v* d = (s8v*)&dst[r * LS + c0];
  d[0] = v0; d[1] = v1; d[2] = v2; d[3] = v3;
}

// Swapped-operand stats (T12): compute S^T = mfma(K, Q) so col=lm=query, row=key.
// Key-reduction is lane-local (16 regs) + 2 cross-quad shfls; each wave owns 16 queries.
__global__ __launch_bounds__(256) void attn_stats_k(
    const short* __restrict__ qkv_all, const int* __restrict__ idx,
    const int* __restrict__ cnt, const int* __restrict__ cstart,
    float* __restrict__ ml)
{
  int c = blockIdx.x, z = blockIdx.z, a = z >> 1, h = z & 1;
  int n = cnt[c];
  int r0 = blockIdx.y * 64;
  if (r0 >= n) return;
  const short* qkv = qkv_all + (size_t)a * NS_ * 768;
  const int* myidx = idx + c * NS_;
  __shared__ short Qs[64 * LS];
  __shared__ short Ks[64 * LS];
  int tid = threadIdx.x, lane = tid & 63, wid = tid >> 6;
  int lm = lane & 15, quad = lane >> 4;
  stage64x128(qkv, myidx, r0, n, h * 128, Qs);
  float m_run = -3e38f, l_run = 0.f;
  for (int j0 = 0; j0 < n; j0 += 64) {
    __syncthreads();
    stage64x128(qkv, myidx, j0, n, 256 + h * 128, Ks);
    __syncthreads();
    f4v acc[4];
    #pragma unroll
    for (int mi = 0; mi < 4; ++mi) acc[mi] = (f4v)(0.f);
    #pragma unroll
    for (int kc = 0; kc < 4; ++kc) {
      s8v qf = *(const s8v*)&Qs[(wid * 16 + lm) * LS + kc * 32 + quad * 8];
      #pragma unroll
      for (int mi = 0; mi < 4; ++mi) {
        s8v kf = *(const s8v*)&Ks[(mi * 16 + lm) * LS + kc * 32 + quad * 8];
        acc[mi] = __builtin_amdgcn_mfma_f32_16x16x32_bf16(kf, qf, acc[mi], 0, 0, 0);
      }
    }
    // lane-local: 16 S^T values for one query (col=lm), keys mi*16+quad*4+r
    float sv[16];
    float tm = -3e38f;
    #pragma unroll
    for (int mi = 0; mi < 4; ++mi) {
      #pragma unroll
      for (int r = 0; r < 4; ++r) {
        int kk = j0 + mi * 16 + quad * 4 + r;
        float s = (kk < n) ? acc[mi][r] * QSCALE : -3e38f;
        sv[mi * 4 + r] = s;
        tm = fmaxf(tm, s);
      }
    }
    tm = fmaxf(tm, __shfl_xor(tm, 16));
    tm = fmaxf(tm, __shfl_xor(tm, 32));   // per-query tile max (all 64 keys)
    float p = 0.f;
    #pragma unroll
    for (int i = 0; i < 16; ++i) p += __expf(sv[i] - tm);   // invalid: exp(-huge)=0
    p += __shfl_xor(p, 16);
    p += __shfl_xor(p, 32);               // per-query tile sum
    float mn = fmaxf(m_run, tm);
    l_run = l_run * __expf(m_run - mn) + p * __expf(tm - mn);
    m_run = mn;
  }
  int row = r0 + wid * 16 + lm;
  if (quad == 0 && row < n) {
    size_t p = (size_t)z * NS_ + cstart[c] + row;
    ml[p * 2] = m_run; ml[p * 2 + 1] = l_run;
  }
}

__global__ __launch_bounds__(256) void attn_colsum_k(
    const short* __restrict__ qkv_all, const int* __restrict__ idx,
    const int* __restrict__ cnt, const int* __restrict__ cstart,
    const float* __restrict__ ml, float* __restrict__ colsum)
{
  int c = blockIdx.x, z = blockIdx.z, a = z >> 1, h = z & 1;
  int n = cnt[c];
  int j0 = blockIdx.y * 64;
  if (j0 >= n) return;
  const short* qkv = qkv_all + (size_t)a * NS_ * 768;
  const int* myidx = idx + c * NS_;
  __shared__ short Qs[64 * LS];
  __shared__ short Ks[64 * LS];
  __shared__ float Msm[64], Lsm[64];
  int tid = threadIdx.x, lane = tid & 63, wid = tid >> 6;
  int lm = lane & 15, quad = lane >> 4;
  stage64x128(qkv, myidx, j0, n, 256 + h * 128, Ks);
  float ca = 0.f;
  for (int i0 = 0; i0 < n; i0 += 64) {
    __syncthreads();
    stage64x128(qkv, myidx, i0, n, h * 128, Qs);
    if (tid < 64) {
      int gi = i0 + tid;
      if (gi < n) {
        size_t p = (size_t)z * NS_ + cstart[c] + gi;
        Msm[tid] = ml[p * 2]; Lsm[tid] = ml[p * 2 + 1];
      } else { Msm[tid] = 0.f; Lsm[tid] = 1.f; }
    }
    __syncthreads();
    f4v acc[4];
    #pragma unroll
    for (int mi = 0; mi < 4; ++mi) acc[mi] = (f4v)(0.f);
    #pragma unroll
    for (int kc = 0; kc < 4; ++kc) {
      s8v bfr = *(const s8v*)&Ks[(wid * 16 + lm) * LS + kc * 32 + quad * 8];
      #pragma unroll
      for (int mi = 0; mi < 4; ++mi) {
        s8v af = *(const s8v*)&Qs[(mi * 16 + lm) * LS + kc * 32 + quad * 8];
        acc[mi] = __builtin_amdgcn_mfma_f32_16x16x32_bf16(af, bfr, acc[mi], 0, 0, 0);
      }
    }
    #pragma unroll
    for (int mi = 0; mi < 4; ++mi) {
      #pragma unroll
      for (int r = 0; r < 4; ++r) {
        int lrow = mi * 16 + quad * 4 + r;
        int gi = i0 + lrow;
        if (gi < n) {
          float m = Msm[lrow];
          float invl = 1.f / Lsm[lrow];
          ca += __expf(acc[mi][r] * QSCALE - m) * invl;
        }
      }
    }
  }
  ca += __shfl_xor(ca, 16);
  ca += __shfl_xor(ca, 32);
  int col = j0 + wid * 16 + lm;
  if (quad == 0 && col < n)
    colsum[(size_t)z * NS_ + cstart[c] + col] = ca;
}

// ---- proto V-aggregation ----
#define PCH 8
__global__ __launch_bounds__(1024) void proto_reduce_k(
    const short* __restrict__ qkv_all, const int* __restrict__ idx,
    const int* __restrict__ cnt, const int* __restrict__ cstart,
    const float* __restrict__ colsum, float* __restrict__ proto_pre) {
  int c = blockIdx.x, a = blockIdx.y;
  int n = cnt[c];
  int tid = threadIdx.x, lane = tid & 63, wid = tid >> 6;
  int h = lane >> 5;
  int e0 = lane * 4;
  const short* qkv = qkv_all + (size_t)a * NS_ * 768 + 512;
  const float* csum = colsum + (size_t)(a * 2 + h) * NS_ + cstart[c];
  const int* myidx = idx + c * NS_;
  float a0 = 0.f, a1 = 0.f, a2 = 0.f, a3 = 0.f;
  for (int k = wid; k < n; k += 16) {
    float w = csum[k];
    const s4v v = *(const s4v*)(qkv + (size_t)myidx[k] * 768 + e0);
    a0 += w * bf2f(v[0]); a1 += w * bf2f(v[1]);
    a2 += w * bf2f(v[2]); a3 += w * bf2f(v[3]);
  }
  __shared__ float red[16][E_];
  *(float4*)&red[wid][e0] = make_float4(a0, a1, a2, a3);
  __syncthreads();
  if (tid < E_) {
    float s = 0.f;
    #pragma unroll
    for (int wdx = 0; wdx < 16; ++wdx) s += red[wdx][tid];
    proto_pre[((size_t)a * NWAY_ + c) * E_ + tid] = (n > 0) ? s / (float)n : 0.f;
  }
}

__global__ void proto_outproj_k(const float* __restrict__ proto_pre, const void* __restrict__ ow,
                                const void* __restrict__ ob, const int* __restrict__ cnt,
                                float* __restrict__ protos_all, float* __restrict__ pnorm,
                                const int* __restrict__ flags) {
  int c = blockIdx.x, a = blockIdx.y, e = threadIdx.x;
  const int fW = flags[49], fB = flags[50];
  __shared__ float pp[E_];
  __shared__ float r2[E_];
  pp[e] = proto_pre[((size_t)a * NWAY_ + c) * E_ + e];
  __syncthreads();
  size_t wb = (size_t)a * E_ * E_ + (size_t)e * E_;
  float s = 0.f;
  for (int k = 0; k < E_; ++k) s += pp[k] * ldw(ow, wb + k, fW);
  float v = s + ldw(ob, (size_t)a * E_ + e, fB);
  float vm = (cnt[c] > 0) ? v : 0.f;
  protos_all[((size_t)a * NWAY_ + c) * E_ + e] = vm;
  r2[e] = vm * vm;
  __syncthreads();
  for (int o = 128; o > 0; o >>= 1) { if (e < o) r2[e] += r2[e + o]; __syncthreads(); }
  if (e == 0) pnorm[a * NWAY_ + c] = r2[0];
}

// ---- biascat2[a][0:256] = ck@w1[256:512] + b1; [256:512] = 0 ----
__global__ void bias2_k(const float* __restrict__ ck, const void* __restrict__ w1,
                        const void* __restrict__ b1, float* __restrict__ biascat2,
                        const int* __restrict__ flags) {
  const int fW = flags[51], fB = flags[52];
  int a = blockIdx.x, n = threadIdx.x;
  __shared__ float c[E_];
  c[n] = ck[a * E_ + n]; __syncthreads();
  size_t wbase = (size_t)a * 2 * E_ * E_ + (size_t)E_ * E_ + n;
  float s = 0.f;
  for (int k = 0; k < E_; ++k) s += c[k] * ldw(w1, wbase + (size_t)k * E_, fW);
  biascat2[(size_t)a * 512 + n] = s + ldw(b1, (size_t)a * E_ + n, fB);
  biascat2[(size_t)a * 512 + 256 + n] = 0.f;
}

// ---- fusion combine: fh1 = relu(sum_a U[a][:,256:512] + f_b1); 8 rows/block ----
__global__ __launch_bounds__(256) void fcomb2_k(const short* __restrict__ U, const void* __restrict__ b1,
                                                short* __restrict__ fh1, const int* __restrict__ flags) {
  const int fB = flags[59];
  int r = threadIdx.x >> 5;
  int n0 = (threadIdx.x & 31) * 8;
  int i = blockIdx.x * 8 + r;
  float acc[8];
  #pragma unroll
  for (int q = 0; q < 8; ++q) acc[q] = ldw(b1, n0 + q, fB);
  #pragma unroll
  for (int a = 0; a < A_; ++a) {
    s8v v = *(const s8v*)(U + ((size_t)a * NQ_ + i) * 512 + 256 + n0);
    #pragma unroll
    for (int q = 0; q < 8; ++q) acc[q] += bf2f(v[q]);
  }
  short yv[8];
  #pragma unroll
  for (int q = 0; q < 8; ++q) yv[q] = f2bf(fmaxf(acc[q], 0.f));
  *(s8v*)(fh1 + (size_t)i * 256 + n0) = *(s8v*)yv;
}

// ---------------- epilogues: thread-per-row, no cross-lane reductions ----------------
__global__ __launch_bounds__(256) void logits2_k(const short* __restrict__ fqbase,
                                                 const float* __restrict__ protos_all,
                                                 const float* __restrict__ pnorm,
                                                 const bf16* __restrict__ c2all,
                                                 const void* __restrict__ w3,
                                                 const void* __restrict__ b3,
                                                 float* __restrict__ out,
                                                 const int* __restrict__ flags) {
  const int fW = flags[55], fB = flags[56];
  const int a = blockIdx.y;
  const int i = blockIdx.x * 256 + threadIdx.x;
  __shared__ float ps[NWAY_][E_];
  __shared__ float w3s[128];
  for (int t = threadIdx.x; t < NWAY_ * E_; t += 256)
    ps[t >> 8][t & 255] = protos_all[(size_t)a * NWAY_ * E_ + t];
  if (threadIdx.x < 128) w3s[threadIdx.x] = ldw(w3, (size_t)a * 128 + threadIdx.x, fW);
  __syncthreads();
  const short* fq = fqbase + (size_t)a * FSTR + (size_t)i * E_;
  float qq = 0.f, dt0 = 0.f, dt1 = 0.f, dt2 = 0.f, dt3 = 0.f, dt4 = 0.f;
  for (int e0 = 0; e0 < E_; e0 += 8) {
    s8v v = *(const s8v*)(fq + e0);
    #pragma unroll
    for (int q = 0; q < 8; ++q) {
      float x = bf2f(v[q]); int e = e0 + q;
      qq += x * x;
      dt0 += x * ps[0][e]; dt1 += x * ps[1][e]; dt2 += x * ps[2][e];
      dt3 += x * ps[3][e]; dt4 += x * ps[4][e];
    }
  }
  const short* c2 = (const short*)c2all + ((size_t)a * NQ_ + i) * 128;
  float conf = 0.f;
  for (int e0 = 0; e0 < 128; e0 += 8) {
    s8v v = *(const s8v*)(c2 + e0);
    #pragma unroll
    for (int q = 0; q < 8; ++q) conf += bf2f(v[q]) * w3s[e0 + q];
  }
  conf += ldw(b3, a, fB);
  float dts[5] = { dt0, dt1, dt2, dt3, dt4 };
  float* o = out + ((size_t)a * NQ_ + i) * NWAY_;
  #pragma unroll
  for (int c = 0; c < NWAY_; ++c) {
    float pp = pnorm[a * NWAY_ + c];
    float d2 = fmaxf(qq + pp - 2.f * dts[c], 1e-12f);
    o[c] = -sqrtf(d2) + 0.1f * conf;
  }
}

__global__ __launch_bounds__(256) void fused2_k(const float* __restrict__ h2, const void* __restrict__ w3,
                                                const void* __restrict__ b3, float* __restrict__ out,
                                                const int* __restrict__ flags) {
  const int fW = flags[62], fB = flags[63];
  int i = blockIdx.x * 256 + threadIdx.x;
  __shared__ float ws[128];
  if (threadIdx.x < 128) ws[threadIdx.x] = ldw(w3, threadIdx.x, fW);
  __syncthreads();
  const float* h = h2 + (size_t)i * 128;
  float s = 0.f;
  for (int e = 0; e < 128; e += 4) {
    float4 v = *(const float4*)(h + e);
    s += v.x * ws[e] + v.y * ws[e + 1] + v.z * ws[e + 2] + v.w * ws[e + 3];
  }
  out[i] = s + ldw(b3, 0, fB);
}

// ---------------- host ----------------
extern "C" void kernel_launch(void* const* d_in, const int* in_sizes, int n_in,
                              void* d_out, int out_size, void* d_ws, size_t ws_size,
                              hipStream_t stream) {
  (void)out_size; (void)ws_size;
  #define P(i) ((const void*)d_in[i])
  const int* support_y = (const int*)d_in[1];
  float* out = (float*)d_out;

  int* flags = (int*)d_ws;
  char* base = (char*)d_ws + 256;
  short* featsC = (short*)base;                        // bf16 [A][NM][E]
  char* R = base + (size_t)A_ * FSTR * 2;
  short* t1cat   = (short*)R;                          // [NM][2304] bf16
  short* qkv_all = (short*)R;                          // [A][NS][768] bf16
  short* U       = (short*)(R + (size_t)15728640);     // [A][NQ][512] bf16
  short* fh1     = (short*)R;                          // [NQ][256] bf16
  float* fh2     = (float*)(R + (size_t)8388608);      // [NQ][128] f32
  char* XCR = R + (size_t)57671680;
  short* XC   = (short*)XCR;
  short* tmp2 = (short*)XCR;
  short* b4   = (short*)(XCR + (size_t)NM_ * 256 * 2);
  short* clsC2_all = (short*)XCR;
  char* S = XCR + (size_t)10485760;
  float* state      = (float*)S;
  float* msg        = state + A_ * E_;
  float* ck         = msg + A_ * E_;
  float* protos_all = ck + A_ * E_;
  float* biascat2   = protos_all + A_ * NWAY_ * E_;
  float* ml         = biascat2 + A_ * 512;
  float* colsum     = ml + (size_t)A_ * 2 * NS_ * 2;
  float* proto_pre  = colsum + (size_t)A_ * 2 * NS_;
  int*   idx        = (int*)(proto_pre + A_ * NWAY_ * E_);
  int*   cnt        = idx + NWAY_ * NS_;
  int*   cstart     = cnt + NWAY_;
  float* statepart  = (float*)(cstart + NWAY_ + 3);
  float* mvp        = statepart + A_ * 16 * E_;
  float* qkvc       = mvp + A_ * 8 * E_;
  float* obar       = qkvc + A_ * 4 * 768;
  float* comb       = obar + A_ * E_;
  float* hh         = comb + A_ * E_;
  float* ckb        = hh + A_ * E_;
  float* ppart      = ckb + A_ * 768;                  // reused as pnorm (25 floats)
  float* bcat       = ppart + (size_t)A_ * NWAY_ * PCH * E_;
  short* Wcat       = (short*)(bcat + 2304);
  short* Bcat2      = Wcat + (size_t)2304 * 512;
  short* W2         = Bcat2 + (size_t)A_ * 512 * 256;  // converted TRB bf16 weights (~3.7 MB)

  const short* fq_base = featsC + (size_t)NS_ * E_;

  Ptrs ps;
  for (int i = 0; i < 64; ++i) {
    ps.p[i] = (i < n_in) ? d_in[i] : nullptr;
    ps.sz[i] = (i < n_in) ? in_sizes[i] : 0;
  }
  probe_k<<<64, 64, 0, stream>>>(ps, flags);
  classidx_k<<<1, 256, 0, stream>>>(support_y, idx, cnt, cstart);
  xcopy_k<<<(NM_ * 512 / 4) / 256, 256, 0, stream>>>(P(0), P(2), XC, flags);
  wcat_k<<<dim3(9, 512), 256, 0, stream>>>(ps, Wcat, bcat, flags);
  wcls_k<<<dim3(512, A_), 256, 0, stream>>>(P(51), P(58), Bcat2, flags);
  wconv_k<<<dim3(960, 9), 256, 0, stream>>>(ps, W2, flags);

  // ---- FE: mega layer-1 GEMM (N = 2304), per-tile act map; GDB gload-dbuf path ----
  gemm<2, 2, false, true, 0, false, false, true, true>(
      stream, XC, 512, Wcat, 512, 0, bcat, 0, (float*)t1cat, 2304,
      NM_, 2304, 512, 1.f, -1, -1, -1, flags, 1, 0, 0, 0, 0, 0, 0x555555000ULL);
  lnv_k<1, 512><<<NM_ / 4, 256, 0, stream>>>(t1cat, P(6), P(7), t1cat, 2304, 2304, 6, 7, flags);
  gemm<2, 2, true, true, 0, false, false, true>(stream, t1cat, 2304, W2 + 0, 512, 0, P(9), 0,
                                                (float*)tmp2, 256, NM_, 256, 512, 1.f, -1, -1, 9, flags);
  lnv_k<1, 256><<<NM_ / 4, 256, 0, stream>>>(tmp2, P(10), P(11), featsC, 256, 256, 10, 11, flags);
  lnv_k<1, 256><<<NM_ / 4, 256, 0, stream>>>(t1cat + 512, P(14), P(15), t1cat + 512, 2304, 2304, 14, 15, flags);
  gemm<2, 2, true, true, 2, false, false, true>(stream, t1cat + 512, 2304, W2 + 131072, 256, 0, P(17), 0,
                                                (float*)(featsC + FSTR), 256, NM_, 256, 256, 1.f, -1, -1, 17, flags);
  gemm<2, 2, true, true, 0, false, false, true>(stream, t1cat + 768, 2304, W2 + 196608, 768, 0, P(21), 0,
                                                (float*)tmp2, 256, NM_, 256, 768, 1.f, -1, -1, 21, flags);
  lnv_k<1, 256><<<NM_ / 4, 256, 0, stream>>>(tmp2, P(22), P(23), featsC + 2 * FSTR, 256, 256, 22, 23, flags);
  gemm<2, 2, true, true, 0, false, false, true>(stream, t1cat + 1536, 2304, W2 + 393216, 256, 0, P(27), 0,
                                                (float*)tmp2, 256, NM_, 256, 256, 1.f, -1, -1, 27, flags);
  lnv_k<3, 256><<<NM_ / 4, 256, 0, stream>>>(tmp2, P(28), P(29), featsC + 3 * FSTR, 256, 256, 28, 29, flags);
  gemm<2, 2, true, true, 1, false, false, true>(stream, t1cat + 1792, 2304, W2 + 458752, 512, 0, P(33), 0,
                                                (float*)b4, 256, NM_, 256, 512, 1.f, -1, -1, 33, flags);
  gemm<2, 2, true, true, 0, false, false, true>(stream, b4, 256, W2 + 589824, 256, 0, P(35), 0,
                                                (float*)(featsC + 4 * FSTR), 256, NM_, 256, 256, 1.f, -1, -1, 35, flags);

  // ---- comm round ----
  statepart_k<<<dim3(A_, 16), 256, 0, stream>>>(featsC, statepart);
  statecomb_k<<<A_, 256, 0, stream>>>(statepart, P(46), state, flags);
  mvpart_k<<<dim3(A_, 8), 256, 0, stream>>>(state, P(36), 36, mvp, flags);
  mvcomb_k<2><<<A_, 256, 0, stream>>>(mvp, P(37), 37, msg, flags);
  qkvcomm_k<<<A_ * 768 / 4, 256, 0, stream>>>(msg, P(57), P(38), P(39), qkvc, flags);
  attn4_k<<<A_, 256, 0, stream>>>(qkvc, obar);
  combproj_k<<<A_ * E_ / 4, 256, 0, stream>>>(obar, P(40), P(41), P(46), comb, flags);
  mvpart_k<<<dim3(A_, 8), 256, 0, stream>>>(comb, P(42), 42, mvp, flags);
  mvcomb_k<1><<<A_, 256, 0, stream>>>(mvp, P(43), 43, hh, flags);
  mvpart_k<<<dim3(A_, 8), 256, 0, stream>>>(hh, P(44), 44, mvp, flags);
  mvcomb_k<0><<<A_, 256, 0, stream>>>(mvp, P(45), 45, ck, flags);

  // ---- batched prototype attention (ck folded into qkv bias; qkv bf16, GDB path) ----
  ckb_k<<<A_ * 768 / 4, 256, 0, stream>>>(ck, P(47), P(48), ckb, flags);
  gemm<2, 2, false, true, 0, false, false, true>(stream, featsC, 256, W2 + 851968, 256, 0, ckb, 0,
                                    (float*)qkv_all, 768, NS_, 768, 256, 1.f, -1, -1, -1, flags,
                                    A_, FSTR, (size_t)768 * 256, (size_t)768, (size_t)NS_ * 768);
  {
    dim3 g(NWAY_, NS_ / 64, A_ * 2);
    attn_stats_k<<<g, 256, 0, stream>>>(qkv_all, idx, cnt, cstart, ml);
    attn_colsum_k<<<g, 256, 0, stream>>>(qkv_all, idx, cnt, cstart, ml, colsum);
  }
  proto_reduce_k<<<dim3(NWAY_, A_), 1024, 0, stream>>>(qkv_all, idx, cnt, cstart, colsum, proto_pre);
  proto_outproj_k<<<dim3(NWAY_, A_), 256, 0, stream>>>(proto_pre, P(49), P(50), cnt, protos_all, ppart, flags);
  bias2_k<<<A_, 256, 0, stream>>>(ck, P(51), P(52), biascat2, flags);

  // ---- combined cls1 + fusion-partial GEMM (GDB gload-dbuf path) ----
  gemm<2, 2, false, true, 0, false, false, true, true>(
      stream, fq_base, 256, Bcat2, 256, 0, biascat2, 0, (float*)U, 512,
      NQ_, 512, 256, 1.f, -1, -1, -1, flags,
      A_, FSTR, (size_t)512 * 256, (size_t)512, (size_t)NQ_ * 512, 0, 0x5ULL);
  fcomb2_k<<<NQ_ / 8, 256, 0, stream>>>(U, P(59), fh1, flags);

  // ---- cls2 + logits ----
  gemm<2, 2, true, true, 1, false, false, true>(stream, U, 512, W2 + 655360, 256, 0,
                                     P(54), 0, (float*)clsC2_all, 128, NQ_, 128, 256, 1.f, -1, -1, 54, flags,
                                     A_, (size_t)NQ_ * 512, (size_t)128 * 256, (size_t)128, (size_t)NQ_ * 128);
  logits2_k<<<dim3(NQ_ / 256, A_), 256, 0, stream>>>(fq_base, protos_all, ppart,
                                                     (const bf16*)clsC2_all, P(55), P(56), out, flags);

  // ---- fusion layer-2 + output ----
  gemm<2, 2, true, true, 1, false>(stream, fh1, 256, W2 + 819200, 256, 0, P(61), 0, fh2, 128,
                                   NQ_, 128, 256, 1.f, -1, -1, 61, flags);
  fused2_k<<<NQ_ / 256, 256, 0, stream>>>(fh2, P(62), P(63), out + (size_t)A_ * NQ_ * NWAY_, flags);
}

// Round 12
// 735.020 us; speedup vs baseline: 1.1455x; 1.0926x over previous
//
#include <hip/hip_runtime.h>
#include <hip/hip_bf16.h>

typedef __hip_bfloat16 bf16;
typedef short s8v __attribute__((ext_vector_type(8)));
typedef short s4v __attribute__((ext_vector_type(4)));
typedef float f4v __attribute__((ext_vector_type(4)));

#define A_  5
#define D_  512
#define E_  256
#define NS_ 2048
#define NQ_ 8192
#define NM_ 10240
#define NWAY_ 5
#define QSCALE 0.088388347648318447f
#define FSTR ((size_t)NM_ * E_)

__device__ inline float ldw(const void* p, size_t i, int f32) {
  return f32 ? ((const float*)p)[i] : __bfloat162float(((const bf16*)p)[i]);
}
template<bool DYN>
__device__ inline float ldT(const void* p, size_t i, int f32) {
  if (DYN) return ldw(p, i, f32);
  return ((const float*)p)[i];
}

__device__ inline short f2bf(float v) {
  union { float f; unsigned u; } x; x.f = v;
  unsigned r = x.u + 0x7fffu + ((x.u >> 16) & 1u);
  return (short)(r >> 16);
}
__device__ inline float bf2f(short s) {
  union { unsigned u; float f; } x; x.u = ((unsigned)(unsigned short)s) << 16;
  return x.f;
}

// async global->LDS, 16B per lane; lds dest = base + lane*16 (wave-uniform base)
__device__ __forceinline__ void gload16(const void* g, void* l) {
  __builtin_amdgcn_global_load_lds(
      (const __attribute__((address_space(1))) unsigned int*)g,
      (__attribute__((address_space(3))) unsigned int*)l, 16, 0, 0);
}

struct Ptrs { const void* p[64]; int sz[64]; };

__global__ void probe_k(Ptrs P, int* flags) {
  int b = blockIdx.x, lane = threadIdx.x;
  if (b == 1 || b == 3) { if (lane == 0) flags[b] = 0; return; }
  const bf16* t = (const bf16*)P.p[b];
  int n = P.sz[b];
  int K = (n >> 1) < 64 ? (n >> 1) : 64;
  bool big = false, eNZ = false, oNZ = false;
  if (lane < K) {
    float e = __bfloat162float(t[2 * lane]);
    float o = __bfloat162float(t[2 * lane + 1]);
    big = !(fabsf(e) <= 1e3f);
    eNZ = (e != 0.f); oNZ = (o != 0.f);
  }
  unsigned long long bb = __ballot(big), eb = __ballot(eNZ), ob = __ballot(oNZ);
  if (lane == 0) flags[b] = (bb != 0ull || (eb == 0ull && ob != 0ull)) ? 1 : 0;
}

__global__ void classidx_k(const int* __restrict__ y, int* __restrict__ idx,
                           int* __restrict__ cnt, int* __restrict__ cstart) {
  __shared__ int sc[NWAY_];
  int tid = threadIdx.x;
  if (tid < NWAY_) sc[tid] = 0;
  __syncthreads();
  for (int i = tid; i < NS_; i += 256) {
    int c = y[i];
    int pos = atomicAdd(&sc[c], 1);
    idx[c * NS_ + pos] = i;
  }
  __syncthreads();
  if (tid < NWAY_) cnt[tid] = sc[tid];
  if (tid == 0) { int s = 0; for (int q = 0; q < NWAY_; ++q) { cstart[q] = s; s += sc[q]; } }
}

__global__ void xcopy_k(const void* __restrict__ sx, const void* __restrict__ qx,
                        short* __restrict__ XC, const int* __restrict__ flags) {
  size_t i = ((size_t)blockIdx.x * 256 + threadIdx.x) * 4;
  const size_t SN = (size_t)NS_ * 512;
  if (i < SN) {
    int f = flags[0];
    #pragma unroll
    for (int q = 0; q < 4; ++q) XC[i + q] = f2bf(ldw(sx, i + q, f));
  } else {
    int f = flags[2];
    size_t j = i - SN;
    #pragma unroll
    for (int q = 0; q < 4; ++q) XC[i + q] = f2bf(ldw(qx, j + q, f));
  }
}

// ---- concat 5 layer-1 weights into Wcat[2304][512] bf16 (TRB layout) + bias cat ----
__global__ void wcat_k(Ptrs P, short* __restrict__ Wcat, float* __restrict__ bcat,
                       const int* __restrict__ flags) {
  int n = blockIdx.x * 256 + threadIdx.x;
  int k = blockIdx.y;
  int iw, ib, nl, Nloc;
  if (n < 512)       { iw = 4;  ib = 5;  nl = n;        Nloc = 512; }
  else if (n < 768)  { iw = 12; ib = 13; nl = n - 512;  Nloc = 256; }
  else if (n < 1536) { iw = 18; ib = 19; nl = n - 768;  Nloc = 768; }
  else if (n < 1792) { iw = 24; ib = 25; nl = n - 1536; Nloc = 256; }
  else               { iw = 30; ib = 31; nl = n - 1792; Nloc = 512; }
  Wcat[(size_t)n * 512 + k] = f2bf(ldw(P.p[iw], (size_t)k * Nloc + nl, flags[iw]));
  if (k == 0) bcat[n] = ldw(P.p[ib], nl, flags[ib]);
}

// ---- Bcat2[a][n][k] bf16 ----
__global__ void wcls_k(const void* __restrict__ cw1, const void* __restrict__ fw1,
                       short* __restrict__ B2, const int* __restrict__ flags) {
  int n = blockIdx.x, a = blockIdx.y, k = threadIdx.x;
  float v;
  if (n < 256) v = ldw(cw1, ((size_t)a * 512 + k) * 256 + n, flags[51]);
  else v = ldw(fw1, ((size_t)(a * 256 + k)) * 256 + (n - 256), flags[58]);
  B2[((size_t)a * 512 + n) * 256 + k] = f2bf(v);
}

// ---- convert/transpose remaining weights to bf16 TRB [N][K] into W2 ----
__global__ void wconv_k(Ptrs P, short* __restrict__ W2, const int* __restrict__ flags) {
  const int id = blockIdx.y;
  int src, K, N; size_t off; int tr, batch;
  switch (id) {
    case 0: src = 8;  K = 512; N = 256; off = 0;      tr = 1; batch = 1;  break;
    case 1: src = 16; K = 256; N = 256; off = 131072; tr = 1; batch = 1;  break;
    case 2: src = 20; K = 768; N = 256; off = 196608; tr = 1; batch = 1;  break;
    case 3: src = 26; K = 256; N = 256; off = 393216; tr = 1; batch = 1;  break;
    case 4: src = 32; K = 512; N = 256; off = 458752; tr = 1; batch = 1;  break;
    case 5: src = 34; K = 256; N = 256; off = 589824; tr = 1; batch = 1;  break;
    case 6: src = 53; K = 256; N = 128; off = 655360; tr = 1; batch = A_; break;
    case 7: src = 60; K = 256; N = 128; off = 819200; tr = 1; batch = 1;  break;
    default: src = 47; K = 256; N = 768; off = 851968; tr = 0; batch = A_; break;
  }
  size_t tot = (size_t)batch * K * N;
  size_t e0 = ((size_t)blockIdx.x * 256 + threadIdx.x) * 4;
  if (e0 >= tot) return;
  const void* sp = P.p[src];
  int f = flags[src];
  if (!tr) {
    #pragma unroll
    for (int q = 0; q < 4; ++q) W2[off + e0 + q] = f2bf(ldw(sp, e0 + q, f));
  } else {
    size_t kn = (size_t)K * N;
    #pragma unroll
    for (int q = 0; q < 4; ++q) {
      size_t e = e0 + q;
      int b = (int)(e / kn);
      int r = (int)(e % kn);
      int n = r / K, k = r % K;
      W2[off + e] = f2bf(ldw(sp, ((size_t)b * K + k) * N + n, f));
    }
  }
}

// ============ MFMA bf16 GEMM (128x128, 4-wave) ============
#define LSTR 40
template<int AMODE, int BMODE, bool DYNBIAS, bool TRB, int ACT, bool ACCUM,
         bool KSPLIT = false, bool OUTBF16 = false, bool DOMAP = false>
__global__ __launch_bounds__(256) void gemm_k(
    const void* __restrict__ A, int lda,
    const void* __restrict__ B, int ldb, size_t offB,
    const void* __restrict__ bias, size_t offBias,
    float* __restrict__ C, int ldc,
    int M, int N, int K, float alpha,
    int ia, int ib, int ibias, const int* __restrict__ flags,
    size_t sA, size_t sB, size_t sBias, size_t sC, size_t kstrideA,
    unsigned long long amap)
{
  constexpr bool GDB = (AMODE == 2) && (BMODE == 2) && TRB && !KSPLIT;
  const int fA = (AMODE == 1) ? flags[ia] : 1;
  const int fB = (BMODE == 1) ? flags[ib] : 1;
  const int fBi = DYNBIAS ? flags[ibias] : 1;
  const size_t zA = (size_t)blockIdx.z * sA;
  const size_t zB = offB + (size_t)blockIdx.z * sB;
  const size_t zBias = offBias + (size_t)blockIdx.z * sBias;
  float* Cz = C + (size_t)blockIdx.z * sC;
  bf16* Cz16 = (bf16*)C + (size_t)blockIdx.z * sC;
  const int tid = threadIdx.x;
  const int bm = blockIdx.y * 128, bn = blockIdx.x * 128;
  const int lane = tid & 63, wid = tid >> 6;
  const int lm = lane & 15, quad = lane >> 4;
  const int wy = (wid >> 1) * 64, wx = (wid & 1) * 64;
  f4v acc[4][4];
  #pragma unroll
  for (int i = 0; i < 4; ++i)
    #pragma unroll
    for (int j = 0; j < 4; ++j) acc[i][j] = (f4v)(0.f);

  if constexpr (GDB) {
    __shared__ short smem[4 * 128 * 32];   // 32 KB: [A0|A1|B0|B1]
    const int srow = lane >> 2, scol = (lane & 3) * 8;
    const short* Azs = (const short*)A + zA;
    const short* Bzs = (const short*)B + zB;
    auto stage = [&](int bsel, int k0) {
      short* Asb = smem + bsel * 4096;
      short* Bsb = smem + 8192 + bsel * 4096;
      #pragma unroll
      for (int q = 0; q < 2; ++q) {
        int rb = (wid * 2 + q) * 16;
        gload16(Azs + (size_t)(bm + rb + srow) * lda + k0 + scol, Asb + rb * 32);
        gload16(Bzs + (size_t)(bn + rb + srow) * ldb + k0 + scol, Bsb + rb * 32);
      }
    };
    stage(0, 0);
    __syncthreads();
    int cur = 0;
    for (int k0 = 0; k0 < K; k0 += 32) {
      if (k0 + 32 < K) stage(cur ^ 1, k0 + 32);   // loads fly across MFMA
      const short* Asb = smem + cur * 4096;
      const short* Bsb = smem + 8192 + cur * 4096;
      s8v af[4], bfr[4];
      #pragma unroll
      for (int mi = 0; mi < 4; ++mi)
        af[mi] = *(const s8v*)&Asb[(wy + mi*16 + lm) * 32 + quad * 8];
      #pragma unroll
      for (int ni = 0; ni < 4; ++ni)
        bfr[ni] = *(const s8v*)&Bsb[(wx + ni*16 + lm) * 32 + quad * 8];
      #pragma unroll
      for (int mi = 0; mi < 4; ++mi)
        #pragma unroll
        for (int ni = 0; ni < 4; ++ni)
          acc[mi][ni] = __builtin_amdgcn_mfma_f32_16x16x32_bf16(af[mi], bfr[ni], acc[mi][ni], 0, 0, 0);
      __syncthreads();
      cur ^= 1;
    }
  } else {
    __shared__ short As[128 * LSTR];
    __shared__ short Bs[128 * LSTR];
    const int am = tid >> 1, ah = (tid & 1) * 16;

    s8v a_s0, a_s1;
    float a_f[16];
    s8v b_s0, b_s1;
    float b_f[16];
    short b_h[16];

    auto loadA = [&](int k0) {
      int kk = k0 + ah;
      size_t base;
      if (KSPLIT) base = zA + (size_t)(kk >> 8) * kstrideA + (size_t)(bm + am) * lda + (kk & 255);
      else base = zA + (size_t)(bm + am) * lda + kk;
      if constexpr (AMODE == 2) {
        const bf16* ap = (const bf16*)A + base;
        a_s0 = *(const s8v*)ap;
        a_s1 = *(const s8v*)(ap + 8);
      } else {
        if (fA) {
          const float4* src = (const float4*)((const float*)A + base);
          #pragma unroll
          for (int q = 0; q < 4; ++q) {
            float4 v = src[q];
            a_f[q*4] = v.x; a_f[q*4+1] = v.y; a_f[q*4+2] = v.z; a_f[q*4+3] = v.w;
          }
        } else {
          #pragma unroll
          for (int q = 0; q < 16; ++q) a_f[q] = ldw(A, base + q, 0);
        }
      }
    };
    auto storeA = [&]() {
      if constexpr (AMODE == 2) {
        *(s8v*)&As[am * LSTR + ah] = a_s0;
        *(s8v*)&As[am * LSTR + ah + 8] = a_s1;
      } else {
        short tmp[16];
        #pragma unroll
        for (int q = 0; q < 16; ++q) tmp[q] = f2bf(a_f[q]);
        s4v* dst = (s4v*)&As[am * LSTR + ah];
        #pragma unroll
        for (int q = 0; q < 4; ++q) dst[q] = *(s4v*)&tmp[q*4];
      }
    };
    auto loadB = [&](int k0) {
      if constexpr (TRB) {
        int n = tid >> 1, h = (tid & 1) * 16;
        size_t base = zB + (size_t)(bn + n) * ldb + k0 + h;
        if constexpr (BMODE == 2) {
          const bf16* bp = (const bf16*)B + base;
          b_s0 = *(const s8v*)bp;
          b_s1 = *(const s8v*)(bp + 8);
        } else {
          if (fB) {
            const float4* src = (const float4*)((const float*)B + base);
            #pragma unroll
            for (int q = 0; q < 4; ++q) {
              float4 v = src[q];
              b_f[q*4] = v.x; b_f[q*4+1] = v.y; b_f[q*4+2] = v.z; b_f[q*4+3] = v.w;
            }
          } else {
            #pragma unroll
            for (int q = 0; q < 16; ++q) b_f[q] = ldw(B, base + q, 0);
          }
        }
      } else {
        int n = tid & 127, kk2 = (tid >> 7) * 16;
        #pragma unroll
        for (int j = 0; j < 16; ++j) {
          size_t bi = zB + (size_t)(k0 + kk2 + j) * ldb + bn + n;
          if constexpr (BMODE == 2) b_h[j] = ((const short*)B)[bi];
          else b_f[j] = ldT<BMODE == 1>(B, bi, fB);
        }
      }
    };
    auto storeB = [&]() {
      if constexpr (TRB) {
        int n = tid >> 1, h = (tid & 1) * 16;
        if constexpr (BMODE == 2) {
          *(s8v*)&Bs[n * LSTR + h] = b_s0;
          *(s8v*)&Bs[n * LSTR + h + 8] = b_s1;
        } else {
          short tmp[16];
          #pragma unroll
          for (int q = 0; q < 16; ++q) tmp[q] = f2bf(b_f[q]);
          s4v* dst = (s4v*)&Bs[n * LSTR + h];
          #pragma unroll
          for (int q = 0; q < 4; ++q) dst[q] = *(s4v*)&tmp[q*4];
        }
      } else {
        int n = tid & 127, kk2 = (tid >> 7) * 16;
        short tmp[16];
        #pragma unroll
        for (int j = 0; j < 16; ++j) tmp[j] = (BMODE == 2) ? b_h[j] : f2bf(b_f[j]);
        s4v* dst = (s4v*)&Bs[n * LSTR + kk2];
        #pragma unroll
        for (int q = 0; q < 4; ++q) dst[q] = *(s4v*)&tmp[q*4];
      }
    };

    loadA(0);
    loadB(0);
    for (int k0 = 0; k0 < K; k0 += 32) {
      storeA();
      storeB();
      __syncthreads();
      if (k0 + 32 < K) { loadA(k0 + 32); loadB(k0 + 32); }
      s8v af[4], bfr[4];
      #pragma unroll
      for (int mi = 0; mi < 4; ++mi)
        af[mi] = *(const s8v*)&As[(wy + mi*16 + lm) * LSTR + quad * 8];
      #pragma unroll
      for (int ni = 0; ni < 4; ++ni)
        bfr[ni] = *(const s8v*)&Bs[(wx + ni*16 + lm) * LSTR + quad * 8];
      #pragma unroll
      for (int mi = 0; mi < 4; ++mi)
        #pragma unroll
        for (int ni = 0; ni < 4; ++ni)
          acc[mi][ni] = __builtin_amdgcn_mfma_f32_16x16x32_bf16(af[mi], bfr[ni], acc[mi][ni], 0, 0, 0);
      __syncthreads();
    }
  }

  const int actc = DOMAP ? (int)((amap >> (((bn + wx) >> 7) * 2)) & 3ULL) : ACT;
  #pragma unroll
  for (int mi = 0; mi < 4; ++mi) {
    #pragma unroll
    for (int r = 0; r < 4; ++r) {
      int row = bm + wy + mi*16 + quad*4 + r;
      #pragma unroll
      for (int ni = 0; ni < 4; ++ni) {
        int col = bn + wx + ni*16 + lm;
        float v = acc[mi][ni][r] * alpha;
        if (ACCUM) v += Cz[(size_t)row * ldc + col];
        if (bias) v += ldT<DYNBIAS>(bias, zBias + col, fBi);
        if (actc == 1) v = fmaxf(v, 0.f);
        else if (actc == 2) v = tanhf(v);
        else if (actc == 3) v = 1.f / (1.f + expf(-v));
        if (OUTBF16) Cz16[(size_t)row * ldc + col] = __float2bfloat16(v);
        else Cz[(size_t)row * ldc + col] = v;
      }
    }
  }
}

template<int AMODE, int BMODE, bool DYNBIAS, bool TRB, int ACT, bool ACCUM,
         bool KSPLIT = false, bool OUTBF16 = false, bool DOMAP = false>
static void gemm(hipStream_t s, const void* A, int lda, const void* B, int ldb, size_t offB,
                 const void* bias, size_t offBias, float* C, int ldc, int M, int N, int K,
                 float alpha, int ia, int ib, int ibias, const int* flags,
                 int batch = 1, size_t sA = 0, size_t sB = 0, size_t sBias = 0, size_t sC = 0,
                 size_t kstrideA = 0, unsigned long long amap = 0) {
  dim3 g(N / 128, M / 128, batch), b(256);
  gemm_k<AMODE, BMODE, DYNBIAS, TRB, ACT, ACCUM, KSPLIT, OUTBF16, DOMAP><<<g, b, 0, s>>>(
      A, lda, B, ldb, offB, bias, offBias, C, ldc, M, N, K, alpha, ia, ib, ibias, flags,
      sA, sB, sBias, sC, kstrideA, amap);
}

// ============ z-batched FE layer-2 GEMM: 5 independent M=10240,N=256 GEMMs in one launch ============
struct MG5 {
  const short* A[5]; int K[5];
  const short* B[5];
  const void* bias[5]; int ib[5];
  short* C[5]; int act[5];
};

__global__ __launch_bounds__(256) void gemm5_k(MG5 P, const int* __restrict__ flags) {
  const int z = blockIdx.z;
  const short* A = P.A[z];
  const short* B = P.B[z];
  const int K = P.K[z];
  const int ldb = K;
  const int actc = P.act[z];
  const int fBi = flags[P.ib[z]];
  const void* bias = P.bias[z];
  short* C = P.C[z];
  __shared__ short smem[4 * 128 * 32];   // 32 KB: [A0|A1|B0|B1]
  const int tid = threadIdx.x;
  const int bm = blockIdx.y * 128, bn = blockIdx.x * 128;
  const int lane = tid & 63, wid = tid >> 6;
  const int lm = lane & 15, quad = lane >> 4;
  const int wy = (wid >> 1) * 64, wx = (wid & 1) * 64;
  const int srow = lane >> 2, scol = (lane & 3) * 8;
  f4v acc[4][4];
  #pragma unroll
  for (int i = 0; i < 4; ++i)
    #pragma unroll
    for (int j = 0; j < 4; ++j) acc[i][j] = (f4v)(0.f);

  auto stage = [&](int bsel, int k0) {
    short* Asb = smem + bsel * 4096;
    short* Bsb = smem + 8192 + bsel * 4096;
    #pragma unroll
    for (int q = 0; q < 2; ++q) {
      int rb = (wid * 2 + q) * 16;
      gload16(A + (size_t)(bm + rb + srow) * 2304 + k0 + scol, Asb + rb * 32);
      gload16(B + (size_t)(bn + rb + srow) * ldb + k0 + scol, Bsb + rb * 32);
    }
  };
  stage(0, 0);
  __syncthreads();
  int cur = 0;
  for (int k0 = 0; k0 < K; k0 += 32) {
    if (k0 + 32 < K) stage(cur ^ 1, k0 + 32);   // loads fly across MFMA
    const short* Asb = smem + cur * 4096;
    const short* Bsb = smem + 8192 + cur * 4096;
    s8v af[4], bfr[4];
    #pragma unroll
    for (int mi = 0; mi < 4; ++mi)
      af[mi] = *(const s8v*)&Asb[(wy + mi*16 + lm) * 32 + quad * 8];
    #pragma unroll
    for (int ni = 0; ni < 4; ++ni)
      bfr[ni] = *(const s8v*)&Bsb[(wx + ni*16 + lm) * 32 + quad * 8];
    #pragma unroll
    for (int mi = 0; mi < 4; ++mi)
      #pragma unroll
      for (int ni = 0; ni < 4; ++ni)
        acc[mi][ni] = __builtin_amdgcn_mfma_f32_16x16x32_bf16(af[mi], bfr[ni], acc[mi][ni], 0, 0, 0);
    __syncthreads();
    cur ^= 1;
  }

  #pragma unroll
  for (int mi = 0; mi < 4; ++mi) {
    #pragma unroll
    for (int r = 0; r < 4; ++r) {
      int row = bm + wy + mi*16 + quad*4 + r;
      #pragma unroll
      for (int ni = 0; ni < 4; ++ni) {
        int col = bn + wx + ni*16 + lm;
        float v = acc[mi][ni][r] + ldw(bias, col, fBi);
        if (actc == 1) v = fmaxf(v, 0.f);
        else if (actc == 2) v = tanhf(v);
        C[(size_t)row * 256 + col] = f2bf(v);
      }
    }
  }
}

// ---------------- vectorized wave-per-row LayerNorm (+relu/sigmoid), bf16 in/out ----------------
template<int ACT, int W>
__global__ __launch_bounds__(256) void lnv_k(const short* __restrict__ X, const void* __restrict__ g,
                                             const void* __restrict__ be, short* __restrict__ Y,
                                             int ldx, int ldy,
                                             int ig, int ibe, const int* __restrict__ flags) {
  const int fG = flags[ig], fBe = flags[ibe];
  const int wid = threadIdx.x >> 6, lane = threadIdx.x & 63;
  const int row = blockIdx.x * 4 + wid;
  constexpr int V = W / 64;
  const short* x = X + (size_t)row * ldx + lane * V;
  float xv[V];
  if constexpr (V == 8) {
    s8v v = *(const s8v*)x;
    #pragma unroll
    for (int q = 0; q < 8; ++q) xv[q] = bf2f(v[q]);
  } else {
    s4v v = *(const s4v*)x;
    #pragma unroll
    for (int q = 0; q < 4; ++q) xv[q] = bf2f(v[q]);
  }
  float s1 = 0.f, s2 = 0.f;
  #pragma unroll
  for (int q = 0; q < V; ++q) { s1 += xv[q]; s2 += xv[q] * xv[q]; }
  #pragma unroll
  for (int o = 32; o > 0; o >>= 1) { s1 += __shfl_xor(s1, o); s2 += __shfl_xor(s2, o); }
  float mean = s1 * (1.f / W);
  float var = fmaxf(s2 * (1.f / W) - mean * mean, 0.f);
  float rstd = rsqrtf(var + 1e-5f);
  short yv[V];
  #pragma unroll
  for (int q = 0; q < V; ++q) {
    int i = lane * V + q;
    float v = (xv[q] - mean) * rstd * ldw(g, i, fG) + ldw(be, i, fBe);
    if (ACT == 1) v = fmaxf(v, 0.f);
    else if (ACT == 3) v = 1.f / (1.f + expf(-v));
    yv[q] = f2bf(v);
  }
  short* y = Y + (size_t)row * ldy + lane * V;
  if constexpr (V == 8) *(s8v*)y = *(s8v*)yv;
  else *(s4v*)y = *(s4v*)yv;
}

// ================= comm round =================
__global__ void statepart_k(const short* __restrict__ featsC, float* __restrict__ part) {
  int a = blockIdx.x, g = blockIdx.y, e = threadIdx.x;
  const short* p = featsC + (size_t)a * FSTR + ((size_t)g * 128) * E_ + e;
  float s = 0.f;
  for (int n = 0; n < 128; ++n) s += bf2f(p[(size_t)n * E_]);
  part[((size_t)a * 16 + g) * E_ + e] = s;
}

__global__ void statecomb_k(const float* __restrict__ part, const void* __restrict__ internal,
                            float* __restrict__ state, const int* __restrict__ flags) {
  int a = blockIdx.x, e = threadIdx.x;
  float s = 0.f;
  for (int g = 0; g < 16; ++g) s += part[((size_t)a * 16 + g) * E_ + e];
  state[a * E_ + e] = s * (1.f / NS_) + ldw(internal, (size_t)a * E_ + e, flags[46]);
}

__global__ void mvpart_k(const float* __restrict__ x, const void* __restrict__ W, int iw,
                         float* __restrict__ part, const int* __restrict__ flags) {
  int a = blockIdx.x, g = blockIdx.y, f = threadIdx.x;
  const int fW = flags[iw];
  float s = 0.f;
  size_t wb = (size_t)a * E_ * E_ + f;
  for (int e = g * 32; e < g * 32 + 32; ++e)
    s += x[a * E_ + e] * ldw(W, wb + (size_t)e * E_, fW);
  part[((size_t)a * 8 + g) * E_ + f] = s;
}

template<int ACT>
__global__ void mvcomb_k(const float* __restrict__ part, const void* __restrict__ b, int ibb,
                         float* __restrict__ y, const int* __restrict__ flags) {
  int a = blockIdx.x, f = threadIdx.x;
  float s = 0.f;
  for (int g = 0; g < 8; ++g) s += part[((size_t)a * 8 + g) * E_ + f];
  s += ldw(b, (size_t)a * E_ + f, flags[ibb]);
  if (ACT == 1) s = fmaxf(s, 0.f);
  else if (ACT == 2) s = tanhf(s);
  y[a * E_ + f] = s;
}

__device__ inline float wave_sum64(float v) {
  for (int o = 32; o > 0; o >>= 1) v += __shfl_down(v, o);
  return v;
}

__global__ __launch_bounds__(256) void qkvcomm_k(const float* __restrict__ msg,
                                                 const void* __restrict__ comm_w,
                                                 const void* __restrict__ in_w,
                                                 const void* __restrict__ in_b,
                                                 float* __restrict__ qkvc,
                                                 const int* __restrict__ flags) {
  const int fCW = flags[57], fIW = flags[38], fIB = flags[39];
  int gw = blockIdx.x * 4 + (threadIdx.x >> 6);
  int a = gw / 768, f = gw % 768;
  int lane = threadIdx.x & 63;
  float w[5]; float mx = -1e30f;
  for (int j = 0; j < 5; ++j) { w[j] = ldw(comm_w, a * 5 + j, fCW); mx = fmaxf(mx, w[j]); }
  float sum = 0.f;
  for (int j = 0; j < 5; ++j) { w[j] = __expf(w[j] - mx); sum += w[j]; }
  for (int j = 0; j < 5; ++j) w[j] /= sum;
  int others[4]; { int c = 0; for (int j = 0; j < 5; ++j) if (j != a) others[c++] = j; }
  int e0 = lane * 4;
  float4 wv;
  size_t b = (size_t)a * 768 * E_ + (size_t)f * E_ + e0;
  if (fIW) wv = *(const float4*)((const float*)in_w + b);
  else wv = make_float4(ldw(in_w, b, 0), ldw(in_w, b + 1, 0), ldw(in_w, b + 2, 0), ldw(in_w, b + 3, 0));
  float acc[4];
  #pragma unroll
  for (int t = 0; t < 4; ++t) {
    const float4 mv = *(const float4*)(msg + others[t] * E_ + e0);
    acc[t] = mv.x * wv.x + mv.y * wv.y + mv.z * wv.z + mv.w * wv.w;
  }
  #pragma unroll
  for (int t = 0; t < 4; ++t) acc[t] = wave_sum64(acc[t]);
  if (lane == 0) {
    float bb = ldw(in_b, (size_t)a * 768 + f, fIB);
    #pragma unroll
    for (int t = 0; t < 4; ++t)
      qkvc[((size_t)a * 4 + t) * 768 + f] = acc[t] * w[others[t]] + bb;
  }
}

__global__ __launch_bounds__(256) void attn4_k(const float* __restrict__ qkvc,
                                               float* __restrict__ obar) {
  int a = blockIdx.x, tid = threadIdx.x;
  __shared__ float qkv[4][768];
  __shared__ float attw[4][16];
  for (int i = tid; i < 4 * 768; i += 256) qkv[i / 768][i % 768] = qkvc[(size_t)a * 4 * 768 + i];
  __syncthreads();
  if (tid < 16) {
    int h = tid >> 2, t = tid & 3;
    float sc[4]; float mx = -1e30f;
    for (int t2 = 0; t2 < 4; ++t2) {
      float s = 0.f;
      for (int d = 0; d < 64; ++d) s += qkv[t][h * 64 + d] * qkv[t2][256 + h * 64 + d];
      sc[t2] = s * 0.125f; mx = fmaxf(mx, sc[t2]);
    }
    float ss = 0.f;
    for (int t2 = 0; t2 < 4; ++t2) { sc[t2] = __expf(sc[t2] - mx); ss += sc[t2]; }
    for (int t2 = 0; t2 < 4; ++t2) attw[h][t * 4 + t2] = sc[t2] / ss;
  }
  __syncthreads();
  {
    int e = tid, h = e >> 6;
    float s = 0.f;
    for (int t = 0; t < 4; ++t)
      for (int t2 = 0; t2 < 4; ++t2)
        s += attw[h][t * 4 + t2] * qkv[t2][512 + e];
    obar[a * E_ + e] = s * 0.25f;
  }
}

__global__ __launch_bounds__(256) void combproj_k(const float* __restrict__ obar,
                                                  const void* __restrict__ ow,
                                                  const void* __restrict__ ob,
                                                  const void* __restrict__ internal,
                                                  float* __restrict__ comb,
                                                  const int* __restrict__ flags) {
  const int fOW = flags[40], fOB = flags[41], fIN = flags[46];
  int gw = blockIdx.x * 4 + (threadIdx.x >> 6);
  int a = gw >> 8, f = gw & 255;
  int lane = threadIdx.x & 63;
  int e0 = lane * 4;
  float4 wv;
  size_t b = (size_t)a * E_ * E_ + (size_t)f * E_ + e0;
  if (fOW) wv = *(const float4*)((const float*)ow + b);
  else wv = make_float4(ldw(ow, b, 0), ldw(ow, b + 1, 0), ldw(ow, b + 2, 0), ldw(ow, b + 3, 0));
  const float4 ov = *(const float4*)(obar + a * E_ + e0);
  float s = wave_sum64(ov.x * wv.x + ov.y * wv.y + ov.z * wv.z + ov.w * wv.w);
  if (lane == 0)
    comb[a * E_ + f] = ldw(internal, (size_t)a * E_ + f, fIN) + s + ldw(ob, (size_t)a * E_ + f, fOB);
}

__global__ __launch_bounds__(256) void ckb_k(const float* __restrict__ ck,
                                             const void* __restrict__ in_w,
                                             const void* __restrict__ in_b,
                                             float* __restrict__ ckb,
                                             const int* __restrict__ flags) {
  const int fW = flags[47], fB = flags[48];
  int gw = blockIdx.x * 4 + (threadIdx.x >> 6);
  int a = gw / 768, f = gw % 768;
  int lane = threadIdx.x & 63;
  int e0 = lane * 4;
  float4 wv;
  size_t b = (size_t)a * 768 * E_ + (size_t)f * E_ + e0;
  if (fW) wv = *(const float4*)((const float*)in_w + b);
  else wv = make_float4(ldw(in_w, b, 0), ldw(in_w, b + 1, 0), ldw(in_w, b + 2, 0), ldw(in_w, b + 3, 0));
  const float4 cv = *(const float4*)(ck + a * E_ + e0);
  float s = wave_sum64(cv.x * wv.x + cv.y * wv.y + cv.z * wv.z + cv.w * wv.w);
  if (lane == 0) ckb[(size_t)a * 768 + f] = s + ldw(in_b, (size_t)a * 768 + f, fB);
}

// ======== MFMA class-block attention (qkv_all is bf16) ========
#define LS 136
__device__ inline void stage64x128(const short* __restrict__ qkv, const int* __restrict__ myidx,
                                   int row0, int n, int ho, short* dst) {
  int t = threadIdx.x;
  int r = t >> 2, c0 = (t & 3) * 32;
  int rr = row0 + r;
  s8v v0 = (s8v)(short)0, v1 = v0, v2 = v0, v3 = v0;
  if (rr < n) {
    const s8v* s = (const s8v*)(qkv + (size_t)myidx[rr] * 768 + ho + c0);
    v0 = s[0]; v1 = s[1]; v2 = s[2]; v3 = s[3];
  }
  s8v* d = (s8v*)&dst[r * LS + c0];
  d[0] = v0; d[1] = v1; d[2] = v2; d[3] = v3;
}

// Swapped-operand stats (T12): compute S^T = mfma(K, Q) so col=lm=query, row=key.
__global__ __launch_bounds__(256) void attn_stats_k(
    const short* __restrict__ qkv_all, const int* __restrict__ idx,
    const int* __restrict__ cnt, const int* __restrict__ cstart,
    float* __restrict__ ml)
{
  int c = blockIdx.x, z = blockIdx.z, a = z >> 1, h = z & 1;
  int n = cnt[c];
  int r0 = blockIdx.y * 64;
  if (r0 >= n) return;
  const short* qkv = qkv_all + (size_t)a * NS_ * 768;
  const int* myidx = idx + c * NS_;
  __shared__ short Qs[64 * LS];
  __shared__ short Ks[64 * LS];
  int tid = threadIdx.x, lane = tid & 63, wid = tid >> 6;
  int lm = lane & 15, quad = lane >> 4;
  stage64x128(qkv, myidx, r0, n, h * 128, Qs);
  float m_run = -3e38f, l_run = 0.f;
  for (int j0 = 0; j0 < n; j0 += 64) {
    __syncthreads();
    stage64x128(qkv, myidx, j0, n, 256 + h * 128, Ks);
    __syncthreads();
    f4v acc[4];
    #pragma unroll
    for (int mi = 0; mi < 4; ++mi) acc[mi] = (f4v)(0.f);
    #pragma unroll
    for (int kc = 0; kc < 4; ++kc) {
      s8v qf = *(const s8v*)&Qs[(wid * 16 + lm) * LS + kc * 32 + quad * 8];
      #pragma unroll
      for (int mi = 0; mi < 4; ++mi) {
        s8v kf = *(const s8v*)&Ks[(mi * 16 + lm) * LS + kc * 32 + quad * 8];
        acc[mi] = __builtin_amdgcn_mfma_f32_16x16x32_bf16(kf, qf, acc[mi], 0, 0, 0);
      }
    }
    float sv[16];
    float tm = -3e38f;
    #pragma unroll
    for (int mi = 0; mi < 4; ++mi) {
      #pragma unroll
      for (int r = 0; r < 4; ++r) {
        int kk = j0 + mi * 16 + quad * 4 + r;
        float s = (kk < n) ? acc[mi][r] * QSCALE : -3e38f;
        sv[mi * 4 + r] = s;
        tm = fmaxf(tm, s);
      }
    }
    tm = fmaxf(tm, __shfl_xor(tm, 16));
    tm = fmaxf(tm, __shfl_xor(tm, 32));
    float p = 0.f;
    #pragma unroll
    for (int i = 0; i < 16; ++i) p += __expf(sv[i] - tm);
    p += __shfl_xor(p, 16);
    p += __shfl_xor(p, 32);
    float mn = fmaxf(m_run, tm);
    l_run = l_run * __expf(m_run - mn) + p * __expf(tm - mn);
    m_run = mn;
  }
  int row = r0 + wid * 16 + lm;
  if (quad == 0 && row < n) {
    size_t p = (size_t)z * NS_ + cstart[c] + row;
    ml[p * 2] = m_run; ml[p * 2 + 1] = l_run;
  }
}

__global__ __launch_bounds__(256) void attn_colsum_k(
    const short* __restrict__ qkv_all, const int* __restrict__ idx,
    const int* __restrict__ cnt, const int* __restrict__ cstart,
    const float* __restrict__ ml, float* __restrict__ colsum)
{
  int c = blockIdx.x, z = blockIdx.z, a = z >> 1, h = z & 1;
  int n = cnt[c];
  int j0 = blockIdx.y * 64;
  if (j0 >= n) return;
  const short* qkv = qkv_all + (size_t)a * NS_ * 768;
  const int* myidx = idx + c * NS_;
  __shared__ short Qs[64 * LS];
  __shared__ short Ks[64 * LS];
  __shared__ float Msm[64], Lsm[64];
  int tid = threadIdx.x, lane = tid & 63, wid = tid >> 6;
  int lm = lane & 15, quad = lane >> 4;
  stage64x128(qkv, myidx, j0, n, 256 + h * 128, Ks);
  float ca = 0.f;
  for (int i0 = 0; i0 < n; i0 += 64) {
    __syncthreads();
    stage64x128(qkv, myidx, i0, n, h * 128, Qs);
    if (tid < 64) {
      int gi = i0 + tid;
      if (gi < n) {
        size_t p = (size_t)z * NS_ + cstart[c] + gi;
        Msm[tid] = ml[p * 2]; Lsm[tid] = ml[p * 2 + 1];
      } else { Msm[tid] = 0.f; Lsm[tid] = 1.f; }
    }
    __syncthreads();
    f4v acc[4];
    #pragma unroll
    for (int mi = 0; mi < 4; ++mi) acc[mi] = (f4v)(0.f);
    #pragma unroll
    for (int kc = 0; kc < 4; ++kc) {
      s8v bfr = *(const s8v*)&Ks[(wid * 16 + lm) * LS + kc * 32 + quad * 8];
      #pragma unroll
      for (int mi = 0; mi < 4; ++mi) {
        s8v af = *(const s8v*)&Qs[(mi * 16 + lm) * LS + kc * 32 + quad * 8];
        acc[mi] = __builtin_amdgcn_mfma_f32_16x16x32_bf16(af, bfr, acc[mi], 0, 0, 0);
      }
    }
    #pragma unroll
    for (int mi = 0; mi < 4; ++mi) {
      #pragma unroll
      for (int r = 0; r < 4; ++r) {
        int lrow = mi * 16 + quad * 4 + r;
        int gi = i0 + lrow;
        if (gi < n) {
          float m = Msm[lrow];
          float invl = 1.f / Lsm[lrow];
          ca += __expf(acc[mi][r] * QSCALE - m) * invl;
        }
      }
    }
  }
  ca += __shfl_xor(ca, 16);
  ca += __shfl_xor(ca, 32);
  int col = j0 + wid * 16 + lm;
  if (quad == 0 && col < n)
    colsum[(size_t)z * NS_ + cstart[c] + col] = ca;
}

// ---- proto V-aggregation ----
#define PCH 8
__global__ __launch_bounds__(1024) void proto_reduce_k(
    const short* __restrict__ qkv_all, const int* __restrict__ idx,
    const int* __restrict__ cnt, const int* __restrict__ cstart,
    const float* __restrict__ colsum, float* __restrict__ proto_pre) {
  int c = blockIdx.x, a = blockIdx.y;
  int n = cnt[c];
  int tid = threadIdx.x, lane = tid & 63, wid = tid >> 6;
  int h = lane >> 5;
  int e0 = lane * 4;
  const short* qkv = qkv_all + (size_t)a * NS_ * 768 + 512;
  const float* csum = colsum + (size_t)(a * 2 + h) * NS_ + cstart[c];
  const int* myidx = idx + c * NS_;
  float a0 = 0.f, a1 = 0.f, a2 = 0.f, a3 = 0.f;
  for (int k = wid; k < n; k += 16) {
    float w = csum[k];
    const s4v v = *(const s4v*)(qkv + (size_t)myidx[k] * 768 + e0);
    a0 += w * bf2f(v[0]); a1 += w * bf2f(v[1]);
    a2 += w * bf2f(v[2]); a3 += w * bf2f(v[3]);
  }
  __shared__ float red[16][E_];
  *(float4*)&red[wid][e0] = make_float4(a0, a1, a2, a3);
  __syncthreads();
  if (tid < E_) {
    float s = 0.f;
    #pragma unroll
    for (int wdx = 0; wdx < 16; ++wdx) s += red[wdx][tid];
    proto_pre[((size_t)a * NWAY_ + c) * E_ + tid] = (n > 0) ? s / (float)n : 0.f;
  }
}

__global__ void proto_outproj_k(const float* __restrict__ proto_pre, const void* __restrict__ ow,
                                const void* __restrict__ ob, const int* __restrict__ cnt,
                                float* __restrict__ protos_all, float* __restrict__ pnorm,
                                const int* __restrict__ flags) {
  int c = blockIdx.x, a = blockIdx.y, e = threadIdx.x;
  const int fW = flags[49], fB = flags[50];
  __shared__ float pp[E_];
  __shared__ float r2[E_];
  pp[e] = proto_pre[((size_t)a * NWAY_ + c) * E_ + e];
  __syncthreads();
  size_t wb = (size_t)a * E_ * E_ + (size_t)e * E_;
  float s = 0.f;
  for (int k = 0; k < E_; ++k) s += pp[k] * ldw(ow, wb + k, fW);
  float v = s + ldw(ob, (size_t)a * E_ + e, fB);
  float vm = (cnt[c] > 0) ? v : 0.f;
  protos_all[((size_t)a * NWAY_ + c) * E_ + e] = vm;
  r2[e] = vm * vm;
  __syncthreads();
  for (int o = 128; o > 0; o >>= 1) { if (e < o) r2[e] += r2[e + o]; __syncthreads(); }
  if (e == 0) pnorm[a * NWAY_ + c] = r2[0];
}

// ---- biascat2[a][0:256] = ck@w1[256:512] + b1; [256:512] = 0 ----
__global__ void bias2_k(const float* __restrict__ ck, const void* __restrict__ w1,
                        const void* __restrict__ b1, float* __restrict__ biascat2,
                        const int* __restrict__ flags) {
  const int fW = flags[51], fB = flags[52];
  int a = blockIdx.x, n = threadIdx.x;
  __shared__ float c[E_];
  c[n] = ck[a * E_ + n]; __syncthreads();
  size_t wbase = (size_t)a * 2 * E_ * E_ + (size_t)E_ * E_ + n;
  float s = 0.f;
  for (int k = 0; k < E_; ++k) s += c[k] * ldw(w1, wbase + (size_t)k * E_, fW);
  biascat2[(size_t)a * 512 + n] = s + ldw(b1, (size_t)a * E_ + n, fB);
  biascat2[(size_t)a * 512 + 256 + n] = 0.f;
}

// ---- fusion combine: fh1 = relu(sum_a U[a][:,256:512] + f_b1); 8 rows/block ----
__global__ __launch_bounds__(256) void fcomb2_k(const short* __restrict__ U, const void* __restrict__ b1,
                                                short* __restrict__ fh1, const int* __restrict__ flags) {
  const int fB = flags[59];
  int r = threadIdx.x >> 5;
  int n0 = (threadIdx.x & 31) * 8;
  int i = blockIdx.x * 8 + r;
  float acc[8];
  #pragma unroll
  for (int q = 0; q < 8; ++q) acc[q] = ldw(b1, n0 + q, fB);
  #pragma unroll
  for (int a = 0; a < A_; ++a) {
    s8v v = *(const s8v*)(U + ((size_t)a * NQ_ + i) * 512 + 256 + n0);
    #pragma unroll
    for (int q = 0; q < 8; ++q) acc[q] += bf2f(v[q]);
  }
  short yv[8];
  #pragma unroll
  for (int q = 0; q < 8; ++q) yv[q] = f2bf(fmaxf(acc[q], 0.f));
  *(s8v*)(fh1 + (size_t)i * 256 + n0) = *(s8v*)yv;
}

// ---------------- epilogues: thread-per-row, no cross-lane reductions ----------------
__global__ __launch_bounds__(256) void logits2_k(const short* __restrict__ fqbase,
                                                 const float* __restrict__ protos_all,
                                                 const float* __restrict__ pnorm,
                                                 const bf16* __restrict__ c2all,
                                                 const void* __restrict__ w3,
                                                 const void* __restrict__ b3,
                                                 float* __restrict__ out,
                                                 const int* __restrict__ flags) {
  const int fW = flags[55], fB = flags[56];
  const int a = blockIdx.y;
  const int i = blockIdx.x * 256 + threadIdx.x;
  __shared__ float ps[NWAY_][E_];
  __shared__ float w3s[128];
  for (int t = threadIdx.x; t < NWAY_ * E_; t += 256)
    ps[t >> 8][t & 255] = protos_all[(size_t)a * NWAY_ * E_ + t];
  if (threadIdx.x < 128) w3s[threadIdx.x] = ldw(w3, (size_t)a * 128 + threadIdx.x, fW);
  __syncthreads();
  const short* fq = fqbase + (size_t)a * FSTR + (size_t)i * E_;
  float qq = 0.f, dt0 = 0.f, dt1 = 0.f, dt2 = 0.f, dt3 = 0.f, dt4 = 0.f;
  for (int e0 = 0; e0 < E_; e0 += 8) {
    s8v v = *(const s8v*)(fq + e0);
    #pragma unroll
    for (int q = 0; q < 8; ++q) {
      float x = bf2f(v[q]); int e = e0 + q;
      qq += x * x;
      dt0 += x * ps[0][e]; dt1 += x * ps[1][e]; dt2 += x * ps[2][e];
      dt3 += x * ps[3][e]; dt4 += x * ps[4][e];
    }
  }
  const short* c2 = (const short*)c2all + ((size_t)a * NQ_ + i) * 128;
  float conf = 0.f;
  for (int e0 = 0; e0 < 128; e0 += 8) {
    s8v v = *(const s8v*)(c2 + e0);
    #pragma unroll
    for (int q = 0; q < 8; ++q) conf += bf2f(v[q]) * w3s[e0 + q];
  }
  conf += ldw(b3, a, fB);
  float dts[5] = { dt0, dt1, dt2, dt3, dt4 };
  float* o = out + ((size_t)a * NQ_ + i) * NWAY_;
  #pragma unroll
  for (int c = 0; c < NWAY_; ++c) {
    float pp = pnorm[a * NWAY_ + c];
    float d2 = fmaxf(qq + pp - 2.f * dts[c], 1e-12f);
    o[c] = -sqrtf(d2) + 0.1f * conf;
  }
}

__global__ __launch_bounds__(256) void fused2_k(const float* __restrict__ h2, const void* __restrict__ w3,
                                                const void* __restrict__ b3, float* __restrict__ out,
                                                const int* __restrict__ flags) {
  const int fW = flags[62], fB = flags[63];
  int i = blockIdx.x * 256 + threadIdx.x;
  __shared__ float ws[128];
  if (threadIdx.x < 128) ws[threadIdx.x] = ldw(w3, threadIdx.x, fW);
  __syncthreads();
  const float* h = h2 + (size_t)i * 128;
  float s = 0.f;
  for (int e = 0; e < 128; e += 4) {
    float4 v = *(const float4*)(h + e);
    s += v.x * ws[e] + v.y * ws[e + 1] + v.z * ws[e + 2] + v.w * ws[e + 3];
  }
  out[i] = s + ldw(b3, 0, fB);
}

// ---------------- host ----------------
extern "C" void kernel_launch(void* const* d_in, const int* in_sizes, int n_in,
                              void* d_out, int out_size, void* d_ws, size_t ws_size,
                              hipStream_t stream) {
  (void)out_size; (void)ws_size;
  #define P(i) ((const void*)d_in[i])
  const int* support_y = (const int*)d_in[1];
  float* out = (float*)d_out;

  int* flags = (int*)d_ws;
  char* base = (char*)d_ws + 256;
  short* featsC = (short*)base;                        // bf16 [A][NM][E]
  char* R = base + (size_t)A_ * FSTR * 2;
  short* t1cat   = (short*)R;                          // [NM][2304] bf16
  short* qkv_all = (short*)R;                          // [A][NS][768] bf16
  short* U       = (short*)(R + (size_t)15728640);     // [A][NQ][512] bf16
  short* fh1     = (short*)R;                          // [NQ][256] bf16
  float* fh2     = (float*)(R + (size_t)8388608);      // [NQ][128] f32
  char* XCR = R + (size_t)57671680;
  short* XC   = (short*)XCR;
  short* b4   = (short*)(XCR + (size_t)NM_ * 256 * 2);
  short* clsC2_all = (short*)XCR;
  char* S = XCR + (size_t)10485760;
  float* state      = (float*)S;
  float* msg        = state + A_ * E_;
  float* ck         = msg + A_ * E_;
  float* protos_all = ck + A_ * E_;
  float* biascat2   = protos_all + A_ * NWAY_ * E_;
  float* ml         = biascat2 + A_ * 512;
  float* colsum     = ml + (size_t)A_ * 2 * NS_ * 2;
  float* proto_pre  = colsum + (size_t)A_ * 2 * NS_;
  int*   idx        = (int*)(proto_pre + A_ * NWAY_ * E_);
  int*   cnt        = idx + NWAY_ * NS_;
  int*   cstart     = cnt + NWAY_;
  float* statepart  = (float*)(cstart + NWAY_ + 3);
  float* mvp        = statepart + A_ * 16 * E_;
  float* qkvc       = mvp + A_ * 8 * E_;
  float* obar       = qkvc + A_ * 4 * 768;
  float* comb       = obar + A_ * E_;
  float* hh         = comb + A_ * E_;
  float* ckb        = hh + A_ * E_;
  float* ppart      = ckb + A_ * 768;                  // reused as pnorm (25 floats)
  float* bcat       = ppart + (size_t)A_ * NWAY_ * PCH * E_;
  short* Wcat       = (short*)(bcat + 2304);
  short* Bcat2      = Wcat + (size_t)2304 * 512;
  short* W2         = Bcat2 + (size_t)A_ * 512 * 256;  // converted TRB bf16 weights (~3.7 MB)

  const short* fq_base = featsC + (size_t)NS_ * E_;

  Ptrs ps;
  for (int i = 0; i < 64; ++i) {
    ps.p[i] = (i < n_in) ? d_in[i] : nullptr;
    ps.sz[i] = (i < n_in) ? in_sizes[i] : 0;
  }
  probe_k<<<64, 64, 0, stream>>>(ps, flags);
  classidx_k<<<1, 256, 0, stream>>>(support_y, idx, cnt, cstart);
  xcopy_k<<<(NM_ * 512 / 4) / 256, 256, 0, stream>>>(P(0), P(2), XC, flags);
  wcat_k<<<dim3(9, 512), 256, 0, stream>>>(ps, Wcat, bcat, flags);
  wcls_k<<<dim3(512, A_), 256, 0, stream>>>(P(51), P(58), Bcat2, flags);
  wconv_k<<<dim3(960, 9), 256, 0, stream>>>(ps, W2, flags);

  // ---- FE: mega layer-1 GEMM (N = 2304), per-tile act map; GDB gload-dbuf path ----
  gemm<2, 2, false, true, 0, false, false, true, true>(
      stream, XC, 512, Wcat, 512, 0, bcat, 0, (float*)t1cat, 2304,
      NM_, 2304, 512, 1.f, -1, -1, -1, flags, 1, 0, 0, 0, 0, 0, 0x555555000ULL);
  // t1cat LNs for branches 0 and 1 (in-place)
  lnv_k<1, 512><<<NM_ / 4, 256, 0, stream>>>(t1cat, P(6), P(7), t1cat, 2304, 2304, 6, 7, flags);
  lnv_k<1, 256><<<NM_ / 4, 256, 0, stream>>>(t1cat + 512, P(14), P(15), t1cat + 512, 2304, 2304, 14, 15, flags);

  // ---- all five FE layer-2 GEMMs in ONE z-batched launch (grid 2x80x5 = 800 blocks) ----
  {
    MG5 mg;
    mg.A[0] = t1cat;        mg.K[0] = 512; mg.B[0] = W2 + 0;      mg.bias[0] = P(9);  mg.ib[0] = 9;  mg.C[0] = featsC;            mg.act[0] = 0;
    mg.A[1] = t1cat + 512;  mg.K[1] = 256; mg.B[1] = W2 + 131072; mg.bias[1] = P(17); mg.ib[1] = 17; mg.C[1] = featsC + FSTR;     mg.act[1] = 2;
    mg.A[2] = t1cat + 768;  mg.K[2] = 768; mg.B[2] = W2 + 196608; mg.bias[2] = P(21); mg.ib[2] = 21; mg.C[2] = featsC + 2 * FSTR; mg.act[2] = 0;
    mg.A[3] = t1cat + 1536; mg.K[3] = 256; mg.B[3] = W2 + 393216; mg.bias[3] = P(27); mg.ib[3] = 27; mg.C[3] = featsC + 3 * FSTR; mg.act[3] = 0;
    mg.A[4] = t1cat + 1792; mg.K[4] = 512; mg.B[4] = W2 + 458752; mg.bias[4] = P(33); mg.ib[4] = 33; mg.C[4] = b4;                mg.act[4] = 1;
    dim3 g(2, NM_ / 128, 5), b(256);
    gemm5_k<<<g, b, 0, stream>>>(mg, flags);
  }
  // per-branch output LNs (in-place on featsC slices)
  lnv_k<1, 256><<<NM_ / 4, 256, 0, stream>>>(featsC, P(10), P(11), featsC, 256, 256, 10, 11, flags);
  lnv_k<1, 256><<<NM_ / 4, 256, 0, stream>>>(featsC + 2 * FSTR, P(22), P(23), featsC + 2 * FSTR, 256, 256, 22, 23, flags);
  lnv_k<3, 256><<<NM_ / 4, 256, 0, stream>>>(featsC + 3 * FSTR, P(28), P(29), featsC + 3 * FSTR, 256, 256, 28, 29, flags);
  // fe4 second layer (depends on b4)
  gemm<2, 2, true, true, 0, false, false, true>(stream, b4, 256, W2 + 589824, 256, 0, P(35), 0,
                                                (float*)(featsC + 4 * FSTR), 256, NM_, 256, 256, 1.f, -1, -1, 35, flags);

  // ---- comm round ----
  statepart_k<<<dim3(A_, 16), 256, 0, stream>>>(featsC, statepart);
  statecomb_k<<<A_, 256, 0, stream>>>(statepart, P(46), state, flags);
  mvpart_k<<<dim3(A_, 8), 256, 0, stream>>>(state, P(36), 36, mvp, flags);
  mvcomb_k<2><<<A_, 256, 0, stream>>>(mvp, P(37), 37, msg, flags);
  qkvcomm_k<<<A_ * 768 / 4, 256, 0, stream>>>(msg, P(57), P(38), P(39), qkvc, flags);
  attn4_k<<<A_, 256, 0, stream>>>(qkvc, obar);
  combproj_k<<<A_ * E_ / 4, 256, 0, stream>>>(obar, P(40), P(41), P(46), comb, flags);
  mvpart_k<<<dim3(A_, 8), 256, 0, stream>>>(comb, P(42), 42, mvp, flags);
  mvcomb_k<1><<<A_, 256, 0, stream>>>(mvp, P(43), 43, hh, flags);
  mvpart_k<<<dim3(A_, 8), 256, 0, stream>>>(hh, P(44), 44, mvp, flags);
  mvcomb_k<0><<<A_, 256, 0, stream>>>(mvp, P(45), 45, ck, flags);

  // ---- batched prototype attention (ck folded into qkv bias; qkv bf16, GDB path) ----
  ckb_k<<<A_ * 768 / 4, 256, 0, stream>>>(ck, P(47), P(48), ckb, flags);
  gemm<2, 2, false, true, 0, false, false, true>(stream, featsC, 256, W2 + 851968, 256, 0, ckb, 0,
                                    (float*)qkv_all, 768, NS_, 768, 256, 1.f, -1, -1, -1, flags,
                                    A_, FSTR, (size_t)768 * 256, (size_t)768, (size_t)NS_ * 768);
  {
    dim3 g(NWAY_, NS_ / 64, A_ * 2);
    attn_stats_k<<<g, 256, 0, stream>>>(qkv_all, idx, cnt, cstart, ml);
    attn_colsum_k<<<g, 256, 0, stream>>>(qkv_all, idx, cnt, cstart, ml, colsum);
  }
  proto_reduce_k<<<dim3(NWAY_, A_), 1024, 0, stream>>>(qkv_all, idx, cnt, cstart, colsum, proto_pre);
  proto_outproj_k<<<dim3(NWAY_, A_), 256, 0, stream>>>(proto_pre, P(49), P(50), cnt, protos_all, ppart, flags);
  bias2_k<<<A_, 256, 0, stream>>>(ck, P(51), P(52), biascat2, flags);

  // ---- combined cls1 + fusion-partial GEMM (GDB gload-dbuf path) ----
  gemm<2, 2, false, true, 0, false, false, true, true>(
      stream, fq_base, 256, Bcat2, 256, 0, biascat2, 0, (float*)U, 512,
      NQ_, 512, 256, 1.f, -1, -1, -1, flags,
      A_, FSTR, (size_t)512 * 256, (size_t)512, (size_t)NQ_ * 512, 0, 0x5ULL);
  fcomb2_k<<<NQ_ / 8, 256, 0, stream>>>(U, P(59), fh1, flags);

  // ---- cls2 + logits ----
  gemm<2, 2, true, true, 1, false, false, true>(stream, U, 512, W2 + 655360, 256, 0,
                                     P(54), 0, (float*)clsC2_all, 128, NQ_, 128, 256, 1.f, -1, -1, 54, flags,
                                     A_, (size_t)NQ_ * 512, (size_t)128 * 256, (size_t)128, (size_t)NQ_ * 128);
  logits2_k<<<dim3(NQ_ / 256, A_), 256, 0, stream>>>(fq_base, protos_all, ppart,
                                                     (const bf16*)clsC2_all, P(55), P(56), out, flags);

  // ---- fusion layer-2 + output ----
  gemm<2, 2, true, true, 1, false>(stream, fh1, 256, W2 + 819200, 256, 0, P(61), 0, fh2, 128,
                                   NQ_, 128, 256, 1.f, -1, -1, 61, flags);
  fused2_k<<<NQ_ / 256, 256, 0, stream>>>(fh2, P(62), P(63), out + (size_t)A_ * NQ_ * NWAY_, flags);
}